// Round 11
// baseline (122.754 us; speedup 1.0000x reference)
//
#include <hip/hip_runtime.h>
#include <hip/hip_bf16.h>
#include <math.h>

typedef __attribute__((ext_vector_type(8))) short bf16x8;
typedef __attribute__((ext_vector_type(4))) float f32x4;

__device__ __forceinline__ void bsplit(float f, unsigned short& h,
                                       unsigned short& l) {
  __hip_bfloat16 hb = __float2bfloat16(f);
  float hf = __bfloat162float(hb);
  __hip_bfloat16 lb = __float2bfloat16(f - hf);
  h = *reinterpret_cast<unsigned short*>(&hb);
  l = *reinterpret_cast<unsigned short*>(&lb);
}

// ---------------- |w|^2 per filter row: one wave per row -------------------
__global__ __launch_bounds__(256) void sw2_kernel(
    const float* __restrict__ w1, const float* __restrict__ w2,
    const float* __restrict__ w3,
    float* __restrict__ s1, float* __restrict__ s2, float* __restrict__ s3) {
  const int wid = blockIdx.x * 4 + (threadIdx.x >> 6);
  const int lane = threadIdx.x & 63;
  const float* r;
  float* dst;
  int len;
  if (wid < 192) {
    r = w1 + wid * 25;
    dst = s1 + wid;
    len = 25;
  } else if (wid < 576) {
    int u = wid - 192;
    r = w2 + u * 576;
    dst = s2 + u;
    len = 576;
  } else {
    int u = wid - 576;
    r = w3 + (size_t)u * 1152;
    dst = s3 + u;
    len = 1152;
  }
  float s = 0.f;
  for (int i = lane; i < len; i += 64) {
    float v = r[i];
    s += v * v;
  }
#pragma unroll
  for (int off = 32; off > 0; off >>= 1) s += __shfl_down(s, off, 64);
  if (lane == 0) *dst = s;
}

// ---------------- pack w1 into B-fragment layout [br][col(64)][k(32)] ------
__global__ __launch_bounds__(256) void pack_w1_kernel(
    const float* __restrict__ w1, unsigned short* __restrict__ bh,
    unsigned short* __restrict__ bl) {
  int idx = blockIdx.x * 256 + threadIdx.x;  // 3*64*32 = 6144
  if (idx >= 6144) return;
  int k = idx & 31;
  int col = (idx >> 5) & 63;
  int br = idx >> 11;
  float f = (k < 25) ? w1[(br * 64 + col) * 25 + k] : 0.f;
  unsigned short h, l;
  bsplit(f, h, l);
  bh[idx] = h;
  bl[idx] = l;
}

// ---------------- pack conv weights (layers 2/3), split hi/lo --------------
template <int CIN, int COUT>
__global__ __launch_bounds__(256) void pack_w_kernel(
    const float* __restrict__ w, unsigned short* __restrict__ bph,
    unsigned short* __restrict__ bpl) {
  constexpr int K = CIN * 9;
  constexpr int CC = CIN / 32;
  const int n = blockIdx.x, br = blockIdx.z;
  const int t = threadIdx.x;
  __shared__ float row[K];
  const float* src = w + ((size_t)br * COUT + n) * K;
  for (int i = t; i < K; i += 256) row[i] = src[i];
  __syncthreads();
  for (int i = t; i < K; i += 256) {
    int kpos = i / CIN;
    int e = i - kpos * CIN;  // = c
    float f = row[e * 9 + kpos];
    unsigned short h, l;
    bsplit(f, h, l);
    size_t oidx =
        (((size_t)br * 9 * CC + (size_t)kpos * CC + (e >> 5)) * COUT + n) * 32 +
        (e & 31);
    bph[oidx] = h;
    bpl[oidx] = l;
  }
}

// ---------------- Layer 1: MFMA split-bf16 5x5 conv, crelu(31), pool -------
// 256 thr = 4 waves; block = 8x8 conv pixels. d^2-domain compares; per-pixel
// channel counts via slot-group ballots on the MFMA register layout.
// Tiers: all-zero (store zeros) > cheap w-path (act direct) > exact radix.
__global__ __launch_bounds__(256) void layer1_kernel(
    const float* __restrict__ x,             // [16][3][96][96]
    const unsigned short* __restrict__ bw1h, // [3][64][32]
    const unsigned short* __restrict__ bw1l,
    const float* __restrict__ sw2v,          // [3][64]
    const float* __restrict__ tri,
    float* __restrict__ a1)                  // [3][16][48][48][64]
{
  const int gidx = blockIdx.x;  // 12 x 12 tiles
  const int gy = gidx / 12, gx = gidx % 12;
  const int n = blockIdx.y, br = blockIdx.z;
  const int t = threadIdx.x;
  const int lane = t & 63, wid = t >> 6;

  __shared__ __align__(16) float win[12][12];
  __shared__ float sp2s[64];
  __shared__ float sw2s[64];
  __shared__ __align__(16) float dmat[64][68];

  const int y0 = gy * 8 - 2, x0 = gx * 8 - 2;
  const float* xb = x + ((size_t)(n * 3 + br)) * 96 * 96;
  if (t < 144) {
    int wy = t / 12, wx = t - (t / 12) * 12;
    int y = y0 + wy, xx = x0 + wx;
    float v = 0.f;
    if (y >= 0 && y < 96 && xx >= 0 && xx < 96) v = xb[y * 96 + xx];
    win[wy][wx] = v;
  }
  if (t >= 192) sw2s[t - 192] = sw2v[br * 64 + (t - 192)];
  __syncthreads();

  if (t < 64) {
    int py = t >> 3, px = t & 7;
    float s = 0.f;
#pragma unroll
    for (int ky = 0; ky < 5; ky++)
#pragma unroll
      for (int kx = 0; kx < 5; kx++) {
        float v = win[py + ky][px + kx];
        s += v * v;
      }
    sp2s[t] = s;
  }

  // ---- A fragment: patch row = pixel (lane&15), k-slot = lane>>4 ----
  const int mrow = lane & 15;
  const int slot = lane >> 4;
  const int pixel = wid * 16 + mrow;
  const int ppy = pixel >> 3, ppx = pixel & 7;
  unsigned short ahv[8], alv[8];
#pragma unroll
  for (int j = 0; j < 8; j++) {
    int k = slot * 8 + j;
    float v = 0.f;
    if (k < 25) {
      int ky = (k * 205) >> 10;  // k/5 exact for k<32
      int kx = k - ky * 5;
      v = win[ppy + ky][ppx + kx];
    }
    bsplit(v, ahv[j], alv[j]);
  }
  bf16x8 ah = *reinterpret_cast<bf16x8*>(ahv);
  bf16x8 al = *reinterpret_cast<bf16x8*>(alv);

  // ---- B fragments (4 N-tiles of 16 ch) + 12 MFMAs ----
  f32x4 acc[4];
  f32x4 zz = {0.f, 0.f, 0.f, 0.f};
#pragma unroll
  for (int nt = 0; nt < 4; nt++) acc[nt] = zz;
#pragma unroll
  for (int nt = 0; nt < 4; nt++) {
    const int off = ((br * 64 + nt * 16 + mrow) << 5) + (slot << 3);
    bf16x8 bh = *reinterpret_cast<const bf16x8*>(bw1h + off);
    bf16x8 bl = *reinterpret_cast<const bf16x8*>(bw1l + off);
    acc[nt] = __builtin_amdgcn_mfma_f32_16x16x32_bf16(ah, bh, acc[nt], 0, 0, 0);
    acc[nt] = __builtin_amdgcn_mfma_f32_16x16x32_bf16(ah, bl, acc[nt], 0, 0, 0);
    acc[nt] = __builtin_amdgcn_mfma_f32_16x16x32_bf16(al, bh, acc[nt], 0, 0, 0);
  }
  __syncthreads();  // sp2s ready (last block-wide barrier; waves diverge after)

  const float w_ = tri[br * 3 + 0];
  const float w2_ = w_ * w_;
  const float sw = sw2s[(lane & 15)];  // placeholder; real sw per nt below

  // ---- d^2 in registers: pixel = wid*16 + slot*4 + rg, ch = nt*16 + mrow --
  float d2v[4][4];
#pragma unroll
  for (int nt = 0; nt < 4; nt++) {
    const float swc = sw2s[nt * 16 + mrow];
#pragma unroll
    for (int rg = 0; rg < 4; rg++) {
      d2v[nt][rg] =
          sp2s[wid * 16 + slot * 4 + rg] + swc - 2.f * acc[nt][rg];
    }
  }

  // ---- per-pixel count of {d < w} via slot-group masked ballots ----------
  int cnt_lt[4] = {0, 0, 0, 0};
#pragma unroll
  for (int rg = 0; rg < 4; rg++) {
#pragma unroll
    for (int nt = 0; nt < 4; nt++) {
      unsigned long long m = __ballot(d2v[nt][rg] < w2_);
      cnt_lt[rg] += __popcll((m >> (slot * 16)) & 0xFFFFull);
    }
  }

  const bool myzero =
      (cnt_lt[0] | cnt_lt[1] | cnt_lt[2] | cnt_lt[3]) == 0;
  if (__all(myzero)) {
    // all 16 pixels of this wave: every activation exactly 0 -> pooled 0
#pragma unroll
    for (int g = 0; g < 4; g++) {
      a1[((((size_t)(br * 16 + n)) * 48 + (gy * 4 + wid)) * 48 +
          (gx * 4 + g)) * 64 + lane] = 0.f;
    }
    return;
  }

  const float A2[2][2] = {{0.9f, 0.93f}, {0.96f, 0.99f}};
  const bool mycheap = cnt_lt[0] <= 32 && cnt_lt[1] <= 32 &&
                       cnt_lt[2] <= 32 && cnt_lt[3] <= 32;
  if (__all(mycheap)) {
    // thr = w for all pixels: write ACT directly, pool, no radix
#pragma unroll
    for (int nt = 0; nt < 4; nt++) {
      const int ch = nt * 16 + mrow;
#pragma unroll
      for (int rg = 0; rg < 4; rg++) {
        const int p = wid * 16 + slot * 4 + rg;
        float d2 = d2v[nt][rg];
        float a = (d2 < w2_)
                      ? 1.f - sqrtf(fmaxf(d2, 1e-12f)) / w_
                      : 0.f;
        dmat[p][ch] = a;
      }
    }
#pragma unroll
    for (int g = 0; g < 4; g++) {
      float pooled = 0.f;
#pragma unroll
      for (int py = 0; py < 2; py++)
#pragma unroll
        for (int q = 0; q < 2; q++) {
          int pi = py * 8 + g * 2 + q;
          pooled += dmat[wid * 16 + pi][lane] * A2[py][q];
        }
      a1[((((size_t)(br * 16 + n)) * 48 + (gy * 4 + wid)) * 48 +
          (gx * 4 + g)) * 64 + lane] = pooled * 0.25f;
    }
    return;
  }

  // ---- exact fallback: d into dmat, per-pixel radix select ---------------
#pragma unroll
  for (int nt = 0; nt < 4; nt++) {
    const int ch = nt * 16 + mrow;
#pragma unroll
    for (int rg = 0; rg < 4; rg++) {
      const int p = wid * 16 + slot * 4 + rg;
      dmat[p][ch] = sqrtf(fmaxf(d2v[nt][rg], 1e-12f));
    }
  }
  float thrv[16];
  unsigned int need = 0;
#pragma unroll
  for (int i = 0; i < 16; i++) {
    float v = dmat[wid * 16 + i][lane];
    int cnt = __popcll(__ballot(v >= w_));
    if (cnt >= 32) thrv[i] = w_;
    else need |= (1u << i);
  }
  if (need) {
#pragma unroll
    for (int i = 0; i < 16; i++) {
      if (!((need >> i) & 1)) continue;
      unsigned int key = __float_as_uint(dmat[wid * 16 + i][lane]);
      unsigned int pre = 0;
      int rem = 31;
      for (int b = 30; b >= 0; --b) {
        unsigned int top = (pre >> b) | 1u;
        int cnt = __popcll(__ballot((key >> b) == top));
        if (cnt > rem) pre |= (1u << b);
        else rem -= cnt;
      }
      thrv[i] = __uint_as_float(pre);
    }
  }
#pragma unroll
  for (int g = 0; g < 4; g++) {
    float pooled = 0.f;
#pragma unroll
    for (int py = 0; py < 2; py++)
#pragma unroll
      for (int q = 0; q < 2; q++) {
        int pi = py * 8 + g * 2 + q;
        float d = dmat[wid * 16 + pi][lane];
        float th = fminf(thrv[pi], w_);
        float a = 1.f - ((d > th) ? w_ : d) / w_;
        pooled += a * A2[py][q];
      }
    a1[((((size_t)(br * 16 + n)) * 48 + (gy * 4 + wid)) * 48 + (gx * 4 + g)) *
           64 + lane] = pooled * 0.25f;
  }
}

// ---------------- Layers 2/3: MFMA split-bf16 RBF conv ---------------------
// Phase-1 computes cell |.|^2 sums only (no staging); zero-window blocks skip
// all bf16 conversion. POOL=0 writes TRANSPOSED feats [3][16][COUT][576].
template <int CIN, int COUT, int HIN, int KRANK, int POOL, int LIDX>
__global__ __launch_bounds__(256) void mfma_rbf3(
    const float* __restrict__ in,            // [3][16][HIN][HIN][CIN]
    const unsigned short* __restrict__ bph,  // packed hi
    const unsigned short* __restrict__ bpl,  // packed lo
    const float* __restrict__ sw2v,          // [3][COUT]
    const float* __restrict__ tri,
    float* __restrict__ out) {
  constexpr int CC = CIN / 32;
  constexpr int NCH = 9 * CC;
  constexpr int NT = COUT / 16;
  constexpr int NTW = NT / 4;
  constexpr int PADC = COUT + 4;
  constexpr int WIN_USH = 60 * CIN;
  constexpr int WIN_BYTES = 2 * WIN_USH * 2;
  constexpr int DMAT_BYTES = 32 * PADC * 4;
  constexpr int UNI_BYTES = WIN_BYTES > DMAT_BYTES ? WIN_BYTES : DMAT_BYTES;

  __shared__ __align__(16) char uni[UNI_BYTES];
  __shared__ float cellq[60][4];
  __shared__ float cellsum[60];
  __shared__ float sp2[32];
  __shared__ float thrs[32];
  __shared__ float sw2s[COUT];
  __shared__ int zflag;

  unsigned short* winh = (unsigned short*)uni;
  unsigned short* winl = winh + WIN_USH;
  float* dmat = (float*)uni;

  const int GX = HIN / 8;
  const int gy = blockIdx.x / GX, gx = blockIdx.x % GX;
  const int n = blockIdx.y, br = blockIdx.z;
  const int t = threadIdx.x;
  const int lane = t & 63;
  const int wvid = t >> 6;
  const int ng = wvid;

  const float w_ = tri[br * 3 + LIDX];
  const int y0 = gy * 4 - 1, x0 = gx * 8 - 1;
  const float* ib = in + ((size_t)(br * 16 + n)) * HIN * HIN * CIN;

  for (int i = t; i < COUT; i += 256) sw2s[i] = sw2v[br * COUT + i];

  // ---- phase 1: cell sums only (no staging / no bsplit) ------------------
  const int cell = t >> 2, q = t & 3;
  const int wy = cell / 10, wx = cell - (cell / 10) * 10;
  const int yy = y0 + wy, xx = x0 + wx;
  const bool ok = (t < 240) && (yy >= 0 && yy < HIN && xx >= 0 && xx < HIN);
  const float* rp = ib + ((size_t)yy * HIN + xx) * CIN + q * (CIN / 4);
  if (t < 240) {
    float ss = 0.f;
    if (ok) {
#pragma unroll
      for (int cq = 0; cq < CIN / 16; cq++) {
        float4 v = *reinterpret_cast<const float4*>(rp + cq * 4);
        ss += v.x * v.x + v.y * v.y + v.z * v.z + v.w * v.w;
      }
    }
    cellq[cell][q] = ss;
  }
  __syncthreads();
  if (t < 60)
    cellsum[t] = cellq[t][0] + cellq[t][1] + cellq[t][2] + cellq[t][3];
  __syncthreads();
  if (t < 32) {
    int py = t >> 3, px = t & 7;
    float s = 0.f;
#pragma unroll
    for (int ky = 0; ky < 3; ky++)
#pragma unroll
      for (int kx = 0; kx < 3; kx++) s += cellsum[(py + ky) * 10 + px + kx];
    sp2[t] = s;
  }
  if (t == 0) {
    float s = 0.f;
    for (int i = 0; i < 60; i++) s += cellsum[i];
    zflag = (s == 0.f);
  }
  __syncthreads();

  // ---- zero-window fast path ---------------------------------------------
  if (zflag) {
    for (int col = t; col < COUT; col += 256)
      dmat[col] = sqrtf(fmaxf(sw2s[col], 1e-12f));
    __syncthreads();
    if (wvid == 0) {
      float v0, v1, v2, v3;
      if constexpr (COUT == 256) {
        float4 f = *reinterpret_cast<const float4*>(&dmat[lane * 4]);
        v0 = f.x; v1 = f.y; v2 = f.z; v3 = f.w;
      } else {
        float2 f = *reinterpret_cast<const float2*>(&dmat[lane * 2]);
        v0 = f.x; v1 = f.y; v2 = 0.f; v3 = 0.f;
      }
      int cnt = __popcll(__ballot(v0 >= w_)) + __popcll(__ballot(v1 >= w_));
      if constexpr (COUT == 256)
        cnt += __popcll(__ballot(v2 >= w_)) + __popcll(__ballot(v3 >= w_));
      float thr;
      if (cnt > KRANK) {
        thr = w_;
      } else {
        unsigned int k0 = __float_as_uint(v0), k1 = __float_as_uint(v1);
        unsigned int k2 = __float_as_uint(v2), k3 = __float_as_uint(v3);
        unsigned int pre = 0;
        int rem = KRANK;
        for (int b = 30; b >= 0; --b) {
          unsigned int top = (pre >> b) | 1u;
          int c = __popcll(__ballot((k0 >> b) == top)) +
                  __popcll(__ballot((k1 >> b) == top));
          if constexpr (COUT == 256)
            c += __popcll(__ballot((k2 >> b) == top)) +
                 __popcll(__ballot((k3 >> b) == top));
          if (c > rem) pre |= (1u << b);
          else rem -= c;
        }
        thr = __uint_as_float(pre);
      }
      if (lane == 0) thrs[0] = thr;
    }
    __syncthreads();
    const float th = fminf(thrs[0], w_);
    if (POOL) {
      const int GW = HIN / 2;
      float* ob = out + ((size_t)(br * 16 + n)) * GW * GW * COUT;
      for (int col = t; col < COUT; col += 256) {
        float d0 = dmat[col];
        float a = 1.f - ((d0 > th) ? w_ : d0) / w_;
        float po = 0.25f * (a * 0.9f + a * 0.93f + a * 0.96f + a * 0.99f);
#pragma unroll
        for (int qq = 0; qq < 8; qq++) {
          int qy = qq >> 2, qx = qq & 3;
          ob[((size_t)((gy * 2 + qy) * GW + gx * 4 + qx)) * COUT + col] = po;
        }
      }
    } else {
      // transposed feats [col][576]
      float* ob = out + ((size_t)(br * 16 + n)) * COUT * 576;
      for (int col = t; col < COUT; col += 256) {
        float d0 = dmat[col];
        float a = 1.f - ((d0 > th) ? w_ : d0) / w_;
        float4 av = make_float4(a, a, a, a);
#pragma unroll
        for (int row = 0; row < 4; row++) {
          float* dst = ob + (size_t)col * 576 + (gy * 4 + row) * 24 + gx * 8;
          *reinterpret_cast<float4*>(dst) = av;
          *reinterpret_cast<float4*>(dst + 4) = av;
        }
      }
    }
    return;
  }

  // ---- phase 2: full staging with bsplit (global reload, L2-hot) ---------
  if (t < 240) {
    const int sx = (wx & 7) << 3;
#pragma unroll
    for (int cq = 0; cq < CIN / 16; cq++) {
      float4 v = ok ? *reinterpret_cast<const float4*>(rp + cq * 4)
                    : make_float4(0.f, 0.f, 0.f, 0.f);
      unsigned short hh[4], ll[4];
      float fv[4] = {v.x, v.y, v.z, v.w};
#pragma unroll
      for (int j = 0; j < 4; j++) bsplit(fv[j], hh[j], ll[j]);
      int c = q * (CIN / 4) + cq * 4;
      int cst = c ^ sx;
      *reinterpret_cast<ushort4*>(&winh[cell * CIN + cst]) =
          make_ushort4(hh[0], hh[1], hh[2], hh[3]);
      *reinterpret_cast<ushort4*>(&winl[cell * CIN + cst]) =
          make_ushort4(ll[0], ll[1], ll[2], ll[3]);
    }
  }
  __syncthreads();

  // ---- conv: reg-dbuf B pipeline, 3-term split ---------------------------
  const int pix0 = lane & 15;
  const int g8 = (lane >> 4) << 3;
  const int ppy = pix0 >> 3, ppx = pix0 & 7;

  f32x4 acc[2][NTW];
  f32x4 zz = {0.f, 0.f, 0.f, 0.f};
#pragma unroll
  for (int mt = 0; mt < 2; mt++)
#pragma unroll
    for (int nt = 0; nt < NTW; nt++) acc[mt][nt] = zz;

  const size_t bbase = (size_t)br * NCH;
  const int nb0 = ng * (NTW * 16) + pix0;

  bf16x8 bufA[2 * NTW], bufB[2 * NTW];

  auto loadB = [&](int chunk, bf16x8* dst) {
    const unsigned short* p0 = bph + ((bbase + chunk) * COUT + nb0) * 32 + g8;
    const unsigned short* p1 = bpl + ((bbase + chunk) * COUT + nb0) * 32 + g8;
#pragma unroll
    for (int nt = 0; nt < NTW; nt++) {
      dst[2 * nt] = *reinterpret_cast<const bf16x8*>(p0 + nt * 512);
      dst[2 * nt + 1] = *reinterpret_cast<const bf16x8*>(p1 + nt * 512);
    }
  };

  auto compute = [&](int chunk, bf16x8* b) {
    const int kpos = chunk / CC, cc = chunk - (chunk / CC) * CC;
    const int ky = kpos / 3, kx = kpos - (kpos / 3) * 3;
    const int wxx = ppx + kx;
    const int sx = (wxx & 7) << 3;
    const int cbase = ((cc << 5) + g8) ^ sx;
#pragma unroll
    for (int mt = 0; mt < 2; mt++) {
      const int r0 = (mt * 2 + ppy + ky) * 10 + wxx;
      bf16x8 ah = *reinterpret_cast<const bf16x8*>(&winh[r0 * CIN + cbase]);
      bf16x8 al = *reinterpret_cast<const bf16x8*>(&winl[r0 * CIN + cbase]);
#pragma unroll
      for (int nt = 0; nt < NTW; nt++) {
        acc[mt][nt] = __builtin_amdgcn_mfma_f32_16x16x32_bf16(
            ah, b[2 * nt], acc[mt][nt], 0, 0, 0);
        acc[mt][nt] = __builtin_amdgcn_mfma_f32_16x16x32_bf16(
            ah, b[2 * nt + 1], acc[mt][nt], 0, 0, 0);
        acc[mt][nt] = __builtin_amdgcn_mfma_f32_16x16x32_bf16(
            al, b[2 * nt], acc[mt][nt], 0, 0, 0);
      }
    }
  };

  loadB(0, bufA);
  for (int ch = 0; ch < NCH; ch += 2) {
    loadB(ch + 1, bufB);
    compute(ch, bufA);
    if (ch + 2 < NCH) loadB(ch + 2, bufA);
    compute(ch + 1, bufB);
  }

  __syncthreads();  // conv reads of win done (alias!), sp2 visible

  const int rgrp = (lane >> 4) << 2;
#pragma unroll
  for (int mt = 0; mt < 2; mt++) {
    const int prow = mt * 16 + rgrp;
#pragma unroll
    for (int nt = 0; nt < NTW; nt++) {
      const int col = ng * (NTW * 16) + nt * 16 + pix0;
      const float sw = sw2s[col];
#pragma unroll
      for (int rg = 0; rg < 4; rg++) {
        const int pix = prow + rg;
        float d2 = sp2[pix] + sw - 2.f * acc[mt][nt][rg];
        dmat[pix * PADC + col] = sqrtf(fmaxf(d2, 1e-12f));
      }
    }
  }
  __syncthreads();

  for (int i = 0; i < 8; i++) {
    const int p = wvid * 8 + i;
    float v0, v1, v2, v3;
    if constexpr (COUT == 256) {
      float4 f = *reinterpret_cast<const float4*>(&dmat[p * PADC + lane * 4]);
      v0 = f.x; v1 = f.y; v2 = f.z; v3 = f.w;
    } else {
      float2 f = *reinterpret_cast<const float2*>(&dmat[p * PADC + lane * 2]);
      v0 = f.x; v1 = f.y; v2 = 0.f; v3 = 0.f;
    }
    int cnt = __popcll(__ballot(v0 >= w_)) + __popcll(__ballot(v1 >= w_));
    if constexpr (COUT == 256)
      cnt += __popcll(__ballot(v2 >= w_)) + __popcll(__ballot(v3 >= w_));
    if (cnt > KRANK) {
      if (lane == 0) thrs[p] = w_;
      continue;
    }
    unsigned int k0 = __float_as_uint(v0), k1 = __float_as_uint(v1);
    unsigned int k2 = __float_as_uint(v2), k3 = __float_as_uint(v3);
    unsigned int pre = 0;
    int rem = KRANK;
    for (int b = 30; b >= 0; --b) {
      unsigned int top = (pre >> b) | 1u;
      int c = __popcll(__ballot((k0 >> b) == top)) +
              __popcll(__ballot((k1 >> b) == top));
      if constexpr (COUT == 256)
        c += __popcll(__ballot((k2 >> b) == top)) +
             __popcll(__ballot((k3 >> b) == top));
      if (c > rem) pre |= (1u << b);
      else rem -= c;
    }
    if (lane == 0) thrs[p] = __uint_as_float(pre);
  }
  __syncthreads();

  if (POOL) {
    const int GW = HIN / 2;
    float* ob = out + ((size_t)(br * 16 + n)) * GW * GW * COUT;
    for (int i = t; i < 8 * COUT; i += 256) {
      int qq = i / COUT;
      int chn = i - qq * COUT;
      int qy = qq >> 2, qx = qq & 3;
      int p00 = qy * 16 + qx * 2;
      float d00 = dmat[p00 * PADC + chn];
      float d01 = dmat[(p00 + 1) * PADC + chn];
      float d10 = dmat[(p00 + 8) * PADC + chn];
      float d11 = dmat[(p00 + 9) * PADC + chn];
      float t00 = fminf(thrs[p00], w_);
      float t01 = fminf(thrs[p00 + 1], w_);
      float t10 = fminf(thrs[p00 + 8], w_);
      float t11 = fminf(thrs[p00 + 9], w_);
      float a00 = 1.f - ((d00 > t00) ? w_ : d00) / w_;
      float a01 = 1.f - ((d01 > t01) ? w_ : d01) / w_;
      float a10 = 1.f - ((d10 > t10) ? w_ : d10) / w_;
      float a11 = 1.f - ((d11 > t11) ? w_ : d11) / w_;
      float po =
          0.25f * (a00 * 0.9f + a01 * 0.93f + a10 * 0.96f + a11 * 0.99f);
      ob[((size_t)((gy * 2 + qy) * GW + gx * 4 + qx)) * COUT + chn] = po;
    }
  } else {
    // transposed feats [ch][576]
    float* ob = out + ((size_t)(br * 16 + n)) * COUT * 576;
    for (int item = t; item < COUT * 4; item += 256) {
      int chn = item & (COUT - 1);
      int rowq = item >> 8;
      float vals[8];
#pragma unroll
      for (int px = 0; px < 8; px++) {
        int p = rowq * 8 + px;
        float d = dmat[p * PADC + chn];
        float tt = fminf(thrs[p], w_);
        vals[px] = 1.f - ((d > tt) ? w_ : d) / w_;
      }
      float* dst = ob + (size_t)chn * 576 + (gy * 4 + rowq) * 24 + gx * 8;
      *reinterpret_cast<float4*>(dst) =
          make_float4(vals[0], vals[1], vals[2], vals[3]);
      *reinterpret_cast<float4*>(dst + 4) =
          make_float4(vals[4], vals[5], vals[6], vals[7]);
    }
  }
}

// ---------------- FC: split-K MFMA, D = [16 n][16 oo] ----------------------
__global__ __launch_bounds__(64) void fc_mfma_kernel(
    const float* __restrict__ featsT, const float* __restrict__ fcw,
    float* __restrict__ partial) {
  const int blk = blockIdx.x;  // 864 blocks, 512 k each (16 chunks of 32)
  const int lane = threadIdx.x;
  const int mrow = lane & 15;  // n for A, oo for B
  const int slot = lane >> 4;
  const int slot8 = slot * 8;
  const int k0base = blk * 512;

  f32x4 acc = {0.f, 0.f, 0.f, 0.f};
  float4 z4 = make_float4(0.f, 0.f, 0.f, 0.f);
  for (int cc = 0; cc < 16; ++cc) {
    int k0 = k0base + cc * 32;
    int br = k0 / 147456;
    int rb = k0 - br * 147456;
    int c = rb / 576;
    int pth = rb - c * 576;
    const float* ap =
        featsT + (((size_t)(br * 16 + mrow) * 256 + c) * 576 + pth + slot8);
    float4 a0 = *reinterpret_cast<const float4*>(ap);
    float4 a1q = *reinterpret_cast<const float4*>(ap + 4);
    float4 b0 = z4, b1q = z4;
    if (mrow < 10) {
      const float* bp = fcw + (size_t)mrow * 442368 + k0 + slot8;
      b0 = *reinterpret_cast<const float4*>(bp);
      b1q = *reinterpret_cast<const float4*>(bp + 4);
    }
    float af[8] = {a0.x, a0.y, a0.z, a0.w, a1q.x, a1q.y, a1q.z, a1q.w};
    float bf[8] = {b0.x, b0.y, b0.z, b0.w, b1q.x, b1q.y, b1q.z, b1q.w};
    unsigned short ahv[8], alv[8], bhv[8], blv[8];
#pragma unroll
    for (int j = 0; j < 8; j++) {
      bsplit(af[j], ahv[j], alv[j]);
      bsplit(bf[j], bhv[j], blv[j]);
    }
    bf16x8 ah = *reinterpret_cast<bf16x8*>(ahv);
    bf16x8 al = *reinterpret_cast<bf16x8*>(alv);
    bf16x8 bh = *reinterpret_cast<bf16x8*>(bhv);
    bf16x8 bl = *reinterpret_cast<bf16x8*>(blv);
    acc = __builtin_amdgcn_mfma_f32_16x16x32_bf16(ah, bh, acc, 0, 0, 0);
    acc = __builtin_amdgcn_mfma_f32_16x16x32_bf16(ah, bl, acc, 0, 0, 0);
    acc = __builtin_amdgcn_mfma_f32_16x16x32_bf16(al, bh, acc, 0, 0, 0);
  }
#pragma unroll
  for (int rg = 0; rg < 4; rg++)
    partial[(size_t)blk * 256 + (slot * 4 + rg) * 16 + mrow] = acc[rg];
}

__global__ __launch_bounds__(64) void fc_final_kernel(
    const float* __restrict__ partial, const float* __restrict__ fcb,
    float* __restrict__ outp) {
  const int n = blockIdx.x / 10, oo = blockIdx.x % 10;
  const int lane = threadIdx.x;
  float s = 0.f;
  for (int b = lane; b < 864; b += 64)
    s += partial[(size_t)b * 256 + n * 16 + oo];
#pragma unroll
  for (int off = 32; off > 0; off >>= 1) s += __shfl_down(s, off, 64);
  if (lane == 0) outp[n * 10 + oo] = s + fcb[oo];
}

// ---------------------------------------------------------------------------
extern "C" void kernel_launch(void* const* d_in, const int* in_sizes, int n_in,
                              void* d_out, int out_size, void* d_ws,
                              size_t ws_size, hipStream_t stream) {
  const float* x   = (const float*)d_in[0];
  const float* w1  = (const float*)d_in[1];
  const float* w2  = (const float*)d_in[2];
  const float* w3  = (const float*)d_in[3];
  const float* tri = (const float*)d_in[4];
  const float* fcw = (const float*)d_in[5];
  const float* fcb = (const float*)d_in[6];
  float* out = (float*)d_out;

  float* ws = (float*)d_ws;
  float* a1     = ws;                 // 7,077,888
  float* a2     = a1 + 7077888;       // 3,538,944
  float* featsT = a2 + 3538944;       // 7,077,888  [br][n][256][576]
  float* s1     = featsT + 7077888;   // 192
  float* s2     = s1 + 192;           // 384
  float* s3     = s2 + 384;           // 768
  unsigned short* bw1h = (unsigned short*)(s3 + 768);    // 6,144 ushorts
  unsigned short* bw1l = bw1h + 6144;
  unsigned short* bph2 = bw1l + 6144;                    // 221,184
  unsigned short* bpl2 = bph2 + 221184;
  unsigned short* bph3 = bpl2 + 221184;                  // 884,736
  unsigned short* bpl3 = bph3 + 884736;
  float* partial = (float*)(bpl3 + 884736);              // 221,184 floats

  sw2_kernel<<<dim3(336), dim3(256), 0, stream>>>(w1, w2, w3, s1, s2, s3);
  pack_w1_kernel<<<dim3(24), dim3(256), 0, stream>>>(w1, bw1h, bw1l);
  pack_w_kernel<64, 128><<<dim3(128, 1, 3), dim3(256), 0, stream>>>(w2, bph2,
                                                                    bpl2);
  pack_w_kernel<128, 256><<<dim3(256, 1, 3), dim3(256), 0, stream>>>(w3, bph3,
                                                                     bpl3);

  layer1_kernel<<<dim3(144, 16, 3), dim3(256), 0, stream>>>(x, bw1h, bw1l, s1,
                                                            tri, a1);
  mfma_rbf3<64, 128, 48, 63, 1, 1>
      <<<dim3(72, 16, 3), dim3(256), 0, stream>>>(a1, bph2, bpl2, s2, tri, a2);
  mfma_rbf3<128, 256, 24, 152, 0, 2>
      <<<dim3(18, 16, 3), dim3(256), 0, stream>>>(a2, bph3, bpl3, s3, tri,
                                                  featsT);
  fc_mfma_kernel<<<dim3(864), dim3(64), 0, stream>>>(featsT, fcw, partial);
  fc_final_kernel<<<dim3(160), dim3(64), 0, stream>>>(partial, fcb, out);
}

// Round 12
// 121.148 us; speedup vs baseline: 1.0133x; 1.0133x over previous
//
#include <hip/hip_runtime.h>
#include <hip/hip_bf16.h>
#include <math.h>

typedef __attribute__((ext_vector_type(8))) short bf16x8;
typedef __attribute__((ext_vector_type(4))) float f32x4;

__device__ __forceinline__ void bsplit(float f, unsigned short& h,
                                       unsigned short& l) {
  __hip_bfloat16 hb = __float2bfloat16(f);
  float hf = __bfloat162float(hb);
  __hip_bfloat16 lb = __float2bfloat16(f - hf);
  h = *reinterpret_cast<unsigned short*>(&hb);
  l = *reinterpret_cast<unsigned short*>(&lb);
}

// ---------------- |w|^2 per filter row: one wave per row -------------------
__global__ __launch_bounds__(256) void sw2_kernel(
    const float* __restrict__ w1, const float* __restrict__ w2,
    const float* __restrict__ w3,
    float* __restrict__ s1, float* __restrict__ s2, float* __restrict__ s3) {
  const int wid = blockIdx.x * 4 + (threadIdx.x >> 6);
  const int lane = threadIdx.x & 63;
  const float* r;
  float* dst;
  int len;
  if (wid < 192) {
    r = w1 + wid * 25; dst = s1 + wid; len = 25;
  } else if (wid < 576) {
    int u = wid - 192; r = w2 + u * 576; dst = s2 + u; len = 576;
  } else {
    int u = wid - 576; r = w3 + (size_t)u * 1152; dst = s3 + u; len = 1152;
  }
  float s = 0.f;
  for (int i = lane; i < len; i += 64) {
    float v = r[i];
    s += v * v;
  }
#pragma unroll
  for (int off = 32; off > 0; off >>= 1) s += __shfl_down(s, off, 64);
  if (lane == 0) *dst = s;
}

// ---------------- prep: zero-window constants for layers 2/3 ---------------
// layer2: po0_2[br][128] (pooled act for all-zero window), sp0_2[br]=sum sq.
// layer3: act0_3[br][256].
__global__ __launch_bounds__(64) void prep_kernel(
    const float* __restrict__ s2, const float* __restrict__ s3,
    const float* __restrict__ tri, float* __restrict__ po0_2,
    float* __restrict__ sp0_2, float* __restrict__ act0_3) {
  const int br = blockIdx.x, lay = blockIdx.y, lane = threadIdx.x;
  if (lay == 0) {
    const float w_ = tri[br * 3 + 1];
    float d0 = sqrtf(fmaxf(s2[br * 128 + lane * 2], 1e-12f));
    float d1 = sqrtf(fmaxf(s2[br * 128 + lane * 2 + 1], 1e-12f));
    int cnt = __popcll(__ballot(d0 >= w_)) + __popcll(__ballot(d1 >= w_));
    float thr;
    if (cnt > 63) {
      thr = w_;
    } else {
      unsigned int k0 = __float_as_uint(d0), k1 = __float_as_uint(d1);
      unsigned int pre = 0;
      int rem = 63;
      for (int b = 30; b >= 0; --b) {
        unsigned int top = (pre >> b) | 1u;
        int c = __popcll(__ballot((k0 >> b) == top)) +
                __popcll(__ballot((k1 >> b) == top));
        if (c > rem) pre |= (1u << b);
        else rem -= c;
      }
      thr = __uint_as_float(pre);
    }
    float th = fminf(thr, w_);
    float a0 = 1.f - ((d0 > th) ? w_ : d0) / w_;
    float a1v = 1.f - ((d1 > th) ? w_ : d1) / w_;
    float p0 = a0 * 0.945f, p1 = a1v * 0.945f;
    po0_2[br * 128 + lane * 2] = p0;
    po0_2[br * 128 + lane * 2 + 1] = p1;
    float ss = p0 * p0 + p1 * p1;
#pragma unroll
    for (int off = 32; off > 0; off >>= 1) ss += __shfl_down(ss, off, 64);
    if (lane == 0) sp0_2[br] = ss;
  } else {
    const float w_ = tri[br * 3 + 2];
    float d[4];
#pragma unroll
    for (int j = 0; j < 4; j++)
      d[j] = sqrtf(fmaxf(s3[br * 256 + lane * 4 + j], 1e-12f));
    int cnt = 0;
#pragma unroll
    for (int j = 0; j < 4; j++) cnt += __popcll(__ballot(d[j] >= w_));
    float thr;
    if (cnt > 152) {
      thr = w_;
    } else {
      unsigned int k[4];
#pragma unroll
      for (int j = 0; j < 4; j++) k[j] = __float_as_uint(d[j]);
      unsigned int pre = 0;
      int rem = 152;
      for (int b = 30; b >= 0; --b) {
        unsigned int top = (pre >> b) | 1u;
        int c = 0;
#pragma unroll
        for (int j = 0; j < 4; j++)
          c += __popcll(__ballot((k[j] >> b) == top));
        if (c > rem) pre |= (1u << b);
        else rem -= c;
      }
      thr = __uint_as_float(pre);
    }
    float th = fminf(thr, w_);
#pragma unroll
    for (int j = 0; j < 4; j++)
      act0_3[br * 256 + lane * 4 + j] = 1.f - ((d[j] > th) ? w_ : d[j]) / w_;
  }
}

// ---------------- pack w1 into B-fragment layout [br][col(64)][k(32)] ------
__global__ __launch_bounds__(256) void pack_w1_kernel(
    const float* __restrict__ w1, unsigned short* __restrict__ bh,
    unsigned short* __restrict__ bl) {
  int idx = blockIdx.x * 256 + threadIdx.x;
  if (idx >= 6144) return;
  int k = idx & 31;
  int col = (idx >> 5) & 63;
  int br = idx >> 11;
  float f = (k < 25) ? w1[(br * 64 + col) * 25 + k] : 0.f;
  unsigned short h, l;
  bsplit(f, h, l);
  bh[idx] = h;
  bl[idx] = l;
}

// ---------------- pack conv weights (layers 2/3), split hi/lo --------------
template <int CIN, int COUT>
__global__ __launch_bounds__(256) void pack_w_kernel(
    const float* __restrict__ w, unsigned short* __restrict__ bph,
    unsigned short* __restrict__ bpl) {
  constexpr int K = CIN * 9;
  constexpr int CC = CIN / 32;
  const int n = blockIdx.x, br = blockIdx.z;
  const int t = threadIdx.x;
  __shared__ float row[K];
  const float* src = w + ((size_t)br * COUT + n) * K;
  for (int i = t; i < K; i += 256) row[i] = src[i];
  __syncthreads();
  for (int i = t; i < K; i += 256) {
    int kpos = i / CIN;
    int e = i - kpos * CIN;
    float f = row[e * 9 + kpos];
    unsigned short h, l;
    bsplit(f, h, l);
    size_t oidx =
        (((size_t)br * 9 * CC + (size_t)kpos * CC + (e >> 5)) * COUT + n) * 32 +
        (e & 31);
    bph[oidx] = h;
    bpl[oidx] = l;
  }
}

// ---------------- Layer 1: MFMA split-bf16 conv, tiered select, flags ------
__global__ __launch_bounds__(256) void layer1_kernel(
    const float* __restrict__ x, const unsigned short* __restrict__ bw1h,
    const unsigned short* __restrict__ bw1l, const float* __restrict__ sw2v,
    const float* __restrict__ tri, float* __restrict__ a1,
    char* __restrict__ zf1) {
  const int gidx = blockIdx.x;  // 12x12 tiles
  const int gy = gidx / 12, gx = gidx % 12;
  const int n = blockIdx.y, br = blockIdx.z;
  const int t = threadIdx.x;
  const int lane = t & 63, wid = t >> 6;

  __shared__ __align__(16) float win[12][12];
  __shared__ float sp2s[64];
  __shared__ float sw2s[64];
  __shared__ __align__(16) float dmat[64][68];

  const int y0 = gy * 8 - 2, x0 = gx * 8 - 2;
  const float* xb = x + ((size_t)(n * 3 + br)) * 96 * 96;
  if (t < 144) {
    int wy = t / 12, wx = t - (t / 12) * 12;
    int y = y0 + wy, xx = x0 + wx;
    float v = 0.f;
    if (y >= 0 && y < 96 && xx >= 0 && xx < 96) v = xb[y * 96 + xx];
    win[wy][wx] = v;
  }
  if (t >= 192) sw2s[t - 192] = sw2v[br * 64 + (t - 192)];
  __syncthreads();

  if (t < 64) {
    int py = t >> 3, px = t & 7;
    float s = 0.f;
#pragma unroll
    for (int ky = 0; ky < 5; ky++)
#pragma unroll
      for (int kx = 0; kx < 5; kx++) {
        float v = win[py + ky][px + kx];
        s += v * v;
      }
    sp2s[t] = s;
  }

  const int mrow = lane & 15;
  const int slot = lane >> 4;
  const int pixel = wid * 16 + mrow;
  const int ppy = pixel >> 3, ppx = pixel & 7;
  unsigned short ahv[8], alv[8];
#pragma unroll
  for (int j = 0; j < 8; j++) {
    int k = slot * 8 + j;
    float v = 0.f;
    if (k < 25) {
      int ky = (k * 205) >> 10;
      int kx = k - ky * 5;
      v = win[ppy + ky][ppx + kx];
    }
    bsplit(v, ahv[j], alv[j]);
  }
  bf16x8 ah = *reinterpret_cast<bf16x8*>(ahv);
  bf16x8 al = *reinterpret_cast<bf16x8*>(alv);

  f32x4 acc[4];
  f32x4 zz = {0.f, 0.f, 0.f, 0.f};
#pragma unroll
  for (int nt = 0; nt < 4; nt++) acc[nt] = zz;
#pragma unroll
  for (int nt = 0; nt < 4; nt++) {
    const int off = ((br * 64 + nt * 16 + mrow) << 5) + (slot << 3);
    bf16x8 bh = *reinterpret_cast<const bf16x8*>(bw1h + off);
    bf16x8 bl = *reinterpret_cast<const bf16x8*>(bw1l + off);
    acc[nt] = __builtin_amdgcn_mfma_f32_16x16x32_bf16(ah, bh, acc[nt], 0, 0, 0);
    acc[nt] = __builtin_amdgcn_mfma_f32_16x16x32_bf16(ah, bl, acc[nt], 0, 0, 0);
    acc[nt] = __builtin_amdgcn_mfma_f32_16x16x32_bf16(al, bh, acc[nt], 0, 0, 0);
  }
  __syncthreads();

  const float w_ = tri[br * 3 + 0];
  const float w2_ = w_ * w_;
  const int flidx = ((br * 16 + n) * 48 + gy * 4 + wid) * 12 + gx;

  float d2v[4][4];
#pragma unroll
  for (int nt = 0; nt < 4; nt++) {
    const float swc = sw2s[nt * 16 + mrow];
#pragma unroll
    for (int rg = 0; rg < 4; rg++)
      d2v[nt][rg] = sp2s[wid * 16 + slot * 4 + rg] + swc - 2.f * acc[nt][rg];
  }

  int cnt_lt[4] = {0, 0, 0, 0};
#pragma unroll
  for (int rg = 0; rg < 4; rg++) {
#pragma unroll
    for (int nt = 0; nt < 4; nt++) {
      unsigned long long m = __ballot(d2v[nt][rg] < w2_);
      cnt_lt[rg] += __popcll((m >> (slot * 16)) & 0xFFFFull);
    }
  }

  const bool myzero = (cnt_lt[0] | cnt_lt[1] | cnt_lt[2] | cnt_lt[3]) == 0;
  if (__all(myzero)) {
    if (lane == 0) zf1[flidx] = 0;   // tile is exact zeros; skip stores
    return;
  }

  const float A2[2][2] = {{0.9f, 0.93f}, {0.96f, 0.99f}};
  const bool mycheap = cnt_lt[0] <= 32 && cnt_lt[1] <= 32 &&
                       cnt_lt[2] <= 32 && cnt_lt[3] <= 32;
  if (__all(mycheap)) {
#pragma unroll
    for (int nt = 0; nt < 4; nt++) {
      const int ch = nt * 16 + mrow;
#pragma unroll
      for (int rg = 0; rg < 4; rg++) {
        const int p = wid * 16 + slot * 4 + rg;
        float d2 = d2v[nt][rg];
        float a = (d2 < w2_) ? 1.f - sqrtf(fmaxf(d2, 1e-12f)) / w_ : 0.f;
        dmat[p][ch] = a;
      }
    }
#pragma unroll
    for (int g = 0; g < 4; g++) {
      float pooled = 0.f;
#pragma unroll
      for (int py = 0; py < 2; py++)
#pragma unroll
        for (int q = 0; q < 2; q++) {
          int pi = py * 8 + g * 2 + q;
          pooled += dmat[wid * 16 + pi][lane] * A2[py][q];
        }
      a1[((((size_t)(br * 16 + n)) * 48 + (gy * 4 + wid)) * 48 +
          (gx * 4 + g)) * 64 + lane] = pooled * 0.25f;
    }
    if (lane == 0) zf1[flidx] = 1;
    return;
  }

  // exact fallback
#pragma unroll
  for (int nt = 0; nt < 4; nt++) {
    const int ch = nt * 16 + mrow;
#pragma unroll
    for (int rg = 0; rg < 4; rg++) {
      const int p = wid * 16 + slot * 4 + rg;
      dmat[p][ch] = sqrtf(fmaxf(d2v[nt][rg], 1e-12f));
    }
  }
  float thrv[16];
  unsigned int need = 0;
#pragma unroll
  for (int i = 0; i < 16; i++) {
    float v = dmat[wid * 16 + i][lane];
    int cnt = __popcll(__ballot(v >= w_));
    if (cnt >= 32) thrv[i] = w_;
    else need |= (1u << i);
  }
  if (need) {
#pragma unroll
    for (int i = 0; i < 16; i++) {
      if (!((need >> i) & 1)) continue;
      unsigned int key = __float_as_uint(dmat[wid * 16 + i][lane]);
      unsigned int pre = 0;
      int rem = 31;
      for (int b = 30; b >= 0; --b) {
        unsigned int top = (pre >> b) | 1u;
        int cnt = __popcll(__ballot((key >> b) == top));
        if (cnt > rem) pre |= (1u << b);
        else rem -= cnt;
      }
      thrv[i] = __uint_as_float(pre);
    }
  }
#pragma unroll
  for (int g = 0; g < 4; g++) {
    float pooled = 0.f;
#pragma unroll
    for (int py = 0; py < 2; py++)
#pragma unroll
      for (int q = 0; q < 2; q++) {
        int pi = py * 8 + g * 2 + q;
        float d = dmat[wid * 16 + pi][lane];
        float th = fminf(thrv[pi], w_);
        float a = 1.f - ((d > th) ? w_ : d) / w_;
        pooled += a * A2[py][q];
      }
    a1[((((size_t)(br * 16 + n)) * 48 + (gy * 4 + wid)) * 48 + (gx * 4 + g)) *
           64 + lane] = pooled * 0.25f;
  }
  if (lane == 0) zf1[flidx] = 1;
}

// ---------------- Layer 2: flag-gated MFMA RBF conv ------------------------
// flag2[tile]==0 means "tile == po0_2[br][:] exactly" (zero window).
__global__ __launch_bounds__(256) void rbf_l2(
    const float* __restrict__ a1, const unsigned short* __restrict__ bph,
    const unsigned short* __restrict__ bpl, const float* __restrict__ sw2v,
    const float* __restrict__ tri, const char* __restrict__ zf1,
    char* __restrict__ zf2, float* __restrict__ a2) {
  constexpr int CIN = 64, COUT = 128, HIN = 48, KRANK = 63;
  constexpr int CC = CIN / 32, NCH = 9 * CC, NTW = 2, PADC = COUT + 4;
  constexpr int WIN_USH = 60 * CIN;
  constexpr int WIN_BYTES = 2 * WIN_USH * 2;
  constexpr int DMAT_BYTES = 32 * PADC * 4;
  constexpr int UNI_BYTES = WIN_BYTES > DMAT_BYTES ? WIN_BYTES : DMAT_BYTES;

  __shared__ __align__(16) char uni[UNI_BYTES];
  __shared__ float cellq[60][4];
  __shared__ float cellsum[60];
  __shared__ float sp2[32];
  __shared__ float thrs[32];
  __shared__ float sw2s[COUT];
  __shared__ char fl[24];
  __shared__ int anyf, zflag;

  unsigned short* winh = (unsigned short*)uni;
  unsigned short* winl = winh + WIN_USH;
  float* dmat = (float*)uni;

  const int gy = blockIdx.x / 6, gx = blockIdx.x % 6;
  const int n = blockIdx.y, br = blockIdx.z;
  const int t = threadIdx.x, lane = t & 63, wvid = t >> 6, ng = wvid;
  const float w_ = tri[br * 3 + 1];
  const int y0 = gy * 4 - 1, x0 = gx * 8 - 1;
  const int fbase = ((br * 16 + n) * 12 + gy) * 6 + gx;

  if (t < 24) {
    int i = t >> 2, j = t & 3;
    int r = gy * 4 - 1 + i, ct = 2 * gx - 1 + j;
    fl[t] = (r >= 0 && r < 48 && ct >= 0 && ct < 12)
                ? zf1[((br * 16 + n) * 48 + r) * 12 + ct]
                : (char)0;
  }
  __syncthreads();
  if (t == 0) {
    int a = 0;
    for (int i = 0; i < 24; i++) a |= fl[i];
    anyf = a;
  }
  __syncthreads();
  if (!anyf) {
    if (t == 0) zf2[fbase] = 0;
    return;
  }

  for (int i = t; i < COUT; i += 256) sw2s[i] = sw2v[br * COUT + i];

  const int cell = t >> 2, q = t & 3;
  const int wy = cell / 10, wx = cell - (cell / 10) * 10;
  const int yy = y0 + wy, xx = x0 + wx;
  bool ok = false;
  if (t < 240 && yy >= 0 && yy < HIN && xx >= 0 && xx < HIN)
    ok = fl[wy * 4 + ((xx >> 2) - (2 * gx - 1))] != 0;
  if (t < 240) {
    const float* rp =
        a1 + ((size_t)((br * 16 + n) * HIN + yy) * HIN + xx) * CIN +
        q * (CIN / 4);
    const int sx = (wx & 7) << 3;
    float ss = 0.f;
#pragma unroll
    for (int cq = 0; cq < CIN / 16; cq++) {
      float4 v = ok ? *reinterpret_cast<const float4*>(rp + cq * 4)
                    : make_float4(0.f, 0.f, 0.f, 0.f);
      unsigned short hh[4], ll[4];
      float fv[4] = {v.x, v.y, v.z, v.w};
#pragma unroll
      for (int j = 0; j < 4; j++) {
        float f = fv[j];
        ss += f * f;
        bsplit(f, hh[j], ll[j]);
      }
      int c = q * (CIN / 4) + cq * 4;
      int cst = c ^ sx;
      *reinterpret_cast<ushort4*>(&winh[cell * CIN + cst]) =
          make_ushort4(hh[0], hh[1], hh[2], hh[3]);
      *reinterpret_cast<ushort4*>(&winl[cell * CIN + cst]) =
          make_ushort4(ll[0], ll[1], ll[2], ll[3]);
    }
    cellq[cell][q] = ss;
  }
  __syncthreads();
  if (t < 60)
    cellsum[t] = cellq[t][0] + cellq[t][1] + cellq[t][2] + cellq[t][3];
  __syncthreads();
  if (t < 32) {
    int py = t >> 3, px = t & 7;
    float s = 0.f;
#pragma unroll
    for (int ky = 0; ky < 3; ky++)
#pragma unroll
      for (int kx = 0; kx < 3; kx++) s += cellsum[(py + ky) * 10 + px + kx];
    sp2[t] = s;
  }
  if (t == 0) {
    float s = 0.f;
    for (int i = 0; i < 60; i++) s += cellsum[i];
    zflag = (s == 0.f);
  }
  __syncthreads();
  if (zflag) {
    if (t == 0) zf2[fbase] = 0;
    return;
  }

  // ---- conv: reg-dbuf B pipeline, 3-term split ---------------------------
  const int pix0 = lane & 15;
  const int g8 = (lane >> 4) << 3;
  const int ppy = pix0 >> 3, ppx = pix0 & 7;

  f32x4 acc[2][NTW];
  f32x4 zz = {0.f, 0.f, 0.f, 0.f};
#pragma unroll
  for (int mt = 0; mt < 2; mt++)
#pragma unroll
    for (int nt = 0; nt < NTW; nt++) acc[mt][nt] = zz;

  const size_t bbase = (size_t)br * NCH;
  const int nb0 = ng * (NTW * 16) + pix0;
  bf16x8 bufA[2 * NTW], bufB[2 * NTW];

  auto loadB = [&](int chunk, bf16x8* dst) {
    const unsigned short* p0 = bph + ((bbase + chunk) * COUT + nb0) * 32 + g8;
    const unsigned short* p1 = bpl + ((bbase + chunk) * COUT + nb0) * 32 + g8;
#pragma unroll
    for (int nt = 0; nt < NTW; nt++) {
      dst[2 * nt] = *reinterpret_cast<const bf16x8*>(p0 + nt * 512);
      dst[2 * nt + 1] = *reinterpret_cast<const bf16x8*>(p1 + nt * 512);
    }
  };
  auto compute = [&](int chunk, bf16x8* b) {
    const int kpos = chunk / CC, cc = chunk - (chunk / CC) * CC;
    const int ky = kpos / 3, kx = kpos - (kpos / 3) * 3;
    const int wxx = ppx + kx;
    const int sx = (wxx & 7) << 3;
    const int cbase = ((cc << 5) + g8) ^ sx;
#pragma unroll
    for (int mt = 0; mt < 2; mt++) {
      const int r0 = (mt * 2 + ppy + ky) * 10 + wxx;
      bf16x8 ah = *reinterpret_cast<const bf16x8*>(&winh[r0 * CIN + cbase]);
      bf16x8 al = *reinterpret_cast<const bf16x8*>(&winl[r0 * CIN + cbase]);
#pragma unroll
      for (int nt = 0; nt < NTW; nt++) {
        acc[mt][nt] = __builtin_amdgcn_mfma_f32_16x16x32_bf16(
            ah, b[2 * nt], acc[mt][nt], 0, 0, 0);
        acc[mt][nt] = __builtin_amdgcn_mfma_f32_16x16x32_bf16(
            ah, b[2 * nt + 1], acc[mt][nt], 0, 0, 0);
        acc[mt][nt] = __builtin_amdgcn_mfma_f32_16x16x32_bf16(
            al, b[2 * nt], acc[mt][nt], 0, 0, 0);
      }
    }
  };

  loadB(0, bufA);
  for (int ch = 0; ch < NCH; ch += 2) {
    loadB(ch + 1, bufB);
    compute(ch, bufA);
    if (ch + 2 < NCH) loadB(ch + 2, bufA);
    compute(ch + 1, bufB);
  }
  __syncthreads();

  const int rgrp = (lane >> 4) << 2;
#pragma unroll
  for (int mt = 0; mt < 2; mt++) {
    const int prow = mt * 16 + rgrp;
#pragma unroll
    for (int nt = 0; nt < NTW; nt++) {
      const int col = ng * (NTW * 16) + nt * 16 + pix0;
      const float sw = sw2s[col];
#pragma unroll
      for (int rg = 0; rg < 4; rg++) {
        const int pix = prow + rg;
        float d2 = sp2[pix] + sw - 2.f * acc[mt][nt][rg];
        dmat[pix * PADC + col] = sqrtf(fmaxf(d2, 1e-12f));
      }
    }
  }
  __syncthreads();

  for (int i = 0; i < 8; i++) {
    const int p = wvid * 8 + i;
    float2 f = *reinterpret_cast<const float2*>(&dmat[p * PADC + lane * 2]);
    float v0 = f.x, v1 = f.y;
    int cnt = __popcll(__ballot(v0 >= w_)) + __popcll(__ballot(v1 >= w_));
    if (cnt > KRANK) {
      if (lane == 0) thrs[p] = w_;
      continue;
    }
    unsigned int k0 = __float_as_uint(v0), k1 = __float_as_uint(v1);
    unsigned int pre = 0;
    int rem = KRANK;
    for (int b = 30; b >= 0; --b) {
      unsigned int top = (pre >> b) | 1u;
      int c = __popcll(__ballot((k0 >> b) == top)) +
              __popcll(__ballot((k1 >> b) == top));
      if (c > rem) pre |= (1u << b);
      else rem -= c;
    }
    if (lane == 0) thrs[p] = __uint_as_float(pre);
  }
  __syncthreads();

  float* ob = a2 + ((size_t)(br * 16 + n)) * 24 * 24 * COUT;
  for (int i = t; i < 8 * COUT; i += 256) {
    int qq = i / COUT;
    int chn = i - qq * COUT;
    int qy = qq >> 2, qx = qq & 3;
    int p00 = qy * 16 + qx * 2;
    float d00 = dmat[p00 * PADC + chn];
    float d01 = dmat[(p00 + 1) * PADC + chn];
    float d10 = dmat[(p00 + 8) * PADC + chn];
    float d11 = dmat[(p00 + 9) * PADC + chn];
    float t00 = fminf(thrs[p00], w_);
    float t01 = fminf(thrs[p00 + 1], w_);
    float t10 = fminf(thrs[p00 + 8], w_);
    float t11 = fminf(thrs[p00 + 9], w_);
    float a00 = 1.f - ((d00 > t00) ? w_ : d00) / w_;
    float a01 = 1.f - ((d01 > t01) ? w_ : d01) / w_;
    float a10 = 1.f - ((d10 > t10) ? w_ : d10) / w_;
    float a11 = 1.f - ((d11 > t11) ? w_ : d11) / w_;
    float po = 0.25f * (a00 * 0.9f + a01 * 0.93f + a10 * 0.96f + a11 * 0.99f);
    ob[((size_t)((gy * 2 + qy) * 24 + gx * 4 + qx)) * COUT + chn] = po;
  }
  if (t == 0) zf2[fbase] = 1;
}

// ---------------- Layer 3: flag-gated, po0-substituting, bf16 feats out ----
__global__ __launch_bounds__(256) void rbf_l3(
    const float* __restrict__ a2, const unsigned short* __restrict__ bph,
    const unsigned short* __restrict__ bpl, const float* __restrict__ sw2v,
    const float* __restrict__ tri, const char* __restrict__ zf2,
    const float* __restrict__ po0_2, const float* __restrict__ sp0_2,
    const float* __restrict__ act0_3, unsigned short* __restrict__ fT) {
  constexpr int CIN = 128, COUT = 256, HIN = 24, KRANK = 152;
  constexpr int CC = CIN / 32, NCH = 9 * CC, NTW = 4, PADC = COUT + 4;
  constexpr int WIN_USH = 60 * CIN;
  constexpr int WIN_BYTES = 2 * WIN_USH * 2;
  constexpr int DMAT_BYTES = 32 * PADC * 4;
  constexpr int UNI_BYTES = WIN_BYTES > DMAT_BYTES ? WIN_BYTES : DMAT_BYTES;

  __shared__ __align__(16) char uni[UNI_BYTES];
  __shared__ float cellq[60][4];
  __shared__ float cellsum[60];
  __shared__ float sp2[32];
  __shared__ float thrs[32];
  __shared__ float sw2s[COUT];
  __shared__ __align__(16) float po0s[128];
  __shared__ char fl[16];
  __shared__ int pure0, zflag;

  unsigned short* winh = (unsigned short*)uni;
  unsigned short* winl = winh + WIN_USH;
  float* dmat = (float*)uni;

  const int gy = blockIdx.x / 3, gx = blockIdx.x % 3;
  const int n = blockIdx.y, br = blockIdx.z;
  const int t = threadIdx.x, lane = t & 63, wvid = t >> 6, ng = wvid;
  const float w_ = tri[br * 3 + 2];
  const int y0 = gy * 4 - 1, x0 = gx * 8 - 1;
  const float sp0 = sp0_2[br];

  if (t < 16) {
    int i = t >> 2, j = t & 3;
    int tr = 2 * gy - 1 + i, tc = 2 * gx - 1 + j;
    fl[t] = (tr >= 0 && tr < 12 && tc >= 0 && tc < 6)
                ? zf2[((br * 16 + n) * 12 + tr) * 6 + tc]
                : (char)0;
  }
  if (t >= 64 && t < 192) po0s[t - 64] = po0_2[br * 128 + (t - 64)];
  __syncthreads();
  if (t == 0) {
    int a = 0;
    for (int i = 0; i < 16; i++) a |= fl[i];
    pure0 = (!a) && (sp0 == 0.f);
  }
  __syncthreads();

  unsigned short* obT = fT + (size_t)(br * 16 + n) * 256 * 576;
  if (pure0) {
    // window == 0 exactly: stream act0 constants (bf16)
    int col = t;  // 256 threads = 256 cols
    float a = act0_3[br * 256 + col];
    unsigned short h, l;
    bsplit(a, h, l);
    unsigned int hh = (unsigned int)h | ((unsigned int)h << 16);
    uint4 hv = {hh, hh, hh, hh};
#pragma unroll
    for (int row = 0; row < 4; row++)
      *reinterpret_cast<uint4*>(obT + (size_t)col * 576 +
                                (gy * 4 + row) * 24 + gx * 8) = hv;
    return;
  }

  for (int i = t; i < COUT; i += 256) sw2s[i] = sw2v[br * COUT + i];

  const int cell = t >> 2, q = t & 3;
  const int wy = cell / 10, wx = cell - (cell / 10) * 10;
  const int yy = y0 + wy, xx = x0 + wx;
  const bool okb =
      (t < 240) && (yy >= 0 && yy < HIN && xx >= 0 && xx < HIN);
  int fcell = 0;
  if (okb)
    fcell = fl[((yy >> 1) - (2 * gy - 1)) * 4 + ((xx >> 2) - (2 * gx - 1))];
  if (t < 240) {
    const float* rp =
        a2 + ((size_t)((br * 16 + n) * HIN + yy) * HIN + xx) * CIN +
        q * (CIN / 4);
    const int sx = (wx & 7) << 3;
    float ss = 0.f;
#pragma unroll
    for (int cq = 0; cq < CIN / 16; cq++) {
      int c = q * (CIN / 4) + cq * 4;
      float4 v;
      if (!okb) v = make_float4(0.f, 0.f, 0.f, 0.f);
      else if (!fcell) v = *reinterpret_cast<const float4*>(&po0s[c]);
      else v = *reinterpret_cast<const float4*>(rp + cq * 4);
      unsigned short hh[4], ll[4];
      float fv[4] = {v.x, v.y, v.z, v.w};
#pragma unroll
      for (int j = 0; j < 4; j++) {
        float f = fv[j];
        ss += f * f;
        bsplit(f, hh[j], ll[j]);
      }
      int cst = c ^ sx;
      *reinterpret_cast<ushort4*>(&winh[cell * CIN + cst]) =
          make_ushort4(hh[0], hh[1], hh[2], hh[3]);
      *reinterpret_cast<ushort4*>(&winl[cell * CIN + cst]) =
          make_ushort4(ll[0], ll[1], ll[2], ll[3]);
    }
    cellq[cell][q] = ss;
  }
  __syncthreads();
  if (t < 60)
    cellsum[t] = cellq[t][0] + cellq[t][1] + cellq[t][2] + cellq[t][3];
  __syncthreads();
  if (t < 32) {
    int py = t >> 3, px = t & 7;
    float s = 0.f;
#pragma unroll
    for (int ky = 0; ky < 3; ky++)
#pragma unroll
      for (int kx = 0; kx < 3; kx++) s += cellsum[(py + ky) * 10 + px + kx];
    sp2[t] = s;
  }
  if (t == 0) {
    float s = 0.f;
    for (int i = 0; i < 60; i++) s += cellsum[i];
    zflag = (s == 0.f);
  }
  __syncthreads();
  if (zflag) {
    int col = t;
    float a = act0_3[br * 256 + col];
    unsigned short h, l;
    bsplit(a, h, l);
    unsigned int hh = (unsigned int)h | ((unsigned int)h << 16);
    uint4 hv = {hh, hh, hh, hh};
#pragma unroll
    for (int row = 0; row < 4; row++)
      *reinterpret_cast<uint4*>(obT + (size_t)col * 576 +
                                (gy * 4 + row) * 24 + gx * 8) = hv;
    return;
  }

  // ---- conv ----
  const int pix0 = lane & 15;
  const int g8 = (lane >> 4) << 3;
  const int ppy = pix0 >> 3, ppx = pix0 & 7;

  f32x4 acc[2][NTW];
  f32x4 zz = {0.f, 0.f, 0.f, 0.f};
#pragma unroll
  for (int mt = 0; mt < 2; mt++)
#pragma unroll
    for (int nt = 0; nt < NTW; nt++) acc[mt][nt] = zz;

  const size_t bbase = (size_t)br * NCH;
  const int nb0 = ng * (NTW * 16) + pix0;
  bf16x8 bufA[2 * NTW], bufB[2 * NTW];

  auto loadB = [&](int chunk, bf16x8* dst) {
    const unsigned short* p0 = bph + ((bbase + chunk) * COUT + nb0) * 32 + g8;
    const unsigned short* p1 = bpl + ((bbase + chunk) * COUT + nb0) * 32 + g8;
#pragma unroll
    for (int nt = 0; nt < NTW; nt++) {
      dst[2 * nt] = *reinterpret_cast<const bf16x8*>(p0 + nt * 512);
      dst[2 * nt + 1] = *reinterpret_cast<const bf16x8*>(p1 + nt * 512);
    }
  };
  auto compute = [&](int chunk, bf16x8* b) {
    const int kpos = chunk / CC, cc = chunk - (chunk / CC) * CC;
    const int ky = kpos / 3, kx = kpos - (kpos / 3) * 3;
    const int wxx = ppx + kx;
    const int sx = (wxx & 7) << 3;
    const int cbase = ((cc << 5) + g8) ^ sx;
#pragma unroll
    for (int mt = 0; mt < 2; mt++) {
      const int r0 = (mt * 2 + ppy + ky) * 10 + wxx;
      bf16x8 ah = *reinterpret_cast<const bf16x8*>(&winh[r0 * CIN + cbase]);
      bf16x8 al = *reinterpret_cast<const bf16x8*>(&winl[r0 * CIN + cbase]);
#pragma unroll
      for (int nt = 0; nt < NTW; nt++) {
        acc[mt][nt] = __builtin_amdgcn_mfma_f32_16x16x32_bf16(
            ah, b[2 * nt], acc[mt][nt], 0, 0, 0);
        acc[mt][nt] = __builtin_amdgcn_mfma_f32_16x16x32_bf16(
            ah, b[2 * nt + 1], acc[mt][nt], 0, 0, 0);
        acc[mt][nt] = __builtin_amdgcn_mfma_f32_16x16x32_bf16(
            al, b[2 * nt], acc[mt][nt], 0, 0, 0);
      }
    }
  };

  loadB(0, bufA);
  for (int ch = 0; ch < NCH; ch += 2) {
    loadB(ch + 1, bufB);
    compute(ch, bufA);
    if (ch + 2 < NCH) loadB(ch + 2, bufA);
    compute(ch + 1, bufB);
  }
  __syncthreads();

  const int rgrp = (lane >> 4) << 2;
#pragma unroll
  for (int mt = 0; mt < 2; mt++) {
    const int prow = mt * 16 + rgrp;
#pragma unroll
    for (int nt = 0; nt < NTW; nt++) {
      const int col = ng * (NTW * 16) + nt * 16 + pix0;
      const float sw = sw2s[col];
#pragma unroll
      for (int rg = 0; rg < 4; rg++) {
        const int pix = prow + rg;
        float d2 = sp2[pix] + sw - 2.f * acc[mt][nt][rg];
        dmat[pix * PADC + col] = sqrtf(fmaxf(d2, 1e-12f));
      }
    }
  }
  __syncthreads();

  for (int i = 0; i < 8; i++) {
    const int p = wvid * 8 + i;
    float4 f = *reinterpret_cast<const float4*>(&dmat[p * PADC + lane * 4]);
    float v0 = f.x, v1 = f.y, v2 = f.z, v3 = f.w;
    int cnt = __popcll(__ballot(v0 >= w_)) + __popcll(__ballot(v1 >= w_)) +
              __popcll(__ballot(v2 >= w_)) + __popcll(__ballot(v3 >= w_));
    if (cnt > KRANK) {
      if (lane == 0) thrs[p] = w_;
      continue;
    }
    unsigned int k0 = __float_as_uint(v0), k1 = __float_as_uint(v1);
    unsigned int k2 = __float_as_uint(v2), k3 = __float_as_uint(v3);
    unsigned int pre = 0;
    int rem = KRANK;
    for (int b = 30; b >= 0; --b) {
      unsigned int top = (pre >> b) | 1u;
      int c = __popcll(__ballot((k0 >> b) == top)) +
              __popcll(__ballot((k1 >> b) == top)) +
              __popcll(__ballot((k2 >> b) == top)) +
              __popcll(__ballot((k3 >> b) == top));
      if (c > rem) pre |= (1u << b);
      else rem -= c;
    }
    if (lane == 0) thrs[p] = __uint_as_float(pre);
  }
  __syncthreads();

  for (int item = t; item < 256 * 4; item += 256) {
    int chn = item & 255;
    int rowq = item >> 8;
    __align__(16) unsigned short hv[8];
#pragma unroll
    for (int px = 0; px < 8; px++) {
      int p = rowq * 8 + px;
      float d = dmat[p * PADC + chn];
      float tt = fminf(thrs[p], w_);
      float a = 1.f - ((d > tt) ? w_ : d) / w_;
      unsigned short h, l;
      bsplit(a, h, l);
      hv[px] = h;
    }
    *reinterpret_cast<uint4*>(obT + (size_t)chn * 576 +
                              (gy * 4 + rowq) * 24 + gx * 8) =
        *reinterpret_cast<uint4*>(hv);
  }
}

// ---------------- FC: split-K MFMA on bf16 feats ---------------------------
__global__ __launch_bounds__(64) void fc_mfma_kernel(
    const unsigned short* __restrict__ fT, const float* __restrict__ fcw,
    float* __restrict__ partial) {
  const int blk = blockIdx.x;  // 1728 blocks, 256 k each (8 chunks of 32)
  const int lane = threadIdx.x;
  const int mrow = lane & 15;
  const int slot = lane >> 4;
  const int slot8 = slot * 8;
  const int k0base = blk * 256;

  f32x4 acc = {0.f, 0.f, 0.f, 0.f};
  float4 z4 = make_float4(0.f, 0.f, 0.f, 0.f);
  for (int cc = 0; cc < 8; ++cc) {
    int k0 = k0base + cc * 32;
    int br = k0 / 147456;
    int rb = k0 - br * 147456;
    int c = rb / 576;
    int pth = rb - c * 576;
    size_t aoff = ((size_t)(br * 16 + mrow) * 256 + c) * 576 + pth + slot8;
    bf16x8 ah = *reinterpret_cast<const bf16x8*>(fT + aoff);
    float4 b0 = z4, b1q = z4;
    if (mrow < 10) {
      const float* bp = fcw + (size_t)mrow * 442368 + k0 + slot8;
      b0 = *reinterpret_cast<const float4*>(bp);
      b1q = *reinterpret_cast<const float4*>(bp + 4);
    }
    float bf[8] = {b0.x, b0.y, b0.z, b0.w, b1q.x, b1q.y, b1q.z, b1q.w};
    unsigned short bhv[8], blv[8];
#pragma unroll
    for (int j = 0; j < 8; j++) bsplit(bf[j], bhv[j], blv[j]);
    bf16x8 bh = *reinterpret_cast<bf16x8*>(bhv);
    bf16x8 bl = *reinterpret_cast<bf16x8*>(blv);
    acc = __builtin_amdgcn_mfma_f32_16x16x32_bf16(ah, bh, acc, 0, 0, 0);
    acc = __builtin_amdgcn_mfma_f32_16x16x32_bf16(ah, bl, acc, 0, 0, 0);
  }
#pragma unroll
  for (int rg = 0; rg < 4; rg++)
    partial[(size_t)blk * 256 + (slot * 4 + rg) * 16 + mrow] = acc[rg];
}

__global__ __launch_bounds__(64) void fc_final_kernel(
    const float* __restrict__ partial, const float* __restrict__ fcb,
    float* __restrict__ outp) {
  const int n = blockIdx.x / 10, oo = blockIdx.x % 10;
  const int lane = threadIdx.x;
  float s = 0.f;
  for (int b = lane; b < 1728; b += 64)
    s += partial[(size_t)b * 256 + n * 16 + oo];
#pragma unroll
  for (int off = 32; off > 0; off >>= 1) s += __shfl_down(s, off, 64);
  if (lane == 0) outp[n * 10 + oo] = s + fcb[oo];
}

// ---------------------------------------------------------------------------
extern "C" void kernel_launch(void* const* d_in, const int* in_sizes, int n_in,
                              void* d_out, int out_size, void* d_ws,
                              size_t ws_size, hipStream_t stream) {
  const float* x   = (const float*)d_in[0];
  const float* w1  = (const float*)d_in[1];
  const float* w2  = (const float*)d_in[2];
  const float* w3  = (const float*)d_in[3];
  const float* tri = (const float*)d_in[4];
  const float* fcw = (const float*)d_in[5];
  const float* fcb = (const float*)d_in[6];
  float* out = (float*)d_out;

  float* ws = (float*)d_ws;
  float* a1      = ws;                    // 7,077,888
  float* a2      = a1 + 7077888;          // 3,538,944
  float* s1      = a2 + 3538944;          // 192
  float* s2      = s1 + 192;              // 384
  float* s3      = s2 + 384;              // 768
  float* po0_2   = s3 + 768;              // 384
  float* sp0_2   = po0_2 + 384;           // 16
  float* act0_3  = sp0_2 + 16;            // 768
  float* partial = act0_3 + 768;          // 442,368
  unsigned short* fT   = (unsigned short*)(partial + 442368);  // 7,077,888
  unsigned short* bw1h = fT + 7077888;    // 6,144
  unsigned short* bw1l = bw1h + 6144;
  unsigned short* bph2 = bw1l + 6144;     // 221,184
  unsigned short* bpl2 = bph2 + 221184;
  unsigned short* bph3 = bpl2 + 221184;   // 884,736
  unsigned short* bpl3 = bph3 + 884736;
  char* zf1 = (char*)(bpl3 + 884736);     // 27,648
  char* zf2 = zf1 + 27648;                // 3,456

  sw2_kernel<<<dim3(336), dim3(256), 0, stream>>>(w1, w2, w3, s1, s2, s3);
  prep_kernel<<<dim3(3, 2), dim3(64), 0, stream>>>(s2, s3, tri, po0_2, sp0_2,
                                                   act0_3);
  pack_w1_kernel<<<dim3(24), dim3(256), 0, stream>>>(w1, bw1h, bw1l);
  pack_w_kernel<64, 128><<<dim3(128, 1, 3), dim3(256), 0, stream>>>(w2, bph2,
                                                                    bpl2);
  pack_w_kernel<128, 256><<<dim3(256, 1, 3), dim3(256), 0, stream>>>(w3, bph3,
                                                                     bpl3);

  layer1_kernel<<<dim3(144, 16, 3), dim3(256), 0, stream>>>(x, bw1h, bw1l, s1,
                                                            tri, a1, zf1);
  rbf_l2<<<dim3(72, 16, 3), dim3(256), 0, stream>>>(a1, bph2, bpl2, s2, tri,
                                                    zf1, zf2, a2);
  rbf_l3<<<dim3(18, 16, 3), dim3(256), 0, stream>>>(a2, bph3, bpl3, s3, tri,
                                                    zf2, po0_2, sp0_2, act0_3,
                                                    fT);
  fc_mfma_kernel<<<dim3(1728), dim3(64), 0, stream>>>(fT, fcw, partial);
  fc_final_kernel<<<dim3(160), dim3(64), 0, stream>>>(partial, fcb, out);
}

// Round 13
// 116.778 us; speedup vs baseline: 1.0512x; 1.0374x over previous
//
#include <hip/hip_runtime.h>
#include <hip/hip_bf16.h>
#include <math.h>

typedef __attribute__((ext_vector_type(8))) short bf16x8;
typedef __attribute__((ext_vector_type(4))) float f32x4;

__device__ __forceinline__ void bsplit(float f, unsigned short& h,
                                       unsigned short& l) {
  __hip_bfloat16 hb = __float2bfloat16(f);
  float hf = __bfloat162float(hb);
  __hip_bfloat16 lb = __float2bfloat16(f - hf);
  h = *reinterpret_cast<unsigned short*>(&hb);
  l = *reinterpret_cast<unsigned short*>(&lb);
}

// ---------------- |w|^2 per filter row: one wave per row -------------------
__global__ __launch_bounds__(256) void sw2_kernel(
    const float* __restrict__ w1, const float* __restrict__ w2,
    const float* __restrict__ w3,
    float* __restrict__ s1, float* __restrict__ s2, float* __restrict__ s3) {
  const int wid = blockIdx.x * 4 + (threadIdx.x >> 6);
  const int lane = threadIdx.x & 63;
  const float* r;
  float* dst;
  int len;
  if (wid < 192) {
    r = w1 + wid * 25; dst = s1 + wid; len = 25;
  } else if (wid < 576) {
    int u = wid - 192; r = w2 + u * 576; dst = s2 + u; len = 576;
  } else {
    int u = wid - 576; r = w3 + (size_t)u * 1152; dst = s3 + u; len = 1152;
  }
  float s = 0.f;
  for (int i = lane; i < len; i += 64) {
    float v = r[i];
    s += v * v;
  }
#pragma unroll
  for (int off = 32; off > 0; off >>= 1) s += __shfl_down(s, off, 64);
  if (lane == 0) *dst = s;
}

// ---------------- prep: zero-window constants for layers 2/3 ---------------
__global__ __launch_bounds__(64) void prep_kernel(
    const float* __restrict__ s2, const float* __restrict__ s3,
    const float* __restrict__ tri, float* __restrict__ po0_2,
    float* __restrict__ sp0_2, float* __restrict__ act0_3) {
  const int br = blockIdx.x, lay = blockIdx.y, lane = threadIdx.x;
  if (lay == 0) {
    const float w_ = tri[br * 3 + 1];
    float d0 = sqrtf(fmaxf(s2[br * 128 + lane * 2], 1e-12f));
    float d1 = sqrtf(fmaxf(s2[br * 128 + lane * 2 + 1], 1e-12f));
    int cnt = __popcll(__ballot(d0 >= w_)) + __popcll(__ballot(d1 >= w_));
    float thr;
    if (cnt > 63) {
      thr = w_;
    } else {
      unsigned int k0 = __float_as_uint(d0), k1 = __float_as_uint(d1);
      unsigned int pre = 0;
      int rem = 63;
      for (int b = 30; b >= 0; --b) {
        unsigned int top = (pre >> b) | 1u;
        int c = __popcll(__ballot((k0 >> b) == top)) +
                __popcll(__ballot((k1 >> b) == top));
        if (c > rem) pre |= (1u << b);
        else rem -= c;
      }
      thr = __uint_as_float(pre);
    }
    float th = fminf(thr, w_);
    float a0 = 1.f - ((d0 > th) ? w_ : d0) / w_;
    float a1v = 1.f - ((d1 > th) ? w_ : d1) / w_;
    float p0 = a0 * 0.945f, p1 = a1v * 0.945f;
    po0_2[br * 128 + lane * 2] = p0;
    po0_2[br * 128 + lane * 2 + 1] = p1;
    float ss = p0 * p0 + p1 * p1;
#pragma unroll
    for (int off = 32; off > 0; off >>= 1) ss += __shfl_down(ss, off, 64);
    if (lane == 0) sp0_2[br] = ss;
  } else {
    const float w_ = tri[br * 3 + 2];
    float d[4];
#pragma unroll
    for (int j = 0; j < 4; j++)
      d[j] = sqrtf(fmaxf(s3[br * 256 + lane * 4 + j], 1e-12f));
    int cnt = 0;
#pragma unroll
    for (int j = 0; j < 4; j++) cnt += __popcll(__ballot(d[j] >= w_));
    float thr;
    if (cnt > 152) {
      thr = w_;
    } else {
      unsigned int k[4];
#pragma unroll
      for (int j = 0; j < 4; j++) k[j] = __float_as_uint(d[j]);
      unsigned int pre = 0;
      int rem = 152;
      for (int b = 30; b >= 0; --b) {
        unsigned int top = (pre >> b) | 1u;
        int c = 0;
#pragma unroll
        for (int j = 0; j < 4; j++)
          c += __popcll(__ballot((k[j] >> b) == top));
        if (c > rem) pre |= (1u << b);
        else rem -= c;
      }
      thr = __uint_as_float(pre);
    }
    float th = fminf(thr, w_);
#pragma unroll
    for (int j = 0; j < 4; j++)
      act0_3[br * 256 + lane * 4 + j] = 1.f - ((d[j] > th) ? w_ : d[j]) / w_;
  }
}

// ---------------- pack w1 into B-fragment layout [br][col(64)][k(32)] ------
__global__ __launch_bounds__(256) void pack_w1_kernel(
    const float* __restrict__ w1, unsigned short* __restrict__ bh,
    unsigned short* __restrict__ bl) {
  int idx = blockIdx.x * 256 + threadIdx.x;
  if (idx >= 6144) return;
  int k = idx & 31;
  int col = (idx >> 5) & 63;
  int br = idx >> 11;
  float f = (k < 25) ? w1[(br * 64 + col) * 25 + k] : 0.f;
  unsigned short h, l;
  bsplit(f, h, l);
  bh[idx] = h;
  bl[idx] = l;
}

// ---------------- pack conv weights (layers 2/3), split hi/lo --------------
template <int CIN, int COUT>
__global__ __launch_bounds__(256) void pack_w_kernel(
    const float* __restrict__ w, unsigned short* __restrict__ bph,
    unsigned short* __restrict__ bpl) {
  constexpr int K = CIN * 9;
  constexpr int CC = CIN / 32;
  const int n = blockIdx.x, br = blockIdx.z;
  const int t = threadIdx.x;
  __shared__ float row[K];
  const float* src = w + ((size_t)br * COUT + n) * K;
  for (int i = t; i < K; i += 256) row[i] = src[i];
  __syncthreads();
  for (int i = t; i < K; i += 256) {
    int kpos = i / CIN;
    int e = i - kpos * CIN;
    float f = row[e * 9 + kpos];
    unsigned short h, l;
    bsplit(f, h, l);
    size_t oidx =
        (((size_t)br * 9 * CC + (size_t)kpos * CC + (e >> 5)) * COUT + n) * 32 +
        (e & 31);
    bph[oidx] = h;
    bpl[oidx] = l;
  }
}

// ---------------- Layer 1: MFMA conv, tiered select, VALUE-EXACT flags -----
// zf1[tile]==0 <=> all 64ch x 4 pool-cols of this (row, col-tile) are 0.
__global__ __launch_bounds__(256) void layer1_kernel(
    const float* __restrict__ x, const unsigned short* __restrict__ bw1h,
    const unsigned short* __restrict__ bw1l, const float* __restrict__ sw2v,
    const float* __restrict__ tri, float* __restrict__ a1,
    char* __restrict__ zf1) {
  const int gidx = blockIdx.x;  // 12x12 tiles
  const int gy = gidx / 12, gx = gidx % 12;
  const int n = blockIdx.y, br = blockIdx.z;
  const int t = threadIdx.x;
  const int lane = t & 63, wid = t >> 6;

  __shared__ __align__(16) float win[12][12];
  __shared__ float sp2s[64];
  __shared__ float sw2s[64];
  __shared__ __align__(16) float dmat[64][68];

  const int y0 = gy * 8 - 2, x0 = gx * 8 - 2;
  const float* xb = x + ((size_t)(n * 3 + br)) * 96 * 96;
  if (t < 144) {
    int wy = t / 12, wx = t - (t / 12) * 12;
    int y = y0 + wy, xx = x0 + wx;
    float v = 0.f;
    if (y >= 0 && y < 96 && xx >= 0 && xx < 96) v = xb[y * 96 + xx];
    win[wy][wx] = v;
  }
  if (t >= 192) sw2s[t - 192] = sw2v[br * 64 + (t - 192)];
  __syncthreads();

  if (t < 64) {
    int py = t >> 3, px = t & 7;
    float s = 0.f;
#pragma unroll
    for (int ky = 0; ky < 5; ky++)
#pragma unroll
      for (int kx = 0; kx < 5; kx++) {
        float v = win[py + ky][px + kx];
        s += v * v;
      }
    sp2s[t] = s;
  }

  const int mrow = lane & 15;
  const int slot = lane >> 4;
  const int pixel = wid * 16 + mrow;
  const int ppy = pixel >> 3, ppx = pixel & 7;
  unsigned short ahv[8], alv[8];
#pragma unroll
  for (int j = 0; j < 8; j++) {
    int k = slot * 8 + j;
    float v = 0.f;
    if (k < 25) {
      int ky = (k * 205) >> 10;
      int kx = k - ky * 5;
      v = win[ppy + ky][ppx + kx];
    }
    bsplit(v, ahv[j], alv[j]);
  }
  bf16x8 ah = *reinterpret_cast<bf16x8*>(ahv);
  bf16x8 al = *reinterpret_cast<bf16x8*>(alv);

  f32x4 acc[4];
  f32x4 zz = {0.f, 0.f, 0.f, 0.f};
#pragma unroll
  for (int nt = 0; nt < 4; nt++) acc[nt] = zz;
#pragma unroll
  for (int nt = 0; nt < 4; nt++) {
    const int off = ((br * 64 + nt * 16 + mrow) << 5) + (slot << 3);
    bf16x8 bh = *reinterpret_cast<const bf16x8*>(bw1h + off);
    bf16x8 bl = *reinterpret_cast<const bf16x8*>(bw1l + off);
    acc[nt] = __builtin_amdgcn_mfma_f32_16x16x32_bf16(ah, bh, acc[nt], 0, 0, 0);
    acc[nt] = __builtin_amdgcn_mfma_f32_16x16x32_bf16(ah, bl, acc[nt], 0, 0, 0);
    acc[nt] = __builtin_amdgcn_mfma_f32_16x16x32_bf16(al, bh, acc[nt], 0, 0, 0);
  }
  __syncthreads();

  const float w_ = tri[br * 3 + 0];
  const float w2_ = w_ * w_;
  const int flidx = ((br * 16 + n) * 48 + gy * 4 + wid) * 12 + gx;

  float d2v[4][4];
#pragma unroll
  for (int nt = 0; nt < 4; nt++) {
    const float swc = sw2s[nt * 16 + mrow];
#pragma unroll
    for (int rg = 0; rg < 4; rg++)
      d2v[nt][rg] = sp2s[wid * 16 + slot * 4 + rg] + swc - 2.f * acc[nt][rg];
  }

  int cnt_lt[4] = {0, 0, 0, 0};
#pragma unroll
  for (int rg = 0; rg < 4; rg++) {
#pragma unroll
    for (int nt = 0; nt < 4; nt++) {
      unsigned long long m = __ballot(d2v[nt][rg] < w2_);
      cnt_lt[rg] += __popcll((m >> (slot * 16)) & 0xFFFFull);
    }
  }

  const bool myzero = (cnt_lt[0] | cnt_lt[1] | cnt_lt[2] | cnt_lt[3]) == 0;
  if (__all(myzero)) {
    if (lane == 0) zf1[flidx] = 0;  // tile is exact zeros; skip stores
    return;
  }

  const float A2[2][2] = {{0.9f, 0.93f}, {0.96f, 0.99f}};
  const bool mycheap = cnt_lt[0] <= 32 && cnt_lt[1] <= 32 &&
                       cnt_lt[2] <= 32 && cnt_lt[3] <= 32;
  if (__all(mycheap)) {
#pragma unroll
    for (int nt = 0; nt < 4; nt++) {
      const int ch = nt * 16 + mrow;
#pragma unroll
      for (int rg = 0; rg < 4; rg++) {
        const int p = wid * 16 + slot * 4 + rg;
        float d2 = d2v[nt][rg];
        float a = (d2 < w2_) ? 1.f - sqrtf(fmaxf(d2, 1e-12f)) / w_ : 0.f;
        dmat[p][ch] = a;
      }
    }
    float pooled[4];
#pragma unroll
    for (int g = 0; g < 4; g++) {
      float po = 0.f;
#pragma unroll
      for (int py = 0; py < 2; py++)
#pragma unroll
        for (int q = 0; q < 2; q++) {
          int pi = py * 8 + g * 2 + q;
          po += dmat[wid * 16 + pi][lane] * A2[py][q];
        }
      pooled[g] = po * 0.25f;
    }
    // VALUE-EXACT flag: only mark (and store) when something is nonzero
    bool nz = (pooled[0] != 0.f) | (pooled[1] != 0.f) | (pooled[2] != 0.f) |
              (pooled[3] != 0.f);
    unsigned long long mm = __ballot(nz);
    if (mm) {
#pragma unroll
      for (int g = 0; g < 4; g++)
        a1[((((size_t)(br * 16 + n)) * 48 + (gy * 4 + wid)) * 48 +
            (gx * 4 + g)) * 64 + lane] = pooled[g];
      if (lane == 0) zf1[flidx] = 1;
    } else {
      if (lane == 0) zf1[flidx] = 0;
    }
    return;
  }

  // exact fallback
#pragma unroll
  for (int nt = 0; nt < 4; nt++) {
    const int ch = nt * 16 + mrow;
#pragma unroll
    for (int rg = 0; rg < 4; rg++) {
      const int p = wid * 16 + slot * 4 + rg;
      dmat[p][ch] = sqrtf(fmaxf(d2v[nt][rg], 1e-12f));
    }
  }
  float thrv[16];
  unsigned int need = 0;
#pragma unroll
  for (int i = 0; i < 16; i++) {
    float v = dmat[wid * 16 + i][lane];
    int cnt = __popcll(__ballot(v >= w_));
    if (cnt >= 32) thrv[i] = w_;
    else need |= (1u << i);
  }
  if (need) {
#pragma unroll
    for (int i = 0; i < 16; i++) {
      if (!((need >> i) & 1)) continue;
      unsigned int key = __float_as_uint(dmat[wid * 16 + i][lane]);
      unsigned int pre = 0;
      int rem = 31;
      for (int b = 30; b >= 0; --b) {
        unsigned int top = (pre >> b) | 1u;
        int cnt = __popcll(__ballot((key >> b) == top));
        if (cnt > rem) pre |= (1u << b);
        else rem -= cnt;
      }
      thrv[i] = __uint_as_float(pre);
    }
  }
  float pooled[4];
#pragma unroll
  for (int g = 0; g < 4; g++) {
    float po = 0.f;
#pragma unroll
    for (int py = 0; py < 2; py++)
#pragma unroll
      for (int q = 0; q < 2; q++) {
        int pi = py * 8 + g * 2 + q;
        float d = dmat[wid * 16 + pi][lane];
        float th = fminf(thrv[pi], w_);
        float a = 1.f - ((d > th) ? w_ : d) / w_;
        po += a * A2[py][q];
      }
    pooled[g] = po * 0.25f;
  }
  bool nz = (pooled[0] != 0.f) | (pooled[1] != 0.f) | (pooled[2] != 0.f) |
            (pooled[3] != 0.f);
  unsigned long long mm = __ballot(nz);
  if (mm) {
#pragma unroll
    for (int g = 0; g < 4; g++)
      a1[((((size_t)(br * 16 + n)) * 48 + (gy * 4 + wid)) * 48 +
          (gx * 4 + g)) * 64 + lane] = pooled[g];
    if (lane == 0) zf1[flidx] = 1;
  } else {
    if (lane == 0) zf1[flidx] = 0;
  }
}

// ---------------- Layer 2: flag-gated MFMA RBF conv ------------------------
// zf2[tile]==0 <=> tile == po0_2[br][:] exactly.
__global__ __launch_bounds__(256) void rbf_l2(
    const float* __restrict__ a1, const unsigned short* __restrict__ bph,
    const unsigned short* __restrict__ bpl, const float* __restrict__ sw2v,
    const float* __restrict__ tri, const char* __restrict__ zf1,
    const float* __restrict__ po0_2, char* __restrict__ zf2,
    float* __restrict__ a2) {
  constexpr int CIN = 64, COUT = 128, HIN = 48, KRANK = 63;
  constexpr int CC = CIN / 32, NCH = 9 * CC, NTW = 2, PADC = COUT + 4;
  constexpr int WIN_USH = 60 * CIN;
  constexpr int WIN_BYTES = 2 * WIN_USH * 2;
  constexpr int DMAT_BYTES = 32 * PADC * 4;
  constexpr int UNI_BYTES = WIN_BYTES > DMAT_BYTES ? WIN_BYTES : DMAT_BYTES;

  __shared__ __align__(16) char uni[UNI_BYTES];
  __shared__ float cellq[60][4];
  __shared__ float cellsum[60];
  __shared__ float sp2[32];
  __shared__ float thrs[32];
  __shared__ float sw2s[COUT];
  __shared__ float po0s[COUT];
  __shared__ char fl[24];
  __shared__ int anyf, zflag, diffl;

  unsigned short* winh = (unsigned short*)uni;
  unsigned short* winl = winh + WIN_USH;
  float* dmat = (float*)uni;

  const int gy = blockIdx.x / 6, gx = blockIdx.x % 6;
  const int n = blockIdx.y, br = blockIdx.z;
  const int t = threadIdx.x, lane = t & 63, wvid = t >> 6, ng = wvid;
  const float w_ = tri[br * 3 + 1];
  const int y0 = gy * 4 - 1, x0 = gx * 8 - 1;
  const int fbase = ((br * 16 + n) * 12 + gy) * 6 + gx;

  if (t < 24) {
    int i = t >> 2, j = t & 3;
    int r = gy * 4 - 1 + i, ct = 2 * gx - 1 + j;
    fl[t] = (r >= 0 && r < 48 && ct >= 0 && ct < 12)
                ? zf1[((br * 16 + n) * 48 + r) * 12 + ct]
                : (char)0;
  }
  if (t == 255) diffl = 0;
  __syncthreads();
  if (t == 0) {
    int a = 0;
    for (int i = 0; i < 24; i++) a |= fl[i];
    anyf = a;
  }
  __syncthreads();
  if (!anyf) {
    if (t == 0) zf2[fbase] = 0;
    return;
  }

  for (int i = t; i < COUT; i += 256) {
    sw2s[i] = sw2v[br * COUT + i];
    po0s[i] = po0_2[br * COUT + i];
  }

  const int cell = t >> 2, q = t & 3;
  const int wy = cell / 10, wx = cell - (cell / 10) * 10;
  const int yy = y0 + wy, xx = x0 + wx;
  bool ok = false;
  if (t < 240 && yy >= 0 && yy < HIN && xx >= 0 && xx < HIN)
    ok = fl[wy * 4 + ((xx >> 2) - (2 * gx - 1))] != 0;
  if (t < 240) {
    const float* rp =
        a1 + ((size_t)((br * 16 + n) * HIN + yy) * HIN + xx) * CIN +
        q * (CIN / 4);
    const int sx = (wx & 7) << 3;
    float ss = 0.f;
#pragma unroll
    for (int cq = 0; cq < CIN / 16; cq++) {
      float4 v = ok ? *reinterpret_cast<const float4*>(rp + cq * 4)
                    : make_float4(0.f, 0.f, 0.f, 0.f);
      unsigned short hh[4], ll[4];
      float fv[4] = {v.x, v.y, v.z, v.w};
#pragma unroll
      for (int j = 0; j < 4; j++) {
        float f = fv[j];
        ss += f * f;
        bsplit(f, hh[j], ll[j]);
      }
      int c = q * (CIN / 4) + cq * 4;
      int cst = c ^ sx;
      *reinterpret_cast<ushort4*>(&winh[cell * CIN + cst]) =
          make_ushort4(hh[0], hh[1], hh[2], hh[3]);
      *reinterpret_cast<ushort4*>(&winl[cell * CIN + cst]) =
          make_ushort4(ll[0], ll[1], ll[2], ll[3]);
    }
    cellq[cell][q] = ss;
  }
  __syncthreads();
  if (t < 60)
    cellsum[t] = cellq[t][0] + cellq[t][1] + cellq[t][2] + cellq[t][3];
  __syncthreads();
  if (t < 32) {
    int py = t >> 3, px = t & 7;
    float s = 0.f;
#pragma unroll
    for (int ky = 0; ky < 3; ky++)
#pragma unroll
      for (int kx = 0; kx < 3; kx++) s += cellsum[(py + ky) * 10 + px + kx];
    sp2[t] = s;
  }
  if (t == 0) {
    float s = 0.f;
    for (int i = 0; i < 60; i++) s += cellsum[i];
    zflag = (s == 0.f);
  }
  __syncthreads();
  if (zflag) {
    if (t == 0) zf2[fbase] = 0;
    return;
  }

  // ---- conv: reg-dbuf B pipeline, 3-term split ---------------------------
  const int pix0 = lane & 15;
  const int g8 = (lane >> 4) << 3;
  const int ppy = pix0 >> 3, ppx = pix0 & 7;

  f32x4 acc[2][NTW];
  f32x4 zz = {0.f, 0.f, 0.f, 0.f};
#pragma unroll
  for (int mt = 0; mt < 2; mt++)
#pragma unroll
    for (int nt = 0; nt < NTW; nt++) acc[mt][nt] = zz;

  const size_t bbase = (size_t)br * NCH;
  const int nb0 = ng * (NTW * 16) + pix0;
  bf16x8 bufA[2 * NTW], bufB[2 * NTW];

  auto loadB = [&](int chunk, bf16x8* dst) {
    const unsigned short* p0 = bph + ((bbase + chunk) * COUT + nb0) * 32 + g8;
    const unsigned short* p1 = bpl + ((bbase + chunk) * COUT + nb0) * 32 + g8;
#pragma unroll
    for (int nt = 0; nt < NTW; nt++) {
      dst[2 * nt] = *reinterpret_cast<const bf16x8*>(p0 + nt * 512);
      dst[2 * nt + 1] = *reinterpret_cast<const bf16x8*>(p1 + nt * 512);
    }
  };
  auto compute = [&](int chunk, bf16x8* b) {
    const int kpos = chunk / CC, cc = chunk - (chunk / CC) * CC;
    const int ky = kpos / 3, kx = kpos - (kpos / 3) * 3;
    const int wxx = ppx + kx;
    const int sx = (wxx & 7) << 3;
    const int cbase = ((cc << 5) + g8) ^ sx;
#pragma unroll
    for (int mt = 0; mt < 2; mt++) {
      const int r0 = (mt * 2 + ppy + ky) * 10 + wxx;
      bf16x8 ah = *reinterpret_cast<const bf16x8*>(&winh[r0 * CIN + cbase]);
      bf16x8 al = *reinterpret_cast<const bf16x8*>(&winl[r0 * CIN + cbase]);
#pragma unroll
      for (int nt = 0; nt < NTW; nt++) {
        acc[mt][nt] = __builtin_amdgcn_mfma_f32_16x16x32_bf16(
            ah, b[2 * nt], acc[mt][nt], 0, 0, 0);
        acc[mt][nt] = __builtin_amdgcn_mfma_f32_16x16x32_bf16(
            ah, b[2 * nt + 1], acc[mt][nt], 0, 0, 0);
        acc[mt][nt] = __builtin_amdgcn_mfma_f32_16x16x32_bf16(
            al, b[2 * nt], acc[mt][nt], 0, 0, 0);
      }
    }
  };

  loadB(0, bufA);
  for (int ch = 0; ch < NCH; ch += 2) {
    loadB(ch + 1, bufB);
    compute(ch, bufA);
    if (ch + 2 < NCH) loadB(ch + 2, bufA);
    compute(ch + 1, bufB);
  }
  __syncthreads();

  const int rgrp = (lane >> 4) << 2;
#pragma unroll
  for (int mt = 0; mt < 2; mt++) {
    const int prow = mt * 16 + rgrp;
#pragma unroll
    for (int nt = 0; nt < NTW; nt++) {
      const int col = ng * (NTW * 16) + nt * 16 + pix0;
      const float sw = sw2s[col];
#pragma unroll
      for (int rg = 0; rg < 4; rg++) {
        const int pix = prow + rg;
        float d2 = sp2[pix] + sw - 2.f * acc[mt][nt][rg];
        dmat[pix * PADC + col] = sqrtf(fmaxf(d2, 1e-12f));
      }
    }
  }
  __syncthreads();

  for (int i = 0; i < 8; i++) {
    const int p = wvid * 8 + i;
    float2 f = *reinterpret_cast<const float2*>(&dmat[p * PADC + lane * 2]);
    float v0 = f.x, v1 = f.y;
    int cnt = __popcll(__ballot(v0 >= w_)) + __popcll(__ballot(v1 >= w_));
    if (cnt > KRANK) {
      if (lane == 0) thrs[p] = w_;
      continue;
    }
    unsigned int k0 = __float_as_uint(v0), k1 = __float_as_uint(v1);
    unsigned int pre = 0;
    int rem = KRANK;
    for (int b = 30; b >= 0; --b) {
      unsigned int top = (pre >> b) | 1u;
      int c = __popcll(__ballot((k0 >> b) == top)) +
              __popcll(__ballot((k1 >> b) == top));
      if (c > rem) pre |= (1u << b);
      else rem -= c;
    }
    if (lane == 0) thrs[p] = __uint_as_float(pre);
  }
  __syncthreads();

  float* ob = a2 + ((size_t)(br * 16 + n)) * 24 * 24 * COUT;
  int mydiff = 0;
  for (int i = t; i < 8 * COUT; i += 256) {
    int qq = i / COUT;
    int chn = i - qq * COUT;
    int qy = qq >> 2, qx = qq & 3;
    int p00 = qy * 16 + qx * 2;
    float d00 = dmat[p00 * PADC + chn];
    float d01 = dmat[(p00 + 1) * PADC + chn];
    float d10 = dmat[(p00 + 8) * PADC + chn];
    float d11 = dmat[(p00 + 9) * PADC + chn];
    float t00 = fminf(thrs[p00], w_);
    float t01 = fminf(thrs[p00 + 1], w_);
    float t10 = fminf(thrs[p00 + 8], w_);
    float t11 = fminf(thrs[p00 + 9], w_);
    float a00 = 1.f - ((d00 > t00) ? w_ : d00) / w_;
    float a01 = 1.f - ((d01 > t01) ? w_ : d01) / w_;
    float a10 = 1.f - ((d10 > t10) ? w_ : d10) / w_;
    float a11 = 1.f - ((d11 > t11) ? w_ : d11) / w_;
    float po = 0.25f * (a00 * 0.9f + a01 * 0.93f + a10 * 0.96f + a11 * 0.99f);
    ob[((size_t)((gy * 2 + qy) * 24 + gx * 4 + qx)) * COUT + chn] = po;
    mydiff |= (po != po0s[chn]);
  }
  if (mydiff) diffl = 1;  // benign race: all writers store 1
  __syncthreads();
  if (t == 0) zf2[fbase] = diffl ? 1 : 0;
}

// ---------------- Layer 3: flag-gated, po0-substituting, bf16 feats out ----
__global__ __launch_bounds__(256) void rbf_l3(
    const float* __restrict__ a2, const unsigned short* __restrict__ bph,
    const unsigned short* __restrict__ bpl, const float* __restrict__ sw2v,
    const float* __restrict__ tri, const char* __restrict__ zf2,
    const float* __restrict__ po0_2, const float* __restrict__ sp0_2,
    const float* __restrict__ act0_3, unsigned short* __restrict__ fT) {
  constexpr int CIN = 128, COUT = 256, HIN = 24, KRANK = 152;
  constexpr int CC = CIN / 32, NCH = 9 * CC, NTW = 4, PADC = COUT + 4;
  constexpr int WIN_USH = 60 * CIN;
  constexpr int WIN_BYTES = 2 * WIN_USH * 2;
  constexpr int DMAT_BYTES = 32 * PADC * 4;
  constexpr int UNI_BYTES = WIN_BYTES > DMAT_BYTES ? WIN_BYTES : DMAT_BYTES;

  __shared__ __align__(16) char uni[UNI_BYTES];
  __shared__ float cellq[60][4];
  __shared__ float cellsum[60];
  __shared__ float sp2[32];
  __shared__ float thrs[32];
  __shared__ float sw2s[COUT];
  __shared__ __align__(16) float po0s[128];
  __shared__ char fl[16];
  __shared__ int pure0, zflag;

  unsigned short* winh = (unsigned short*)uni;
  unsigned short* winl = winh + WIN_USH;
  float* dmat = (float*)uni;

  const int gy = blockIdx.x / 3, gx = blockIdx.x % 3;
  const int n = blockIdx.y, br = blockIdx.z;
  const int t = threadIdx.x, lane = t & 63, wvid = t >> 6, ng = wvid;
  const float w_ = tri[br * 3 + 2];
  const int y0 = gy * 4 - 1, x0 = gx * 8 - 1;
  const float sp0 = sp0_2[br];

  if (t < 16) {
    int i = t >> 2, j = t & 3;
    int tr = 2 * gy - 1 + i, tc = 2 * gx - 1 + j;
    fl[t] = (tr >= 0 && tr < 12 && tc >= 0 && tc < 6)
                ? zf2[((br * 16 + n) * 12 + tr) * 6 + tc]
                : (char)0;
  }
  if (t >= 64 && t < 192) po0s[t - 64] = po0_2[br * 128 + (t - 64)];
  __syncthreads();
  if (t == 0) {
    int a = 0;
    for (int i = 0; i < 16; i++) a |= fl[i];
    pure0 = (!a) && (sp0 == 0.f);
  }
  __syncthreads();

  unsigned short* obT = fT + (size_t)(br * 16 + n) * 256 * 576;
  if (pure0) {
    int col = t;
    float a = act0_3[br * 256 + col];
    unsigned short h, l;
    bsplit(a, h, l);
    unsigned int hh = (unsigned int)h | ((unsigned int)h << 16);
    uint4 hv = {hh, hh, hh, hh};
#pragma unroll
    for (int row = 0; row < 4; row++)
      *reinterpret_cast<uint4*>(obT + (size_t)col * 576 +
                                (gy * 4 + row) * 24 + gx * 8) = hv;
    return;
  }

  for (int i = t; i < COUT; i += 256) sw2s[i] = sw2v[br * COUT + i];

  const int cell = t >> 2, q = t & 3;
  const int wy = cell / 10, wx = cell - (cell / 10) * 10;
  const int yy = y0 + wy, xx = x0 + wx;
  const bool okb =
      (t < 240) && (yy >= 0 && yy < HIN && xx >= 0 && xx < HIN);
  int fcell = 0;
  if (okb)
    fcell = fl[((yy >> 1) - (2 * gy - 1)) * 4 + ((xx >> 2) - (2 * gx - 1))];
  if (t < 240) {
    const float* rp =
        a2 + ((size_t)((br * 16 + n) * HIN + yy) * HIN + xx) * CIN +
        q * (CIN / 4);
    const int sx = (wx & 7) << 3;
    float ss = 0.f;
#pragma unroll
    for (int cq = 0; cq < CIN / 16; cq++) {
      int c = q * (CIN / 4) + cq * 4;
      float4 v;
      if (!okb) v = make_float4(0.f, 0.f, 0.f, 0.f);
      else if (!fcell) v = *reinterpret_cast<const float4*>(&po0s[c]);
      else v = *reinterpret_cast<const float4*>(rp + cq * 4);
      unsigned short hh[4], ll[4];
      float fv[4] = {v.x, v.y, v.z, v.w};
#pragma unroll
      for (int j = 0; j < 4; j++) {
        float f = fv[j];
        ss += f * f;
        bsplit(f, hh[j], ll[j]);
      }
      int cst = c ^ sx;
      *reinterpret_cast<ushort4*>(&winh[cell * CIN + cst]) =
          make_ushort4(hh[0], hh[1], hh[2], hh[3]);
      *reinterpret_cast<ushort4*>(&winl[cell * CIN + cst]) =
          make_ushort4(ll[0], ll[1], ll[2], ll[3]);
    }
    cellq[cell][q] = ss;
  }
  __syncthreads();
  if (t < 60)
    cellsum[t] = cellq[t][0] + cellq[t][1] + cellq[t][2] + cellq[t][3];
  __syncthreads();
  if (t < 32) {
    int py = t >> 3, px = t & 7;
    float s = 0.f;
#pragma unroll
    for (int ky = 0; ky < 3; ky++)
#pragma unroll
      for (int kx = 0; kx < 3; kx++) s += cellsum[(py + ky) * 10 + px + kx];
    sp2[t] = s;
  }
  if (t == 0) {
    float s = 0.f;
    for (int i = 0; i < 60; i++) s += cellsum[i];
    zflag = (s == 0.f);
  }
  __syncthreads();
  if (zflag) {
    int col = t;
    float a = act0_3[br * 256 + col];
    unsigned short h, l;
    bsplit(a, h, l);
    unsigned int hh = (unsigned int)h | ((unsigned int)h << 16);
    uint4 hv = {hh, hh, hh, hh};
#pragma unroll
    for (int row = 0; row < 4; row++)
      *reinterpret_cast<uint4*>(obT + (size_t)col * 576 +
                                (gy * 4 + row) * 24 + gx * 8) = hv;
    return;
  }

  // ---- conv ----
  const int pix0 = lane & 15;
  const int g8 = (lane >> 4) << 3;
  const int ppy = pix0 >> 3, ppx = pix0 & 7;

  f32x4 acc[2][NTW];
  f32x4 zz = {0.f, 0.f, 0.f, 0.f};
#pragma unroll
  for (int mt = 0; mt < 2; mt++)
#pragma unroll
    for (int nt = 0; nt < NTW; nt++) acc[mt][nt] = zz;

  const size_t bbase = (size_t)br * NCH;
  const int nb0 = ng * (NTW * 16) + pix0;
  bf16x8 bufA[2 * NTW], bufB[2 * NTW];

  auto loadB = [&](int chunk, bf16x8* dst) {
    const unsigned short* p0 = bph + ((bbase + chunk) * COUT + nb0) * 32 + g8;
    const unsigned short* p1 = bpl + ((bbase + chunk) * COUT + nb0) * 32 + g8;
#pragma unroll
    for (int nt = 0; nt < NTW; nt++) {
      dst[2 * nt] = *reinterpret_cast<const bf16x8*>(p0 + nt * 512);
      dst[2 * nt + 1] = *reinterpret_cast<const bf16x8*>(p1 + nt * 512);
    }
  };
  auto compute = [&](int chunk, bf16x8* b) {
    const int kpos = chunk / CC, cc = chunk - (chunk / CC) * CC;
    const int ky = kpos / 3, kx = kpos - (kpos / 3) * 3;
    const int wxx = ppx + kx;
    const int sx = (wxx & 7) << 3;
    const int cbase = ((cc << 5) + g8) ^ sx;
#pragma unroll
    for (int mt = 0; mt < 2; mt++) {
      const int r0 = (mt * 2 + ppy + ky) * 10 + wxx;
      bf16x8 ah = *reinterpret_cast<const bf16x8*>(&winh[r0 * CIN + cbase]);
      bf16x8 al = *reinterpret_cast<const bf16x8*>(&winl[r0 * CIN + cbase]);
#pragma unroll
      for (int nt = 0; nt < NTW; nt++) {
        acc[mt][nt] = __builtin_amdgcn_mfma_f32_16x16x32_bf16(
            ah, b[2 * nt], acc[mt][nt], 0, 0, 0);
        acc[mt][nt] = __builtin_amdgcn_mfma_f32_16x16x32_bf16(
            ah, b[2 * nt + 1], acc[mt][nt], 0, 0, 0);
        acc[mt][nt] = __builtin_amdgcn_mfma_f32_16x16x32_bf16(
            al, b[2 * nt], acc[mt][nt], 0, 0, 0);
      }
    }
  };

  loadB(0, bufA);
  for (int ch = 0; ch < NCH; ch += 2) {
    loadB(ch + 1, bufB);
    compute(ch, bufA);
    if (ch + 2 < NCH) loadB(ch + 2, bufA);
    compute(ch + 1, bufB);
  }
  __syncthreads();

  const int rgrp = (lane >> 4) << 2;
#pragma unroll
  for (int mt = 0; mt < 2; mt++) {
    const int prow = mt * 16 + rgrp;
#pragma unroll
    for (int nt = 0; nt < NTW; nt++) {
      const int col = ng * (NTW * 16) + nt * 16 + pix0;
      const float sw = sw2s[col];
#pragma unroll
      for (int rg = 0; rg < 4; rg++) {
        const int pix = prow + rg;
        float d2 = sp2[pix] + sw - 2.f * acc[mt][nt][rg];
        dmat[pix * PADC + col] = sqrtf(fmaxf(d2, 1e-12f));
      }
    }
  }
  __syncthreads();

  for (int i = 0; i < 8; i++) {
    const int p = wvid * 8 + i;
    float4 f = *reinterpret_cast<const float4*>(&dmat[p * PADC + lane * 4]);
    float v0 = f.x, v1 = f.y, v2 = f.z, v3 = f.w;
    int cnt = __popcll(__ballot(v0 >= w_)) + __popcll(__ballot(v1 >= w_)) +
              __popcll(__ballot(v2 >= w_)) + __popcll(__ballot(v3 >= w_));
    if (cnt > KRANK) {
      if (lane == 0) thrs[p] = w_;
      continue;
    }
    unsigned int k0 = __float_as_uint(v0), k1 = __float_as_uint(v1);
    unsigned int k2 = __float_as_uint(v2), k3 = __float_as_uint(v3);
    unsigned int pre = 0;
    int rem = KRANK;
    for (int b = 30; b >= 0; --b) {
      unsigned int top = (pre >> b) | 1u;
      int c = __popcll(__ballot((k0 >> b) == top)) +
              __popcll(__ballot((k1 >> b) == top)) +
              __popcll(__ballot((k2 >> b) == top)) +
              __popcll(__ballot((k3 >> b) == top));
      if (c > rem) pre |= (1u << b);
      else rem -= c;
    }
    if (lane == 0) thrs[p] = __uint_as_float(pre);
  }
  __syncthreads();

  for (int item = t; item < 256 * 4; item += 256) {
    int chn = item & 255;
    int rowq = item >> 8;
    __align__(16) unsigned short hv[8];
#pragma unroll
    for (int px = 0; px < 8; px++) {
      int p = rowq * 8 + px;
      float d = dmat[p * PADC + chn];
      float tt = fminf(thrs[p], w_);
      float a = 1.f - ((d > tt) ? w_ : d) / w_;
      unsigned short h, l;
      bsplit(a, h, l);
      hv[px] = h;
    }
    *reinterpret_cast<uint4*>(obT + (size_t)chn * 576 +
                              (gy * 4 + rowq) * 24 + gx * 8) =
        *reinterpret_cast<uint4*>(hv);
  }
}

// ---------------- FC: split-K MFMA on bf16 feats ---------------------------
__global__ __launch_bounds__(64) void fc_mfma_kernel(
    const unsigned short* __restrict__ fT, const float* __restrict__ fcw,
    float* __restrict__ partial) {
  const int blk = blockIdx.x;  // 1728 blocks, 256 k each (8 chunks of 32)
  const int lane = threadIdx.x;
  const int mrow = lane & 15;
  const int slot = lane >> 4;
  const int slot8 = slot * 8;
  const int k0base = blk * 256;

  f32x4 acc = {0.f, 0.f, 0.f, 0.f};
  float4 z4 = make_float4(0.f, 0.f, 0.f, 0.f);
  for (int cc = 0; cc < 8; ++cc) {
    int k0 = k0base + cc * 32;
    int br = k0 / 147456;
    int rb = k0 - br * 147456;
    int c = rb / 576;
    int pth = rb - c * 576;
    size_t aoff = ((size_t)(br * 16 + mrow) * 256 + c) * 576 + pth + slot8;
    bf16x8 ah = *reinterpret_cast<const bf16x8*>(fT + aoff);
    float4 b0 = z4, b1q = z4;
    if (mrow < 10) {
      const float* bp = fcw + (size_t)mrow * 442368 + k0 + slot8;
      b0 = *reinterpret_cast<const float4*>(bp);
      b1q = *reinterpret_cast<const float4*>(bp + 4);
    }
    float bf[8] = {b0.x, b0.y, b0.z, b0.w, b1q.x, b1q.y, b1q.z, b1q.w};
    unsigned short bhv[8], blv[8];
#pragma unroll
    for (int j = 0; j < 8; j++) bsplit(bf[j], bhv[j], blv[j]);
    bf16x8 bh = *reinterpret_cast<bf16x8*>(bhv);
    bf16x8 bl = *reinterpret_cast<bf16x8*>(blv);
    acc = __builtin_amdgcn_mfma_f32_16x16x32_bf16(ah, bh, acc, 0, 0, 0);
    acc = __builtin_amdgcn_mfma_f32_16x16x32_bf16(ah, bl, acc, 0, 0, 0);
  }
#pragma unroll
  for (int rg = 0; rg < 4; rg++)
    partial[(size_t)blk * 256 + (slot * 4 + rg) * 16 + mrow] = acc[rg];
}

__global__ __launch_bounds__(64) void fc_final_kernel(
    const float* __restrict__ partial, const float* __restrict__ fcb,
    float* __restrict__ outp) {
  const int n = blockIdx.x / 10, oo = blockIdx.x % 10;
  const int lane = threadIdx.x;
  float s = 0.f;
  for (int b = lane; b < 1728; b += 64)
    s += partial[(size_t)b * 256 + n * 16 + oo];
#pragma unroll
  for (int off = 32; off > 0; off >>= 1) s += __shfl_down(s, off, 64);
  if (lane == 0) outp[n * 10 + oo] = s + fcb[oo];
}

// ---------------------------------------------------------------------------
extern "C" void kernel_launch(void* const* d_in, const int* in_sizes, int n_in,
                              void* d_out, int out_size, void* d_ws,
                              size_t ws_size, hipStream_t stream) {
  const float* x   = (const float*)d_in[0];
  const float* w1  = (const float*)d_in[1];
  const float* w2  = (const float*)d_in[2];
  const float* w3  = (const float*)d_in[3];
  const float* tri = (const float*)d_in[4];
  const float* fcw = (const float*)d_in[5];
  const float* fcb = (const float*)d_in[6];
  float* out = (float*)d_out;

  float* ws = (float*)d_ws;
  float* a1      = ws;                    // 7,077,888
  float* a2      = a1 + 7077888;          // 3,538,944
  float* s1      = a2 + 3538944;          // 192
  float* s2      = s1 + 192;              // 384
  float* s3      = s2 + 384;              // 768
  float* po0_2   = s3 + 768;              // 384
  float* sp0_2   = po0_2 + 384;           // 16
  float* act0_3  = sp0_2 + 16;            // 768
  float* partial = act0_3 + 768;          // 442,368
  unsigned short* fT   = (unsigned short*)(partial + 442368);  // 7,077,888
  unsigned short* bw1h = fT + 7077888;    // 6,144
  unsigned short* bw1l = bw1h + 6144;
  unsigned short* bph2 = bw1l + 6144;     // 221,184
  unsigned short* bpl2 = bph2 + 221184;
  unsigned short* bph3 = bpl2 + 221184;   // 884,736
  unsigned short* bpl3 = bph3 + 884736;
  char* zf1 = (char*)(bpl3 + 884736);     // 27,648
  char* zf2 = zf1 + 27648;                // 3,456

  sw2_kernel<<<dim3(336), dim3(256), 0, stream>>>(w1, w2, w3, s1, s2, s3);
  prep_kernel<<<dim3(3, 2), dim3(64), 0, stream>>>(s2, s3, tri, po0_2, sp0_2,
                                                   act0_3);
  pack_w1_kernel<<<dim3(24), dim3(256), 0, stream>>>(w1, bw1h, bw1l);
  pack_w_kernel<64, 128><<<dim3(128, 1, 3), dim3(256), 0, stream>>>(w2, bph2,
                                                                    bpl2);
  pack_w_kernel<128, 256><<<dim3(256, 1, 3), dim3(256), 0, stream>>>(w3, bph3,
                                                                     bpl3);

  layer1_kernel<<<dim3(144, 16, 3), dim3(256), 0, stream>>>(x, bw1h, bw1l, s1,
                                                            tri, a1, zf1);
  rbf_l2<<<dim3(72, 16, 3), dim3(256), 0, stream>>>(a1, bph2, bpl2, s2, tri,
                                                    zf1, po0_2, zf2, a2);
  rbf_l3<<<dim3(18, 16, 3), dim3(256), 0, stream>>>(a2, bph3, bpl3, s3, tri,
                                                    zf2, po0_2, sp0_2, act0_3,
                                                    fT);
  fc_mfma_kernel<<<dim3(1728), dim3(64), 0, stream>>>(fT, fcw, partial);
  fc_final_kernel<<<dim3(160), dim3(64), 0, stream>>>(partial, fcb, out);
}

// Round 14
// 78.299 us; speedup vs baseline: 1.5678x; 1.4914x over previous
//
#include <hip/hip_runtime.h>
#include <hip/hip_bf16.h>
#include <math.h>

typedef __attribute__((ext_vector_type(8))) short bf16x8;
typedef __attribute__((ext_vector_type(4))) float f32x4;

__device__ __forceinline__ void bsplit(float f, unsigned short& h,
                                       unsigned short& l) {
  __hip_bfloat16 hb = __float2bfloat16(f);
  float hf = __bfloat162float(hb);
  __hip_bfloat16 lb = __float2bfloat16(f - hf);
  h = *reinterpret_cast<unsigned short*>(&hb);
  l = *reinterpret_cast<unsigned short*>(&lb);
}

// ---------------- |w|^2 per filter row: one wave per row -------------------
__global__ __launch_bounds__(256) void sw2_kernel(
    const float* __restrict__ w1, const float* __restrict__ w2,
    const float* __restrict__ w3,
    float* __restrict__ s1, float* __restrict__ s2, float* __restrict__ s3) {
  const int wid = blockIdx.x * 4 + (threadIdx.x >> 6);
  const int lane = threadIdx.x & 63;
  const float* r;
  float* dst;
  int len;
  if (wid < 192) {
    r = w1 + wid * 25; dst = s1 + wid; len = 25;
  } else if (wid < 576) {
    int u = wid - 192; r = w2 + u * 576; dst = s2 + u; len = 576;
  } else {
    int u = wid - 576; r = w3 + (size_t)u * 1152; dst = s3 + u; len = 1152;
  }
  float s = 0.f;
  for (int i = lane; i < len; i += 64) {
    float v = r[i];
    s += v * v;
  }
#pragma unroll
  for (int off = 32; off > 0; off >>= 1) s += __shfl_down(s, off, 64);
  if (lane == 0) *dst = s;
}

// ---------------- prep: zero-window constants for layers 2/3 ---------------
__global__ __launch_bounds__(64) void prep_kernel(
    const float* __restrict__ s2, const float* __restrict__ s3,
    const float* __restrict__ tri, float* __restrict__ po0_2,
    float* __restrict__ sp0_2, float* __restrict__ act0_3) {
  const int br = blockIdx.x, lay = blockIdx.y, lane = threadIdx.x;
  if (lay == 0) {
    const float w_ = tri[br * 3 + 1];
    float d0 = sqrtf(fmaxf(s2[br * 128 + lane * 2], 1e-12f));
    float d1 = sqrtf(fmaxf(s2[br * 128 + lane * 2 + 1], 1e-12f));
    int cnt = __popcll(__ballot(d0 >= w_)) + __popcll(__ballot(d1 >= w_));
    float thr;
    if (cnt > 63) {
      thr = w_;
    } else {
      unsigned int k0 = __float_as_uint(d0), k1 = __float_as_uint(d1);
      unsigned int pre = 0;
      int rem = 63;
      for (int b = 30; b >= 0; --b) {
        unsigned int top = (pre >> b) | 1u;
        int c = __popcll(__ballot((k0 >> b) == top)) +
                __popcll(__ballot((k1 >> b) == top));
        if (c > rem) pre |= (1u << b);
        else rem -= c;
      }
      thr = __uint_as_float(pre);
    }
    float th = fminf(thr, w_);
    float a0 = 1.f - ((d0 > th) ? w_ : d0) / w_;
    float a1v = 1.f - ((d1 > th) ? w_ : d1) / w_;
    float p0 = a0 * 0.945f, p1 = a1v * 0.945f;
    po0_2[br * 128 + lane * 2] = p0;
    po0_2[br * 128 + lane * 2 + 1] = p1;
    float ss = p0 * p0 + p1 * p1;
#pragma unroll
    for (int off = 32; off > 0; off >>= 1) ss += __shfl_down(ss, off, 64);
    if (lane == 0) sp0_2[br] = ss;
  } else {
    const float w_ = tri[br * 3 + 2];
    float d[4];
#pragma unroll
    for (int j = 0; j < 4; j++)
      d[j] = sqrtf(fmaxf(s3[br * 256 + lane * 4 + j], 1e-12f));
    int cnt = 0;
#pragma unroll
    for (int j = 0; j < 4; j++) cnt += __popcll(__ballot(d[j] >= w_));
    float thr;
    if (cnt > 152) {
      thr = w_;
    } else {
      unsigned int k[4];
#pragma unroll
      for (int j = 0; j < 4; j++) k[j] = __float_as_uint(d[j]);
      unsigned int pre = 0;
      int rem = 152;
      for (int b = 30; b >= 0; --b) {
        unsigned int top = (pre >> b) | 1u;
        int c = 0;
#pragma unroll
        for (int j = 0; j < 4; j++)
          c += __popcll(__ballot((k[j] >> b) == top));
        if (c > rem) pre |= (1u << b);
        else rem -= c;
      }
      thr = __uint_as_float(pre);
    }
    float th = fminf(thr, w_);
#pragma unroll
    for (int j = 0; j < 4; j++)
      act0_3[br * 256 + lane * 4 + j] = 1.f - ((d[j] > th) ? w_ : d[j]) / w_;
  }
}

// ---------------- pack w1 into B-fragment layout [br][col(64)][k(32)] ------
__global__ __launch_bounds__(256) void pack_w1_kernel(
    const float* __restrict__ w1, unsigned short* __restrict__ bh,
    unsigned short* __restrict__ bl) {
  int idx = blockIdx.x * 256 + threadIdx.x;
  if (idx >= 6144) return;
  int k = idx & 31;
  int col = (idx >> 5) & 63;
  int br = idx >> 11;
  float f = (k < 25) ? w1[(br * 64 + col) * 25 + k] : 0.f;
  unsigned short h, l;
  bsplit(f, h, l);
  bh[idx] = h;
  bl[idx] = l;
}

// ---------------- pack conv weights (layers 2/3), split hi/lo --------------
template <int CIN, int COUT>
__global__ __launch_bounds__(256) void pack_w_kernel(
    const float* __restrict__ w, unsigned short* __restrict__ bph,
    unsigned short* __restrict__ bpl) {
  constexpr int K = CIN * 9;
  constexpr int CC = CIN / 32;
  const int n = blockIdx.x, br = blockIdx.z;
  const int t = threadIdx.x;
  __shared__ float row[K];
  const float* src = w + ((size_t)br * COUT + n) * K;
  for (int i = t; i < K; i += 256) row[i] = src[i];
  __syncthreads();
  for (int i = t; i < K; i += 256) {
    int kpos = i / CIN;
    int e = i - kpos * CIN;
    float f = row[e * 9 + kpos];
    unsigned short h, l;
    bsplit(f, h, l);
    size_t oidx =
        (((size_t)br * 9 * CC + (size_t)kpos * CC + (e >> 5)) * COUT + n) * 32 +
        (e & 31);
    bph[oidx] = h;
    bpl[oidx] = l;
  }
}

// ---------------- Layer 1: MFMA conv, tiered select, VALUE-EXACT flags -----
__global__ __launch_bounds__(256) void layer1_kernel(
    const float* __restrict__ x, const unsigned short* __restrict__ bw1h,
    const unsigned short* __restrict__ bw1l, const float* __restrict__ sw2v,
    const float* __restrict__ tri, float* __restrict__ a1,
    char* __restrict__ zf1) {
  const int gidx = blockIdx.x;  // 12x12 tiles
  const int gy = gidx / 12, gx = gidx % 12;
  const int n = blockIdx.y, br = blockIdx.z;
  const int t = threadIdx.x;
  const int lane = t & 63, wid = t >> 6;

  __shared__ __align__(16) float win[12][12];
  __shared__ float sp2s[64];
  __shared__ float sw2s[64];
  __shared__ __align__(16) float dmat[64][68];

  const int y0 = gy * 8 - 2, x0 = gx * 8 - 2;
  const float* xb = x + ((size_t)(n * 3 + br)) * 96 * 96;
  if (t < 144) {
    int wy = t / 12, wx = t - (t / 12) * 12;
    int y = y0 + wy, xx = x0 + wx;
    float v = 0.f;
    if (y >= 0 && y < 96 && xx >= 0 && xx < 96) v = xb[y * 96 + xx];
    win[wy][wx] = v;
  }
  if (t >= 192) sw2s[t - 192] = sw2v[br * 64 + (t - 192)];
  __syncthreads();

  if (t < 64) {
    int py = t >> 3, px = t & 7;
    float s = 0.f;
#pragma unroll
    for (int ky = 0; ky < 5; ky++)
#pragma unroll
      for (int kx = 0; kx < 5; kx++) {
        float v = win[py + ky][px + kx];
        s += v * v;
      }
    sp2s[t] = s;
  }

  const int mrow = lane & 15;
  const int slot = lane >> 4;
  const int pixel = wid * 16 + mrow;
  const int ppy = pixel >> 3, ppx = pixel & 7;
  unsigned short ahv[8], alv[8];
#pragma unroll
  for (int j = 0; j < 8; j++) {
    int k = slot * 8 + j;
    float v = 0.f;
    if (k < 25) {
      int ky = (k * 205) >> 10;
      int kx = k - ky * 5;
      v = win[ppy + ky][ppx + kx];
    }
    bsplit(v, ahv[j], alv[j]);
  }
  bf16x8 ah = *reinterpret_cast<bf16x8*>(ahv);
  bf16x8 al = *reinterpret_cast<bf16x8*>(alv);

  f32x4 acc[4], accB[4];
  f32x4 zz = {0.f, 0.f, 0.f, 0.f};
#pragma unroll
  for (int nt = 0; nt < 4; nt++) {
    acc[nt] = zz;
    accB[nt] = zz;
  }
#pragma unroll
  for (int nt = 0; nt < 4; nt++) {
    const int off = ((br * 64 + nt * 16 + mrow) << 5) + (slot << 3);
    bf16x8 bh = *reinterpret_cast<const bf16x8*>(bw1h + off);
    bf16x8 bl = *reinterpret_cast<const bf16x8*>(bw1l + off);
    acc[nt] = __builtin_amdgcn_mfma_f32_16x16x32_bf16(ah, bh, acc[nt], 0, 0, 0);
    accB[nt] =
        __builtin_amdgcn_mfma_f32_16x16x32_bf16(ah, bl, accB[nt], 0, 0, 0);
    accB[nt] =
        __builtin_amdgcn_mfma_f32_16x16x32_bf16(al, bh, accB[nt], 0, 0, 0);
  }
  __syncthreads();

  const float w_ = tri[br * 3 + 0];
  const float w2_ = w_ * w_;
  const int flidx = ((br * 16 + n) * 48 + gy * 4 + wid) * 12 + gx;

  float d2v[4][4];
#pragma unroll
  for (int nt = 0; nt < 4; nt++) {
    const float swc = sw2s[nt * 16 + mrow];
#pragma unroll
    for (int rg = 0; rg < 4; rg++)
      d2v[nt][rg] = sp2s[wid * 16 + slot * 4 + rg] + swc -
                    2.f * (acc[nt][rg] + accB[nt][rg]);
  }

  int cnt_lt[4] = {0, 0, 0, 0};
#pragma unroll
  for (int rg = 0; rg < 4; rg++) {
#pragma unroll
    for (int nt = 0; nt < 4; nt++) {
      unsigned long long m = __ballot(d2v[nt][rg] < w2_);
      cnt_lt[rg] += __popcll((m >> (slot * 16)) & 0xFFFFull);
    }
  }

  const bool myzero = (cnt_lt[0] | cnt_lt[1] | cnt_lt[2] | cnt_lt[3]) == 0;
  if (__all(myzero)) {
    if (lane == 0) zf1[flidx] = 0;
    return;
  }

  const float A2[2][2] = {{0.9f, 0.93f}, {0.96f, 0.99f}};
  const bool mycheap = cnt_lt[0] <= 32 && cnt_lt[1] <= 32 &&
                       cnt_lt[2] <= 32 && cnt_lt[3] <= 32;
  if (__all(mycheap)) {
#pragma unroll
    for (int nt = 0; nt < 4; nt++) {
      const int ch = nt * 16 + mrow;
#pragma unroll
      for (int rg = 0; rg < 4; rg++) {
        const int p = wid * 16 + slot * 4 + rg;
        float d2 = d2v[nt][rg];
        float a = (d2 < w2_) ? 1.f - sqrtf(fmaxf(d2, 1e-12f)) / w_ : 0.f;
        dmat[p][ch] = a;
      }
    }
    float pooled[4];
#pragma unroll
    for (int g = 0; g < 4; g++) {
      float po = 0.f;
#pragma unroll
      for (int py = 0; py < 2; py++)
#pragma unroll
        for (int q = 0; q < 2; q++) {
          int pi = py * 8 + g * 2 + q;
          po += dmat[wid * 16 + pi][lane] * A2[py][q];
        }
      pooled[g] = po * 0.25f;
    }
    bool nz = (pooled[0] != 0.f) | (pooled[1] != 0.f) | (pooled[2] != 0.f) |
              (pooled[3] != 0.f);
    unsigned long long mm = __ballot(nz);
    if (mm) {
#pragma unroll
      for (int g = 0; g < 4; g++)
        a1[((((size_t)(br * 16 + n)) * 48 + (gy * 4 + wid)) * 48 +
            (gx * 4 + g)) * 64 + lane] = pooled[g];
      if (lane == 0) zf1[flidx] = 1;
    } else {
      if (lane == 0) zf1[flidx] = 0;
    }
    return;
  }

  // exact fallback
#pragma unroll
  for (int nt = 0; nt < 4; nt++) {
    const int ch = nt * 16 + mrow;
#pragma unroll
    for (int rg = 0; rg < 4; rg++) {
      const int p = wid * 16 + slot * 4 + rg;
      dmat[p][ch] = sqrtf(fmaxf(d2v[nt][rg], 1e-12f));
    }
  }
  float thrv[16];
  unsigned int need = 0;
#pragma unroll
  for (int i = 0; i < 16; i++) {
    float v = dmat[wid * 16 + i][lane];
    int cnt = __popcll(__ballot(v >= w_));
    if (cnt >= 32) thrv[i] = w_;
    else need |= (1u << i);
  }
  if (need) {
#pragma unroll
    for (int i = 0; i < 16; i++) {
      if (!((need >> i) & 1)) continue;
      unsigned int key = __float_as_uint(dmat[wid * 16 + i][lane]);
      unsigned int pre = 0;
      int rem = 31;
      for (int b = 30; b >= 0; --b) {
        unsigned int top = (pre >> b) | 1u;
        int cnt = __popcll(__ballot((key >> b) == top));
        if (cnt > rem) pre |= (1u << b);
        else rem -= cnt;
      }
      thrv[i] = __uint_as_float(pre);
    }
  }
  float pooled[4];
#pragma unroll
  for (int g = 0; g < 4; g++) {
    float po = 0.f;
#pragma unroll
    for (int py = 0; py < 2; py++)
#pragma unroll
      for (int q = 0; q < 2; q++) {
        int pi = py * 8 + g * 2 + q;
        float d = dmat[wid * 16 + pi][lane];
        float th = fminf(thrv[pi], w_);
        float a = 1.f - ((d > th) ? w_ : d) / w_;
        po += a * A2[py][q];
      }
    pooled[g] = po * 0.25f;
  }
  bool nz = (pooled[0] != 0.f) | (pooled[1] != 0.f) | (pooled[2] != 0.f) |
            (pooled[3] != 0.f);
  unsigned long long mm = __ballot(nz);
  if (mm) {
#pragma unroll
    for (int g = 0; g < 4; g++)
      a1[((((size_t)(br * 16 + n)) * 48 + (gy * 4 + wid)) * 48 +
          (gx * 4 + g)) * 64 + lane] = pooled[g];
    if (lane == 0) zf1[flidx] = 1;
  } else {
    if (lane == 0) zf1[flidx] = 0;
  }
}

// ---------------- Layer 2: flag-gated MFMA RBF conv ------------------------
__global__ __launch_bounds__(256) void rbf_l2(
    const float* __restrict__ a1, const unsigned short* __restrict__ bph,
    const unsigned short* __restrict__ bpl, const float* __restrict__ sw2v,
    const float* __restrict__ tri, const char* __restrict__ zf1,
    const float* __restrict__ po0_2, char* __restrict__ zf2,
    float* __restrict__ a2) {
  constexpr int CIN = 64, COUT = 128, HIN = 48, KRANK = 63;
  constexpr int CC = CIN / 32, NCH = 9 * CC, NTW = 2, PADC = COUT + 4;
  constexpr int WIN_USH = 60 * CIN;
  constexpr int WIN_BYTES = 2 * WIN_USH * 2;
  constexpr int DMAT_BYTES = 32 * PADC * 4;
  constexpr int UNI_BYTES = WIN_BYTES > DMAT_BYTES ? WIN_BYTES : DMAT_BYTES;

  __shared__ __align__(16) char uni[UNI_BYTES];
  __shared__ float cellq[60][4];
  __shared__ float cellsum[60];
  __shared__ float sp2[32];
  __shared__ float thrs[32];
  __shared__ float sw2s[COUT];
  __shared__ float po0s[COUT];
  __shared__ char fl[24];
  __shared__ int anyf, zflag, diffl;

  unsigned short* winh = (unsigned short*)uni;
  unsigned short* winl = winh + WIN_USH;
  float* dmat = (float*)uni;

  const int gy = blockIdx.x / 6, gx = blockIdx.x % 6;
  const int n = blockIdx.y, br = blockIdx.z;
  const int t = threadIdx.x, lane = t & 63, wvid = t >> 6, ng = wvid;
  const float w_ = tri[br * 3 + 1];
  const int y0 = gy * 4 - 1, x0 = gx * 8 - 1;
  const int fbase = ((br * 16 + n) * 12 + gy) * 6 + gx;

  if (t < 24) {
    int i = t >> 2, j = t & 3;
    int r = gy * 4 - 1 + i, ct = 2 * gx - 1 + j;
    fl[t] = (r >= 0 && r < 48 && ct >= 0 && ct < 12)
                ? zf1[((br * 16 + n) * 48 + r) * 12 + ct]
                : (char)0;
  }
  if (t == 255) diffl = 0;
  __syncthreads();
  if (t == 0) {
    int a = 0;
    for (int i = 0; i < 24; i++) a |= fl[i];
    anyf = a;
  }
  __syncthreads();
  if (!anyf) {
    if (t == 0) zf2[fbase] = 0;
    return;
  }

  for (int i = t; i < COUT; i += 256) {
    sw2s[i] = sw2v[br * COUT + i];
    po0s[i] = po0_2[br * COUT + i];
  }

  const int cell = t >> 2, q = t & 3;
  const int wy = cell / 10, wx = cell - (cell / 10) * 10;
  const int yy = y0 + wy, xx = x0 + wx;
  bool ok = false;
  if (t < 240 && yy >= 0 && yy < HIN && xx >= 0 && xx < HIN)
    ok = fl[wy * 4 + ((xx >> 2) - (2 * gx - 1))] != 0;
  if (t < 240) {
    const float* rp =
        a1 + ((size_t)((br * 16 + n) * HIN + yy) * HIN + xx) * CIN +
        q * (CIN / 4);
    const int sx = (wx & 7) << 3;
    float ss = 0.f;
#pragma unroll
    for (int cq = 0; cq < CIN / 16; cq++) {
      float4 v = ok ? *reinterpret_cast<const float4*>(rp + cq * 4)
                    : make_float4(0.f, 0.f, 0.f, 0.f);
      unsigned short hh[4], ll[4];
      float fv[4] = {v.x, v.y, v.z, v.w};
#pragma unroll
      for (int j = 0; j < 4; j++) {
        float f = fv[j];
        ss += f * f;
        bsplit(f, hh[j], ll[j]);
      }
      int c = q * (CIN / 4) + cq * 4;
      int cst = c ^ sx;
      *reinterpret_cast<ushort4*>(&winh[cell * CIN + cst]) =
          make_ushort4(hh[0], hh[1], hh[2], hh[3]);
      *reinterpret_cast<ushort4*>(&winl[cell * CIN + cst]) =
          make_ushort4(ll[0], ll[1], ll[2], ll[3]);
    }
    cellq[cell][q] = ss;
  }
  __syncthreads();
  if (t < 60)
    cellsum[t] = cellq[t][0] + cellq[t][1] + cellq[t][2] + cellq[t][3];
  __syncthreads();
  if (t < 32) {
    int py = t >> 3, px = t & 7;
    float s = 0.f;
#pragma unroll
    for (int ky = 0; ky < 3; ky++)
#pragma unroll
      for (int kx = 0; kx < 3; kx++) s += cellsum[(py + ky) * 10 + px + kx];
    sp2[t] = s;
  }
  if (t == 0) {
    float s = 0.f;
    for (int i = 0; i < 60; i++) s += cellsum[i];
    zflag = (s == 0.f);
  }
  __syncthreads();
  if (zflag) {
    if (t == 0) zf2[fbase] = 0;
    return;
  }

  // ---- conv: 3-deep B pipeline, dual accumulators ------------------------
  const int pix0 = lane & 15;
  const int g8 = (lane >> 4) << 3;
  const int ppy = pix0 >> 3, ppx = pix0 & 7;

  f32x4 acc[2][NTW], accB[2][NTW];
  f32x4 zz = {0.f, 0.f, 0.f, 0.f};
#pragma unroll
  for (int mt = 0; mt < 2; mt++)
#pragma unroll
    for (int nt = 0; nt < NTW; nt++) {
      acc[mt][nt] = zz;
      accB[mt][nt] = zz;
    }

  const size_t bbase = (size_t)br * NCH;
  const int nb0 = ng * (NTW * 16) + pix0;
  bf16x8 bufA[2 * NTW], bufB[2 * NTW], bufC[2 * NTW];

  auto loadB = [&](int chunk, bf16x8* dst) {
    const unsigned short* p0 = bph + ((bbase + chunk) * COUT + nb0) * 32 + g8;
    const unsigned short* p1 = bpl + ((bbase + chunk) * COUT + nb0) * 32 + g8;
#pragma unroll
    for (int nt = 0; nt < NTW; nt++) {
      dst[2 * nt] = *reinterpret_cast<const bf16x8*>(p0 + nt * 512);
      dst[2 * nt + 1] = *reinterpret_cast<const bf16x8*>(p1 + nt * 512);
    }
  };
  auto compute = [&](int chunk, bf16x8* b) {
    const int kpos = chunk / CC, cc = chunk - (chunk / CC) * CC;
    const int ky = kpos / 3, kx = kpos - (kpos / 3) * 3;
    const int wxx = ppx + kx;
    const int sx = (wxx & 7) << 3;
    const int cbase = ((cc << 5) + g8) ^ sx;
#pragma unroll
    for (int mt = 0; mt < 2; mt++) {
      const int r0 = (mt * 2 + ppy + ky) * 10 + wxx;
      bf16x8 ah = *reinterpret_cast<const bf16x8*>(&winh[r0 * CIN + cbase]);
      bf16x8 al = *reinterpret_cast<const bf16x8*>(&winl[r0 * CIN + cbase]);
#pragma unroll
      for (int nt = 0; nt < NTW; nt++) {
        acc[mt][nt] = __builtin_amdgcn_mfma_f32_16x16x32_bf16(
            ah, b[2 * nt], acc[mt][nt], 0, 0, 0);
        accB[mt][nt] = __builtin_amdgcn_mfma_f32_16x16x32_bf16(
            ah, b[2 * nt + 1], accB[mt][nt], 0, 0, 0);
        accB[mt][nt] = __builtin_amdgcn_mfma_f32_16x16x32_bf16(
            al, b[2 * nt], accB[mt][nt], 0, 0, 0);
      }
    }
  };

  loadB(0, bufA);
  loadB(1, bufB);
  for (int g = 0; g < NCH; g += 3) {
    if (g + 2 < NCH) loadB(g + 2, bufC);
    compute(g, bufA);
    if (g + 3 < NCH) loadB(g + 3, bufA);
    compute(g + 1, bufB);
    if (g + 4 < NCH) loadB(g + 4, bufB);
    compute(g + 2, bufC);
  }
  __syncthreads();

  const int rgrp = (lane >> 4) << 2;
#pragma unroll
  for (int mt = 0; mt < 2; mt++) {
    const int prow = mt * 16 + rgrp;
#pragma unroll
    for (int nt = 0; nt < NTW; nt++) {
      const int col = ng * (NTW * 16) + nt * 16 + pix0;
      const float sw = sw2s[col];
#pragma unroll
      for (int rg = 0; rg < 4; rg++) {
        const int pix = prow + rg;
        float d2 =
            sp2[pix] + sw - 2.f * (acc[mt][nt][rg] + accB[mt][nt][rg]);
        dmat[pix * PADC + col] = sqrtf(fmaxf(d2, 1e-12f));
      }
    }
  }
  __syncthreads();

  for (int i = 0; i < 8; i++) {
    const int p = wvid * 8 + i;
    float2 f = *reinterpret_cast<const float2*>(&dmat[p * PADC + lane * 2]);
    float v0 = f.x, v1 = f.y;
    int cnt = __popcll(__ballot(v0 >= w_)) + __popcll(__ballot(v1 >= w_));
    if (cnt > KRANK) {
      if (lane == 0) thrs[p] = w_;
      continue;
    }
    unsigned int k0 = __float_as_uint(v0), k1 = __float_as_uint(v1);
    unsigned int pre = 0;
    int rem = KRANK;
    for (int b = 30; b >= 0; --b) {
      unsigned int top = (pre >> b) | 1u;
      int c = __popcll(__ballot((k0 >> b) == top)) +
              __popcll(__ballot((k1 >> b) == top));
      if (c > rem) pre |= (1u << b);
      else rem -= c;
    }
    if (lane == 0) thrs[p] = __uint_as_float(pre);
  }
  __syncthreads();

  float* ob = a2 + ((size_t)(br * 16 + n)) * 24 * 24 * COUT;
  int mydiff = 0;
  for (int i = t; i < 8 * COUT; i += 256) {
    int qq = i / COUT;
    int chn = i - qq * COUT;
    int qy = qq >> 2, qx = qq & 3;
    int p00 = qy * 16 + qx * 2;
    float d00 = dmat[p00 * PADC + chn];
    float d01 = dmat[(p00 + 1) * PADC + chn];
    float d10 = dmat[(p00 + 8) * PADC + chn];
    float d11 = dmat[(p00 + 9) * PADC + chn];
    float t00 = fminf(thrs[p00], w_);
    float t01 = fminf(thrs[p00 + 1], w_);
    float t10 = fminf(thrs[p00 + 8], w_);
    float t11 = fminf(thrs[p00 + 9], w_);
    float a00 = 1.f - ((d00 > t00) ? w_ : d00) / w_;
    float a01 = 1.f - ((d01 > t01) ? w_ : d01) / w_;
    float a10 = 1.f - ((d10 > t10) ? w_ : d10) / w_;
    float a11 = 1.f - ((d11 > t11) ? w_ : d11) / w_;
    float po = 0.25f * (a00 * 0.9f + a01 * 0.93f + a10 * 0.96f + a11 * 0.99f);
    ob[((size_t)((gy * 2 + qy) * 24 + gx * 4 + qx)) * COUT + chn] = po;
    mydiff |= (po != po0s[chn]);
  }
  if (mydiff) diffl = 1;
  __syncthreads();
  if (t == 0) zf2[fbase] = diffl ? 1 : 0;
}

// ---------------- Layer 3: flag-gated, po0-substituting, bf16 feats out ----
__global__ __launch_bounds__(256) void rbf_l3(
    const float* __restrict__ a2, const unsigned short* __restrict__ bph,
    const unsigned short* __restrict__ bpl, const float* __restrict__ sw2v,
    const float* __restrict__ tri, const char* __restrict__ zf2,
    const float* __restrict__ po0_2, const float* __restrict__ sp0_2,
    const float* __restrict__ act0_3, unsigned short* __restrict__ fT) {
  constexpr int CIN = 128, COUT = 256, HIN = 24, KRANK = 152;
  constexpr int CC = CIN / 32, NCH = 9 * CC, NTW = 4, PADC = COUT + 4;
  constexpr int WIN_USH = 60 * CIN;
  constexpr int WIN_BYTES = 2 * WIN_USH * 2;
  constexpr int DMAT_BYTES = 32 * PADC * 4;
  constexpr int UNI_BYTES = WIN_BYTES > DMAT_BYTES ? WIN_BYTES : DMAT_BYTES;

  __shared__ __align__(16) char uni[UNI_BYTES];
  __shared__ float cellq[60][4];
  __shared__ float cellsum[60];
  __shared__ float sp2[32];
  __shared__ float thrs[32];
  __shared__ float sw2s[COUT];
  __shared__ __align__(16) float po0s[128];
  __shared__ char fl[16];
  __shared__ int pure0, zflag;

  unsigned short* winh = (unsigned short*)uni;
  unsigned short* winl = winh + WIN_USH;
  float* dmat = (float*)uni;

  const int gy = blockIdx.x / 3, gx = blockIdx.x % 3;
  const int n = blockIdx.y, br = blockIdx.z;
  const int t = threadIdx.x, lane = t & 63, wvid = t >> 6, ng = wvid;
  const float w_ = tri[br * 3 + 2];
  const int y0 = gy * 4 - 1, x0 = gx * 8 - 1;
  const float sp0 = sp0_2[br];

  if (t < 16) {
    int i = t >> 2, j = t & 3;
    int tr = 2 * gy - 1 + i, tc = 2 * gx - 1 + j;
    fl[t] = (tr >= 0 && tr < 12 && tc >= 0 && tc < 6)
                ? zf2[((br * 16 + n) * 12 + tr) * 6 + tc]
                : (char)0;
  }
  if (t >= 64 && t < 192) po0s[t - 64] = po0_2[br * 128 + (t - 64)];
  __syncthreads();
  if (t == 0) {
    int a = 0;
    for (int i = 0; i < 16; i++) a |= fl[i];
    pure0 = (!a) && (sp0 == 0.f);
  }
  __syncthreads();

  unsigned short* obT = fT + (size_t)(br * 16 + n) * 256 * 576;
  if (pure0) {
    int col = t;
    float a = act0_3[br * 256 + col];
    unsigned short h, l;
    bsplit(a, h, l);
    unsigned int hh = (unsigned int)h | ((unsigned int)h << 16);
    uint4 hv = {hh, hh, hh, hh};
#pragma unroll
    for (int row = 0; row < 4; row++)
      *reinterpret_cast<uint4*>(obT + (size_t)col * 576 +
                                (gy * 4 + row) * 24 + gx * 8) = hv;
    return;
  }

  for (int i = t; i < COUT; i += 256) sw2s[i] = sw2v[br * COUT + i];

  const int cell = t >> 2, q = t & 3;
  const int wy = cell / 10, wx = cell - (cell / 10) * 10;
  const int yy = y0 + wy, xx = x0 + wx;
  const bool okb =
      (t < 240) && (yy >= 0 && yy < HIN && xx >= 0 && xx < HIN);
  int fcell = 0;
  if (okb)
    fcell = fl[((yy >> 1) - (2 * gy - 1)) * 4 + ((xx >> 2) - (2 * gx - 1))];
  if (t < 240) {
    const float* rp =
        a2 + ((size_t)((br * 16 + n) * HIN + yy) * HIN + xx) * CIN +
        q * (CIN / 4);
    const int sx = (wx & 7) << 3;
    float ss = 0.f;
#pragma unroll
    for (int cq = 0; cq < CIN / 16; cq++) {
      int c = q * (CIN / 4) + cq * 4;
      float4 v;
      if (!okb) v = make_float4(0.f, 0.f, 0.f, 0.f);
      else if (!fcell) v = *reinterpret_cast<const float4*>(&po0s[c]);
      else v = *reinterpret_cast<const float4*>(rp + cq * 4);
      unsigned short hh[4], ll[4];
      float fv[4] = {v.x, v.y, v.z, v.w};
#pragma unroll
      for (int j = 0; j < 4; j++) {
        float f = fv[j];
        ss += f * f;
        bsplit(f, hh[j], ll[j]);
      }
      int cst = c ^ sx;
      *reinterpret_cast<ushort4*>(&winh[cell * CIN + cst]) =
          make_ushort4(hh[0], hh[1], hh[2], hh[3]);
      *reinterpret_cast<ushort4*>(&winl[cell * CIN + cst]) =
          make_ushort4(ll[0], ll[1], ll[2], ll[3]);
    }
    cellq[cell][q] = ss;
  }
  __syncthreads();
  if (t < 60)
    cellsum[t] = cellq[t][0] + cellq[t][1] + cellq[t][2] + cellq[t][3];
  __syncthreads();
  if (t < 32) {
    int py = t >> 3, px = t & 7;
    float s = 0.f;
#pragma unroll
    for (int ky = 0; ky < 3; ky++)
#pragma unroll
      for (int kx = 0; kx < 3; kx++) s += cellsum[(py + ky) * 10 + px + kx];
    sp2[t] = s;
  }
  if (t == 0) {
    float s = 0.f;
    for (int i = 0; i < 60; i++) s += cellsum[i];
    zflag = (s == 0.f);
  }
  __syncthreads();
  if (zflag) {
    int col = t;
    float a = act0_3[br * 256 + col];
    unsigned short h, l;
    bsplit(a, h, l);
    unsigned int hh = (unsigned int)h | ((unsigned int)h << 16);
    uint4 hv = {hh, hh, hh, hh};
#pragma unroll
    for (int row = 0; row < 4; row++)
      *reinterpret_cast<uint4*>(obT + (size_t)col * 576 +
                                (gy * 4 + row) * 24 + gx * 8) = hv;
    return;
  }

  // ---- conv: 3-deep B pipeline, dual accumulators ------------------------
  const int pix0 = lane & 15;
  const int g8 = (lane >> 4) << 3;
  const int ppy = pix0 >> 3, ppx = pix0 & 7;

  f32x4 acc[2][NTW], accB[2][NTW];
  f32x4 zz = {0.f, 0.f, 0.f, 0.f};
#pragma unroll
  for (int mt = 0; mt < 2; mt++)
#pragma unroll
    for (int nt = 0; nt < NTW; nt++) {
      acc[mt][nt] = zz;
      accB[mt][nt] = zz;
    }

  const size_t bbase = (size_t)br * NCH;
  const int nb0 = ng * (NTW * 16) + pix0;
  bf16x8 bufA[2 * NTW], bufB[2 * NTW], bufC[2 * NTW];

  auto loadB = [&](int chunk, bf16x8* dst) {
    const unsigned short* p0 = bph + ((bbase + chunk) * COUT + nb0) * 32 + g8;
    const unsigned short* p1 = bpl + ((bbase + chunk) * COUT + nb0) * 32 + g8;
#pragma unroll
    for (int nt = 0; nt < NTW; nt++) {
      dst[2 * nt] = *reinterpret_cast<const bf16x8*>(p0 + nt * 512);
      dst[2 * nt + 1] = *reinterpret_cast<const bf16x8*>(p1 + nt * 512);
    }
  };
  auto compute = [&](int chunk, bf16x8* b) {
    const int kpos = chunk / CC, cc = chunk - (chunk / CC) * CC;
    const int ky = kpos / 3, kx = kpos - (kpos / 3) * 3;
    const int wxx = ppx + kx;
    const int sx = (wxx & 7) << 3;
    const int cbase = ((cc << 5) + g8) ^ sx;
#pragma unroll
    for (int mt = 0; mt < 2; mt++) {
      const int r0 = (mt * 2 + ppy + ky) * 10 + wxx;
      bf16x8 ah = *reinterpret_cast<const bf16x8*>(&winh[r0 * CIN + cbase]);
      bf16x8 al = *reinterpret_cast<const bf16x8*>(&winl[r0 * CIN + cbase]);
#pragma unroll
      for (int nt = 0; nt < NTW; nt++) {
        acc[mt][nt] = __builtin_amdgcn_mfma_f32_16x16x32_bf16(
            ah, b[2 * nt], acc[mt][nt], 0, 0, 0);
        accB[mt][nt] = __builtin_amdgcn_mfma_f32_16x16x32_bf16(
            ah, b[2 * nt + 1], accB[mt][nt], 0, 0, 0);
        accB[mt][nt] = __builtin_amdgcn_mfma_f32_16x16x32_bf16(
            al, b[2 * nt], accB[mt][nt], 0, 0, 0);
      }
    }
  };

  loadB(0, bufA);
  loadB(1, bufB);
  for (int g = 0; g < NCH; g += 3) {
    if (g + 2 < NCH) loadB(g + 2, bufC);
    compute(g, bufA);
    if (g + 3 < NCH) loadB(g + 3, bufA);
    compute(g + 1, bufB);
    if (g + 4 < NCH) loadB(g + 4, bufB);
    compute(g + 2, bufC);
  }
  __syncthreads();

  const int rgrp = (lane >> 4) << 2;
#pragma unroll
  for (int mt = 0; mt < 2; mt++) {
    const int prow = mt * 16 + rgrp;
#pragma unroll
    for (int nt = 0; nt < NTW; nt++) {
      const int col = ng * (NTW * 16) + nt * 16 + pix0;
      const float sw = sw2s[col];
#pragma unroll
      for (int rg = 0; rg < 4; rg++) {
        const int pix = prow + rg;
        float d2 =
            sp2[pix] + sw - 2.f * (acc[mt][nt][rg] + accB[mt][nt][rg]);
        dmat[pix * PADC + col] = sqrtf(fmaxf(d2, 1e-12f));
      }
    }
  }
  __syncthreads();

  for (int i = 0; i < 8; i++) {
    const int p = wvid * 8 + i;
    float4 f = *reinterpret_cast<const float4*>(&dmat[p * PADC + lane * 4]);
    float v0 = f.x, v1 = f.y, v2 = f.z, v3 = f.w;
    int cnt = __popcll(__ballot(v0 >= w_)) + __popcll(__ballot(v1 >= w_)) +
              __popcll(__ballot(v2 >= w_)) + __popcll(__ballot(v3 >= w_));
    if (cnt > KRANK) {
      if (lane == 0) thrs[p] = w_;
      continue;
    }
    unsigned int k0 = __float_as_uint(v0), k1 = __float_as_uint(v1);
    unsigned int k2 = __float_as_uint(v2), k3 = __float_as_uint(v3);
    unsigned int pre = 0;
    int rem = KRANK;
    for (int b = 30; b >= 0; --b) {
      unsigned int top = (pre >> b) | 1u;
      int c = __popcll(__ballot((k0 >> b) == top)) +
              __popcll(__ballot((k1 >> b) == top)) +
              __popcll(__ballot((k2 >> b) == top)) +
              __popcll(__ballot((k3 >> b) == top));
      if (c > rem) pre |= (1u << b);
      else rem -= c;
    }
    if (lane == 0) thrs[p] = __uint_as_float(pre);
  }
  __syncthreads();

  for (int item = t; item < 256 * 4; item += 256) {
    int chn = item & 255;
    int rowq = item >> 8;
    __align__(16) unsigned short hv[8];
#pragma unroll
    for (int px = 0; px < 8; px++) {
      int p = rowq * 8 + px;
      float d = dmat[p * PADC + chn];
      float tt = fminf(thrs[p], w_);
      float a = 1.f - ((d > tt) ? w_ : d) / w_;
      unsigned short h, l;
      bsplit(a, h, l);
      hv[px] = h;
    }
    *reinterpret_cast<uint4*>(obT + (size_t)chn * 576 +
                              (gy * 4 + rowq) * 24 + gx * 8) =
        *reinterpret_cast<uint4*>(hv);
  }
}

// ---------------- FC: split-K MFMA on bf16 feats ---------------------------
__global__ __launch_bounds__(64) void fc_mfma_kernel(
    const unsigned short* __restrict__ fT, const float* __restrict__ fcw,
    float* __restrict__ partial) {
  const int blk = blockIdx.x;
  const int lane = threadIdx.x;
  const int mrow = lane & 15;
  const int slot = lane >> 4;
  const int slot8 = slot * 8;
  const int k0base = blk * 256;

  f32x4 acc = {0.f, 0.f, 0.f, 0.f};
  float4 z4 = make_float4(0.f, 0.f, 0.f, 0.f);
  for (int cc = 0; cc < 8; ++cc) {
    int k0 = k0base + cc * 32;
    int br = k0 / 147456;
    int rb = k0 - br * 147456;
    int c = rb / 576;
    int pth = rb - c * 576;
    size_t aoff = ((size_t)(br * 16 + mrow) * 256 + c) * 576 + pth + slot8;
    bf16x8 ah = *reinterpret_cast<const bf16x8*>(fT + aoff);
    float4 b0 = z4, b1q = z4;
    if (mrow < 10) {
      const float* bp = fcw + (size_t)mrow * 442368 + k0 + slot8;
      b0 = *reinterpret_cast<const float4*>(bp);
      b1q = *reinterpret_cast<const float4*>(bp + 4);
    }
    float bf[8] = {b0.x, b0.y, b0.z, b0.w, b1q.x, b1q.y, b1q.z, b1q.w};
    unsigned short bhv[8], blv[8];
#pragma unroll
    for (int j = 0; j < 8; j++) bsplit(bf[j], bhv[j], blv[j]);
    bf16x8 bh = *reinterpret_cast<bf16x8*>(bhv);
    bf16x8 bl = *reinterpret_cast<bf16x8*>(blv);
    acc = __builtin_amdgcn_mfma_f32_16x16x32_bf16(ah, bh, acc, 0, 0, 0);
    acc = __builtin_amdgcn_mfma_f32_16x16x32_bf16(ah, bl, acc, 0, 0, 0);
  }
#pragma unroll
  for (int rg = 0; rg < 4; rg++)
    partial[(size_t)blk * 256 + (slot * 4 + rg) * 16 + mrow] = acc[rg];
}

__global__ __launch_bounds__(64) void fc_final_kernel(
    const float* __restrict__ partial, const float* __restrict__ fcb,
    float* __restrict__ outp) {
  const int n = blockIdx.x / 10, oo = blockIdx.x % 10;
  const int lane = threadIdx.x;
  float s = 0.f;
  for (int b = lane; b < 1728; b += 64)
    s += partial[(size_t)b * 256 + n * 16 + oo];
#pragma unroll
  for (int off = 32; off > 0; off >>= 1) s += __shfl_down(s, off, 64);
  if (lane == 0) outp[n * 10 + oo] = s + fcb[oo];
}

// ---------------------------------------------------------------------------
extern "C" void kernel_launch(void* const* d_in, const int* in_sizes, int n_in,
                              void* d_out, int out_size, void* d_ws,
                              size_t ws_size, hipStream_t stream) {
  const float* x   = (const float*)d_in[0];
  const float* w1  = (const float*)d_in[1];
  const float* w2  = (const float*)d_in[2];
  const float* w3  = (const float*)d_in[3];
  const float* tri = (const float*)d_in[4];
  const float* fcw = (const float*)d_in[5];
  const float* fcb = (const float*)d_in[6];
  float* out = (float*)d_out;

  float* ws = (float*)d_ws;
  float* a1      = ws;                    // 7,077,888
  float* a2      = a1 + 7077888;          // 3,538,944
  float* s1      = a2 + 3538944;          // 192
  float* s2      = s1 + 192;              // 384
  float* s3      = s2 + 384;              // 768
  float* po0_2   = s3 + 768;              // 384
  float* sp0_2   = po0_2 + 384;           // 16
  float* act0_3  = sp0_2 + 16;            // 768
  float* partial = act0_3 + 768;          // 442,368
  unsigned short* fT   = (unsigned short*)(partial + 442368);  // 7,077,888
  unsigned short* bw1h = fT + 7077888;    // 6,144
  unsigned short* bw1l = bw1h + 6144;
  unsigned short* bph2 = bw1l + 6144;     // 221,184
  unsigned short* bpl2 = bph2 + 221184;
  unsigned short* bph3 = bpl2 + 221184;   // 884,736
  unsigned short* bpl3 = bph3 + 884736;
  char* zf1 = (char*)(bpl3 + 884736);     // 27,648
  char* zf2 = zf1 + 27648;                // 3,456

  sw2_kernel<<<dim3(336), dim3(256), 0, stream>>>(w1, w2, w3, s1, s2, s3);
  prep_kernel<<<dim3(3, 2), dim3(64), 0, stream>>>(s2, s3, tri, po0_2, sp0_2,
                                                   act0_3);
  pack_w1_kernel<<<dim3(24), dim3(256), 0, stream>>>(w1, bw1h, bw1l);
  pack_w_kernel<64, 128><<<dim3(128, 1, 3), dim3(256), 0, stream>>>(w2, bph2,
                                                                    bpl2);
  pack_w_kernel<128, 256><<<dim3(256, 1, 3), dim3(256), 0, stream>>>(w3, bph3,
                                                                     bpl3);

  layer1_kernel<<<dim3(144, 16, 3), dim3(256), 0, stream>>>(x, bw1h, bw1l, s1,
                                                            tri, a1, zf1);
  rbf_l2<<<dim3(72, 16, 3), dim3(256), 0, stream>>>(a1, bph2, bpl2, s2, tri,
                                                    zf1, po0_2, zf2, a2);
  rbf_l3<<<dim3(18, 16, 3), dim3(256), 0, stream>>>(a2, bph3, bpl3, s3, tri,
                                                    zf2, po0_2, sp0_2, act0_3,
                                                    fT);
  fc_mfma_kernel<<<dim3(1728), dim3(64), 0, stream>>>(fT, fcw, partial);
  fc_final_kernel<<<dim3(160), dim3(64), 0, stream>>>(partial, fcb, out);
}

// Round 15
// 71.510 us; speedup vs baseline: 1.7166x; 1.0949x over previous
//
#include <hip/hip_runtime.h>
#include <hip/hip_bf16.h>
#include <math.h>

typedef __attribute__((ext_vector_type(8))) short bf16x8;
typedef __attribute__((ext_vector_type(4))) float f32x4;

__device__ __forceinline__ void bsplit(float f, unsigned short& h,
                                       unsigned short& l) {
  __hip_bfloat16 hb = __float2bfloat16(f);
  float hf = __bfloat162float(hb);
  __hip_bfloat16 lb = __float2bfloat16(f - hf);
  h = *reinterpret_cast<unsigned short*>(&hb);
  l = *reinterpret_cast<unsigned short*>(&lb);
}

// ---------------- pack conv weights (layers 2/3) + row |w|^2 ---------------
template <int CIN, int COUT>
__global__ __launch_bounds__(256) void pack_w_kernel(
    const float* __restrict__ w, unsigned short* __restrict__ bph,
    unsigned short* __restrict__ bpl, float* __restrict__ sout) {
  constexpr int K = CIN * 9;
  constexpr int CC = CIN / 32;
  const int n = blockIdx.x, br = blockIdx.z;
  const int t = threadIdx.x;
  __shared__ float row[K];
  __shared__ float red[256];
  const float* src = w + ((size_t)br * COUT + n) * K;
  float ss = 0.f;
  for (int i = t; i < K; i += 256) {
    float f = src[i];
    row[i] = f;
    ss += f * f;
  }
  red[t] = ss;
  __syncthreads();
  for (int st = 128; st > 0; st >>= 1) {
    if (t < st) red[t] += red[t + st];
    __syncthreads();
  }
  if (t == 0) sout[br * COUT + n] = red[0];
  for (int i = t; i < K; i += 256) {
    int kpos = i / CIN;
    int e = i - kpos * CIN;
    float f = row[e * 9 + kpos];
    unsigned short h, l;
    bsplit(f, h, l);
    size_t oidx =
        (((size_t)br * 9 * CC + (size_t)kpos * CC + (e >> 5)) * COUT + n) * 32 +
        (e & 31);
    bph[oidx] = h;
    bpl[oidx] = l;
  }
}

// ---------------- fused: pack w1 (+s1) and prep constants ------------------
// blocks 0..23: pack w1 fragments + s1 (32-lane-group reduce).
// blocks 24..26: prep layer2 (br=blk-24); 27..29: prep layer3 (br=blk-27).
__global__ __launch_bounds__(256) void pack_w1_prep_kernel(
    const float* __restrict__ w1, const float* __restrict__ s2,
    const float* __restrict__ s3, const float* __restrict__ tri,
    unsigned short* __restrict__ bh, unsigned short* __restrict__ bl,
    float* __restrict__ s1, float* __restrict__ po0_2,
    float* __restrict__ sp0_2, float* __restrict__ act0_3) {
  const int blk = blockIdx.x;
  const int t = threadIdx.x;
  if (blk < 24) {
    int idx = blk * 256 + t;  // < 6144
    int k = idx & 31;
    int col = (idx >> 5) & 63;
    int br = idx >> 11;
    float f = (k < 31 && k < 25) ? w1[(br * 64 + col) * 25 + k] : 0.f;
    unsigned short h, l;
    bsplit(f, h, l);
    bh[idx] = h;
    bl[idx] = l;
    // s1: sum f^2 over the 32-lane group (one col per group)
    float v = f * f;
#pragma unroll
    for (int off = 16; off > 0; off >>= 1) v += __shfl_xor(v, off, 64);
    if ((t & 31) == 0) s1[br * 64 + col] = v;
    return;
  }
  if (t >= 64) return;
  const int lane = t;
  if (blk < 27) {
    const int br = blk - 24;
    const float w_ = tri[br * 3 + 1];
    float d0 = sqrtf(fmaxf(s2[br * 128 + lane * 2], 1e-12f));
    float d1 = sqrtf(fmaxf(s2[br * 128 + lane * 2 + 1], 1e-12f));
    int cnt = __popcll(__ballot(d0 >= w_)) + __popcll(__ballot(d1 >= w_));
    float thr;
    if (cnt > 63) {
      thr = w_;
    } else {
      unsigned int k0 = __float_as_uint(d0), k1 = __float_as_uint(d1);
      unsigned int pre = 0;
      int rem = 63;
      for (int b = 30; b >= 0; --b) {
        unsigned int top = (pre >> b) | 1u;
        int c = __popcll(__ballot((k0 >> b) == top)) +
                __popcll(__ballot((k1 >> b) == top));
        if (c > rem) pre |= (1u << b);
        else rem -= c;
      }
      thr = __uint_as_float(pre);
    }
    float th = fminf(thr, w_);
    float a0 = 1.f - ((d0 > th) ? w_ : d0) / w_;
    float a1v = 1.f - ((d1 > th) ? w_ : d1) / w_;
    float p0 = a0 * 0.945f, p1 = a1v * 0.945f;
    po0_2[br * 128 + lane * 2] = p0;
    po0_2[br * 128 + lane * 2 + 1] = p1;
    float ss = p0 * p0 + p1 * p1;
#pragma unroll
    for (int off = 32; off > 0; off >>= 1) ss += __shfl_down(ss, off, 64);
    if (lane == 0) sp0_2[br] = ss;
  } else {
    const int br = blk - 27;
    const float w_ = tri[br * 3 + 2];
    float d[4];
#pragma unroll
    for (int j = 0; j < 4; j++)
      d[j] = sqrtf(fmaxf(s3[br * 256 + lane * 4 + j], 1e-12f));
    int cnt = 0;
#pragma unroll
    for (int j = 0; j < 4; j++) cnt += __popcll(__ballot(d[j] >= w_));
    float thr;
    if (cnt > 152) {
      thr = w_;
    } else {
      unsigned int k[4];
#pragma unroll
      for (int j = 0; j < 4; j++) k[j] = __float_as_uint(d[j]);
      unsigned int pre = 0;
      int rem = 152;
      for (int b = 30; b >= 0; --b) {
        unsigned int top = (pre >> b) | 1u;
        int c = 0;
#pragma unroll
        for (int j = 0; j < 4; j++)
          c += __popcll(__ballot((k[j] >> b) == top));
        if (c > rem) pre |= (1u << b);
        else rem -= c;
      }
      thr = __uint_as_float(pre);
    }
    float th = fminf(thr, w_);
#pragma unroll
    for (int j = 0; j < 4; j++)
      act0_3[br * 256 + lane * 4 + j] = 1.f - ((d[j] > th) ? w_ : d[j]) / w_;
  }
}

// ---------------- Layer 1: MFMA conv, tiered select, VALUE-EXACT flags -----
__global__ __launch_bounds__(256) void layer1_kernel(
    const float* __restrict__ x, const unsigned short* __restrict__ bw1h,
    const unsigned short* __restrict__ bw1l, const float* __restrict__ sw2v,
    const float* __restrict__ tri, float* __restrict__ a1,
    char* __restrict__ zf1) {
  const int gidx = blockIdx.x;  // 12x12 tiles
  const int gy = gidx / 12, gx = gidx % 12;
  const int n = blockIdx.y, br = blockIdx.z;
  const int t = threadIdx.x;
  const int lane = t & 63, wid = t >> 6;

  __shared__ __align__(16) float win[12][12];
  __shared__ float sp2s[64];
  __shared__ float sw2s[64];
  __shared__ __align__(16) float dmat[64][68];

  const int y0 = gy * 8 - 2, x0 = gx * 8 - 2;
  const float* xb = x + ((size_t)(n * 3 + br)) * 96 * 96;
  if (t < 144) {
    int wy = t / 12, wx = t - (t / 12) * 12;
    int y = y0 + wy, xx = x0 + wx;
    float v = 0.f;
    if (y >= 0 && y < 96 && xx >= 0 && xx < 96) v = xb[y * 96 + xx];
    win[wy][wx] = v;
  }
  if (t >= 192) sw2s[t - 192] = sw2v[br * 64 + (t - 192)];
  __syncthreads();

  if (t < 64) {
    int py = t >> 3, px = t & 7;
    float s = 0.f;
#pragma unroll
    for (int ky = 0; ky < 5; ky++)
#pragma unroll
      for (int kx = 0; kx < 5; kx++) {
        float v = win[py + ky][px + kx];
        s += v * v;
      }
    sp2s[t] = s;
  }

  const int mrow = lane & 15;
  const int slot = lane >> 4;
  const int pixel = wid * 16 + mrow;
  const int ppy = pixel >> 3, ppx = pixel & 7;
  unsigned short ahv[8], alv[8];
#pragma unroll
  for (int j = 0; j < 8; j++) {
    int k = slot * 8 + j;
    float v = 0.f;
    if (k < 25) {
      int ky = (k * 205) >> 10;
      int kx = k - ky * 5;
      v = win[ppy + ky][ppx + kx];
    }
    bsplit(v, ahv[j], alv[j]);
  }
  bf16x8 ah = *reinterpret_cast<bf16x8*>(ahv);
  bf16x8 al = *reinterpret_cast<bf16x8*>(alv);

  f32x4 acc[4], accB[4];
  f32x4 zz = {0.f, 0.f, 0.f, 0.f};
#pragma unroll
  for (int nt = 0; nt < 4; nt++) {
    acc[nt] = zz;
    accB[nt] = zz;
  }
#pragma unroll
  for (int nt = 0; nt < 4; nt++) {
    const int off = ((br * 64 + nt * 16 + mrow) << 5) + (slot << 3);
    bf16x8 bh = *reinterpret_cast<const bf16x8*>(bw1h + off);
    bf16x8 bl = *reinterpret_cast<const bf16x8*>(bw1l + off);
    acc[nt] = __builtin_amdgcn_mfma_f32_16x16x32_bf16(ah, bh, acc[nt], 0, 0, 0);
    accB[nt] =
        __builtin_amdgcn_mfma_f32_16x16x32_bf16(ah, bl, accB[nt], 0, 0, 0);
    accB[nt] =
        __builtin_amdgcn_mfma_f32_16x16x32_bf16(al, bh, accB[nt], 0, 0, 0);
  }
  __syncthreads();

  const float w_ = tri[br * 3 + 0];
  const float w2_ = w_ * w_;
  const int flidx = ((br * 16 + n) * 48 + gy * 4 + wid) * 12 + gx;

  float d2v[4][4];
#pragma unroll
  for (int nt = 0; nt < 4; nt++) {
    const float swc = sw2s[nt * 16 + mrow];
#pragma unroll
    for (int rg = 0; rg < 4; rg++)
      d2v[nt][rg] = sp2s[wid * 16 + slot * 4 + rg] + swc -
                    2.f * (acc[nt][rg] + accB[nt][rg]);
  }

  int cnt_lt[4] = {0, 0, 0, 0};
#pragma unroll
  for (int rg = 0; rg < 4; rg++) {
#pragma unroll
    for (int nt = 0; nt < 4; nt++) {
      unsigned long long m = __ballot(d2v[nt][rg] < w2_);
      cnt_lt[rg] += __popcll((m >> (slot * 16)) & 0xFFFFull);
    }
  }

  const bool myzero = (cnt_lt[0] | cnt_lt[1] | cnt_lt[2] | cnt_lt[3]) == 0;
  if (__all(myzero)) {
    if (lane == 0) zf1[flidx] = 0;
    return;
  }

  const float A2[2][2] = {{0.9f, 0.93f}, {0.96f, 0.99f}};
  const bool mycheap = cnt_lt[0] <= 32 && cnt_lt[1] <= 32 &&
                       cnt_lt[2] <= 32 && cnt_lt[3] <= 32;
  if (__all(mycheap)) {
#pragma unroll
    for (int nt = 0; nt < 4; nt++) {
      const int ch = nt * 16 + mrow;
#pragma unroll
      for (int rg = 0; rg < 4; rg++) {
        const int p = wid * 16 + slot * 4 + rg;
        float d2 = d2v[nt][rg];
        float a = (d2 < w2_) ? 1.f - sqrtf(fmaxf(d2, 1e-12f)) / w_ : 0.f;
        dmat[p][ch] = a;
      }
    }
    float pooled[4];
#pragma unroll
    for (int g = 0; g < 4; g++) {
      float po = 0.f;
#pragma unroll
      for (int py = 0; py < 2; py++)
#pragma unroll
        for (int q = 0; q < 2; q++) {
          int pi = py * 8 + g * 2 + q;
          po += dmat[wid * 16 + pi][lane] * A2[py][q];
        }
      pooled[g] = po * 0.25f;
    }
    bool nz = (pooled[0] != 0.f) | (pooled[1] != 0.f) | (pooled[2] != 0.f) |
              (pooled[3] != 0.f);
    unsigned long long mm = __ballot(nz);
    if (mm) {
#pragma unroll
      for (int g = 0; g < 4; g++)
        a1[((((size_t)(br * 16 + n)) * 48 + (gy * 4 + wid)) * 48 +
            (gx * 4 + g)) * 64 + lane] = pooled[g];
      if (lane == 0) zf1[flidx] = 1;
    } else {
      if (lane == 0) zf1[flidx] = 0;
    }
    return;
  }

  // exact fallback
#pragma unroll
  for (int nt = 0; nt < 4; nt++) {
    const int ch = nt * 16 + mrow;
#pragma unroll
    for (int rg = 0; rg < 4; rg++) {
      const int p = wid * 16 + slot * 4 + rg;
      dmat[p][ch] = sqrtf(fmaxf(d2v[nt][rg], 1e-12f));
    }
  }
  float thrv[16];
  unsigned int need = 0;
#pragma unroll
  for (int i = 0; i < 16; i++) {
    float v = dmat[wid * 16 + i][lane];
    int cnt = __popcll(__ballot(v >= w_));
    if (cnt >= 32) thrv[i] = w_;
    else need |= (1u << i);
  }
  if (need) {
#pragma unroll
    for (int i = 0; i < 16; i++) {
      if (!((need >> i) & 1)) continue;
      unsigned int key = __float_as_uint(dmat[wid * 16 + i][lane]);
      unsigned int pre = 0;
      int rem = 31;
      for (int b = 30; b >= 0; --b) {
        unsigned int top = (pre >> b) | 1u;
        int cnt = __popcll(__ballot((key >> b) == top));
        if (cnt > rem) pre |= (1u << b);
        else rem -= cnt;
      }
      thrv[i] = __uint_as_float(pre);
    }
  }
  float pooled[4];
#pragma unroll
  for (int g = 0; g < 4; g++) {
    float po = 0.f;
#pragma unroll
    for (int py = 0; py < 2; py++)
#pragma unroll
      for (int q = 0; q < 2; q++) {
        int pi = py * 8 + g * 2 + q;
        float d = dmat[wid * 16 + pi][lane];
        float th = fminf(thrv[pi], w_);
        float a = 1.f - ((d > th) ? w_ : d) / w_;
        po += a * A2[py][q];
      }
    pooled[g] = po * 0.25f;
  }
  bool nz = (pooled[0] != 0.f) | (pooled[1] != 0.f) | (pooled[2] != 0.f) |
            (pooled[3] != 0.f);
  unsigned long long mm = __ballot(nz);
  if (mm) {
#pragma unroll
    for (int g = 0; g < 4; g++)
      a1[((((size_t)(br * 16 + n)) * 48 + (gy * 4 + wid)) * 48 +
          (gx * 4 + g)) * 64 + lane] = pooled[g];
    if (lane == 0) zf1[flidx] = 1;
  } else {
    if (lane == 0) zf1[flidx] = 0;
  }
}

// ---------------- Layer 2: flag-gated MFMA RBF conv ------------------------
__global__ __launch_bounds__(256) void rbf_l2(
    const float* __restrict__ a1, const unsigned short* __restrict__ bph,
    const unsigned short* __restrict__ bpl, const float* __restrict__ sw2v,
    const float* __restrict__ tri, const char* __restrict__ zf1,
    const float* __restrict__ po0_2, char* __restrict__ zf2,
    float* __restrict__ a2) {
  constexpr int CIN = 64, COUT = 128, HIN = 48, KRANK = 63;
  constexpr int CC = CIN / 32, NCH = 9 * CC, NTW = 2, PADC = COUT + 4;
  constexpr int WIN_USH = 60 * CIN;
  constexpr int WIN_BYTES = 2 * WIN_USH * 2;
  constexpr int DMAT_BYTES = 32 * PADC * 4;
  constexpr int UNI_BYTES = WIN_BYTES > DMAT_BYTES ? WIN_BYTES : DMAT_BYTES;

  __shared__ __align__(16) char uni[UNI_BYTES];
  __shared__ float cellq[60][4];
  __shared__ float cellsum[60];
  __shared__ float sp2[32];
  __shared__ float thrs[32];
  __shared__ float sw2s[COUT];
  __shared__ float po0s[COUT];
  __shared__ char fl[24];
  __shared__ int anyf, zflag, diffl;

  unsigned short* winh = (unsigned short*)uni;
  unsigned short* winl = winh + WIN_USH;
  float* dmat = (float*)uni;

  const int gy = blockIdx.x / 6, gx = blockIdx.x % 6;
  const int n = blockIdx.y, br = blockIdx.z;
  const int t = threadIdx.x, lane = t & 63, wvid = t >> 6, ng = wvid;
  const float w_ = tri[br * 3 + 1];
  const int y0 = gy * 4 - 1, x0 = gx * 8 - 1;
  const int fbase = ((br * 16 + n) * 12 + gy) * 6 + gx;

  if (t < 24) {
    int i = t >> 2, j = t & 3;
    int r = gy * 4 - 1 + i, ct = 2 * gx - 1 + j;
    fl[t] = (r >= 0 && r < 48 && ct >= 0 && ct < 12)
                ? zf1[((br * 16 + n) * 48 + r) * 12 + ct]
                : (char)0;
  }
  if (t == 255) diffl = 0;
  __syncthreads();
  if (t == 0) {
    int a = 0;
    for (int i = 0; i < 24; i++) a |= fl[i];
    anyf = a;
  }
  __syncthreads();
  if (!anyf) {
    if (t == 0) zf2[fbase] = 0;
    return;
  }

  for (int i = t; i < COUT; i += 256) {
    sw2s[i] = sw2v[br * COUT + i];
    po0s[i] = po0_2[br * COUT + i];
  }

  const int cell = t >> 2, q = t & 3;
  const int wy = cell / 10, wx = cell - (cell / 10) * 10;
  const int yy = y0 + wy, xx = x0 + wx;
  bool ok = false;
  if (t < 240 && yy >= 0 && yy < HIN && xx >= 0 && xx < HIN)
    ok = fl[wy * 4 + ((xx >> 2) - (2 * gx - 1))] != 0;
  if (t < 240) {
    const float* rp =
        a1 + ((size_t)((br * 16 + n) * HIN + yy) * HIN + xx) * CIN +
        q * (CIN / 4);
    const int sx = (wx & 7) << 3;
    float ss = 0.f;
#pragma unroll
    for (int cq = 0; cq < CIN / 16; cq++) {
      float4 v = ok ? *reinterpret_cast<const float4*>(rp + cq * 4)
                    : make_float4(0.f, 0.f, 0.f, 0.f);
      unsigned short hh[4], ll[4];
      float fv[4] = {v.x, v.y, v.z, v.w};
#pragma unroll
      for (int j = 0; j < 4; j++) {
        float f = fv[j];
        ss += f * f;
        bsplit(f, hh[j], ll[j]);
      }
      int c = q * (CIN / 4) + cq * 4;
      int cst = c ^ sx;
      *reinterpret_cast<ushort4*>(&winh[cell * CIN + cst]) =
          make_ushort4(hh[0], hh[1], hh[2], hh[3]);
      *reinterpret_cast<ushort4*>(&winl[cell * CIN + cst]) =
          make_ushort4(ll[0], ll[1], ll[2], ll[3]);
    }
    cellq[cell][q] = ss;
  }
  __syncthreads();
  if (t < 60)
    cellsum[t] = cellq[t][0] + cellq[t][1] + cellq[t][2] + cellq[t][3];
  __syncthreads();
  if (t < 32) {
    int py = t >> 3, px = t & 7;
    float s = 0.f;
#pragma unroll
    for (int ky = 0; ky < 3; ky++)
#pragma unroll
      for (int kx = 0; kx < 3; kx++) s += cellsum[(py + ky) * 10 + px + kx];
    sp2[t] = s;
  }
  if (t == 0) {
    float s = 0.f;
    for (int i = 0; i < 60; i++) s += cellsum[i];
    zflag = (s == 0.f);
  }
  __syncthreads();
  if (zflag) {
    if (t == 0) zf2[fbase] = 0;
    return;
  }

  // ---- conv: 3-deep B pipeline, dual accumulators ------------------------
  const int pix0 = lane & 15;
  const int g8 = (lane >> 4) << 3;
  const int ppy = pix0 >> 3, ppx = pix0 & 7;

  f32x4 acc[2][NTW], accB[2][NTW];
  f32x4 zz = {0.f, 0.f, 0.f, 0.f};
#pragma unroll
  for (int mt = 0; mt < 2; mt++)
#pragma unroll
    for (int nt = 0; nt < NTW; nt++) {
      acc[mt][nt] = zz;
      accB[mt][nt] = zz;
    }

  const size_t bbase = (size_t)br * NCH;
  const int nb0 = ng * (NTW * 16) + pix0;
  bf16x8 bufA[2 * NTW], bufB[2 * NTW], bufC[2 * NTW];

  auto loadB = [&](int chunk, bf16x8* dst) {
    const unsigned short* p0 = bph + ((bbase + chunk) * COUT + nb0) * 32 + g8;
    const unsigned short* p1 = bpl + ((bbase + chunk) * COUT + nb0) * 32 + g8;
#pragma unroll
    for (int nt = 0; nt < NTW; nt++) {
      dst[2 * nt] = *reinterpret_cast<const bf16x8*>(p0 + nt * 512);
      dst[2 * nt + 1] = *reinterpret_cast<const bf16x8*>(p1 + nt * 512);
    }
  };
  auto compute = [&](int chunk, bf16x8* b) {
    const int kpos = chunk / CC, cc = chunk - (chunk / CC) * CC;
    const int ky = kpos / 3, kx = kpos - (kpos / 3) * 3;
    const int wxx = ppx + kx;
    const int sx = (wxx & 7) << 3;
    const int cbase = ((cc << 5) + g8) ^ sx;
#pragma unroll
    for (int mt = 0; mt < 2; mt++) {
      const int r0 = (mt * 2 + ppy + ky) * 10 + wxx;
      bf16x8 ah = *reinterpret_cast<const bf16x8*>(&winh[r0 * CIN + cbase]);
      bf16x8 al = *reinterpret_cast<const bf16x8*>(&winl[r0 * CIN + cbase]);
#pragma unroll
      for (int nt = 0; nt < NTW; nt++) {
        acc[mt][nt] = __builtin_amdgcn_mfma_f32_16x16x32_bf16(
            ah, b[2 * nt], acc[mt][nt], 0, 0, 0);
        accB[mt][nt] = __builtin_amdgcn_mfma_f32_16x16x32_bf16(
            ah, b[2 * nt + 1], accB[mt][nt], 0, 0, 0);
        accB[mt][nt] = __builtin_amdgcn_mfma_f32_16x16x32_bf16(
            al, b[2 * nt], accB[mt][nt], 0, 0, 0);
      }
    }
  };

  loadB(0, bufA);
  loadB(1, bufB);
  for (int g = 0; g < NCH; g += 3) {
    if (g + 2 < NCH) loadB(g + 2, bufC);
    compute(g, bufA);
    if (g + 3 < NCH) loadB(g + 3, bufA);
    compute(g + 1, bufB);
    if (g + 4 < NCH) loadB(g + 4, bufB);
    compute(g + 2, bufC);
  }
  __syncthreads();

  const int rgrp = (lane >> 4) << 2;
#pragma unroll
  for (int mt = 0; mt < 2; mt++) {
    const int prow = mt * 16 + rgrp;
#pragma unroll
    for (int nt = 0; nt < NTW; nt++) {
      const int col = ng * (NTW * 16) + nt * 16 + pix0;
      const float sw = sw2s[col];
#pragma unroll
      for (int rg = 0; rg < 4; rg++) {
        const int pix = prow + rg;
        float d2 =
            sp2[pix] + sw - 2.f * (acc[mt][nt][rg] + accB[mt][nt][rg]);
        dmat[pix * PADC + col] = sqrtf(fmaxf(d2, 1e-12f));
      }
    }
  }
  __syncthreads();

  for (int i = 0; i < 8; i++) {
    const int p = wvid * 8 + i;
    float2 f = *reinterpret_cast<const float2*>(&dmat[p * PADC + lane * 2]);
    float v0 = f.x, v1 = f.y;
    int cnt = __popcll(__ballot(v0 >= w_)) + __popcll(__ballot(v1 >= w_));
    if (cnt > KRANK) {
      if (lane == 0) thrs[p] = w_;
      continue;
    }
    unsigned int k0 = __float_as_uint(v0), k1 = __float_as_uint(v1);
    unsigned int pre = 0;
    int rem = KRANK;
    for (int b = 30; b >= 0; --b) {
      unsigned int top = (pre >> b) | 1u;
      int c = __popcll(__ballot((k0 >> b) == top)) +
              __popcll(__ballot((k1 >> b) == top));
      if (c > rem) pre |= (1u << b);
      else rem -= c;
    }
    if (lane == 0) thrs[p] = __uint_as_float(pre);
  }
  __syncthreads();

  float* ob = a2 + ((size_t)(br * 16 + n)) * 24 * 24 * COUT;
  int mydiff = 0;
  for (int i = t; i < 8 * COUT; i += 256) {
    int qq = i / COUT;
    int chn = i - qq * COUT;
    int qy = qq >> 2, qx = qq & 3;
    int p00 = qy * 16 + qx * 2;
    float d00 = dmat[p00 * PADC + chn];
    float d01 = dmat[(p00 + 1) * PADC + chn];
    float d10 = dmat[(p00 + 8) * PADC + chn];
    float d11 = dmat[(p00 + 9) * PADC + chn];
    float t00 = fminf(thrs[p00], w_);
    float t01 = fminf(thrs[p00 + 1], w_);
    float t10 = fminf(thrs[p00 + 8], w_);
    float t11 = fminf(thrs[p00 + 9], w_);
    float a00 = 1.f - ((d00 > t00) ? w_ : d00) / w_;
    float a01 = 1.f - ((d01 > t01) ? w_ : d01) / w_;
    float a10 = 1.f - ((d10 > t10) ? w_ : d10) / w_;
    float a11 = 1.f - ((d11 > t11) ? w_ : d11) / w_;
    float po = 0.25f * (a00 * 0.9f + a01 * 0.93f + a10 * 0.96f + a11 * 0.99f);
    ob[((size_t)((gy * 2 + qy) * 24 + gx * 4 + qx)) * COUT + chn] = po;
    mydiff |= (po != po0s[chn]);
  }
  if (mydiff) diffl = 1;
  __syncthreads();
  if (t == 0) zf2[fbase] = diffl ? 1 : 0;
}

// ---------------- Layer 3: flag-gated, po0-substituting, bf16 feats out ----
__global__ __launch_bounds__(256) void rbf_l3(
    const float* __restrict__ a2, const unsigned short* __restrict__ bph,
    const unsigned short* __restrict__ bpl, const float* __restrict__ sw2v,
    const float* __restrict__ tri, const char* __restrict__ zf2,
    const float* __restrict__ po0_2, const float* __restrict__ sp0_2,
    const float* __restrict__ act0_3, unsigned short* __restrict__ fT) {
  constexpr int CIN = 128, COUT = 256, HIN = 24, KRANK = 152;
  constexpr int CC = CIN / 32, NCH = 9 * CC, NTW = 4, PADC = COUT + 4;
  constexpr int WIN_USH = 60 * CIN;
  constexpr int WIN_BYTES = 2 * WIN_USH * 2;
  constexpr int DMAT_BYTES = 32 * PADC * 4;
  constexpr int UNI_BYTES = WIN_BYTES > DMAT_BYTES ? WIN_BYTES : DMAT_BYTES;

  __shared__ __align__(16) char uni[UNI_BYTES];
  __shared__ float cellq[60][4];
  __shared__ float cellsum[60];
  __shared__ float sp2[32];
  __shared__ float thrs[32];
  __shared__ float sw2s[COUT];
  __shared__ __align__(16) float po0s[128];
  __shared__ char fl[16];
  __shared__ int pure0, zflag;

  unsigned short* winh = (unsigned short*)uni;
  unsigned short* winl = winh + WIN_USH;
  float* dmat = (float*)uni;

  const int gy = blockIdx.x / 3, gx = blockIdx.x % 3;
  const int n = blockIdx.y, br = blockIdx.z;
  const int t = threadIdx.x, lane = t & 63, wvid = t >> 6, ng = wvid;
  const float w_ = tri[br * 3 + 2];
  const int y0 = gy * 4 - 1, x0 = gx * 8 - 1;
  const float sp0 = sp0_2[br];

  if (t < 16) {
    int i = t >> 2, j = t & 3;
    int tr = 2 * gy - 1 + i, tc = 2 * gx - 1 + j;
    fl[t] = (tr >= 0 && tr < 12 && tc >= 0 && tc < 6)
                ? zf2[((br * 16 + n) * 12 + tr) * 6 + tc]
                : (char)0;
  }
  if (t >= 64 && t < 192) po0s[t - 64] = po0_2[br * 128 + (t - 64)];
  __syncthreads();
  if (t == 0) {
    int a = 0;
    for (int i = 0; i < 16; i++) a |= fl[i];
    pure0 = (!a) && (sp0 == 0.f);
  }
  __syncthreads();

  unsigned short* obT = fT + (size_t)(br * 16 + n) * 256 * 576;
  if (pure0) {
    int col = t;
    float a = act0_3[br * 256 + col];
    unsigned short h, l;
    bsplit(a, h, l);
    unsigned int hh = (unsigned int)h | ((unsigned int)h << 16);
    uint4 hv = {hh, hh, hh, hh};
#pragma unroll
    for (int row = 0; row < 4; row++)
      *reinterpret_cast<uint4*>(obT + (size_t)col * 576 +
                                (gy * 4 + row) * 24 + gx * 8) = hv;
    return;
  }

  for (int i = t; i < COUT; i += 256) sw2s[i] = sw2v[br * COUT + i];

  const int cell = t >> 2, q = t & 3;
  const int wy = cell / 10, wx = cell - (cell / 10) * 10;
  const int yy = y0 + wy, xx = x0 + wx;
  const bool okb =
      (t < 240) && (yy >= 0 && yy < HIN && xx >= 0 && xx < HIN);
  int fcell = 0;
  if (okb)
    fcell = fl[((yy >> 1) - (2 * gy - 1)) * 4 + ((xx >> 2) - (2 * gx - 1))];
  if (t < 240) {
    const float* rp =
        a2 + ((size_t)((br * 16 + n) * HIN + yy) * HIN + xx) * CIN +
        q * (CIN / 4);
    const int sx = (wx & 7) << 3;
    float ss = 0.f;
#pragma unroll
    for (int cq = 0; cq < CIN / 16; cq++) {
      int c = q * (CIN / 4) + cq * 4;
      float4 v;
      if (!okb) v = make_float4(0.f, 0.f, 0.f, 0.f);
      else if (!fcell) v = *reinterpret_cast<const float4*>(&po0s[c]);
      else v = *reinterpret_cast<const float4*>(rp + cq * 4);
      unsigned short hh[4], ll[4];
      float fv[4] = {v.x, v.y, v.z, v.w};
#pragma unroll
      for (int j = 0; j < 4; j++) {
        float f = fv[j];
        ss += f * f;
        bsplit(f, hh[j], ll[j]);
      }
      int cst = c ^ sx;
      *reinterpret_cast<ushort4*>(&winh[cell * CIN + cst]) =
          make_ushort4(hh[0], hh[1], hh[2], hh[3]);
      *reinterpret_cast<ushort4*>(&winl[cell * CIN + cst]) =
          make_ushort4(ll[0], ll[1], ll[2], ll[3]);
    }
    cellq[cell][q] = ss;
  }
  __syncthreads();
  if (t < 60)
    cellsum[t] = cellq[t][0] + cellq[t][1] + cellq[t][2] + cellq[t][3];
  __syncthreads();
  if (t < 32) {
    int py = t >> 3, px = t & 7;
    float s = 0.f;
#pragma unroll
    for (int ky = 0; ky < 3; ky++)
#pragma unroll
      for (int kx = 0; kx < 3; kx++) s += cellsum[(py + ky) * 10 + px + kx];
    sp2[t] = s;
  }
  if (t == 0) {
    float s = 0.f;
    for (int i = 0; i < 60; i++) s += cellsum[i];
    zflag = (s == 0.f);
  }
  __syncthreads();
  if (zflag) {
    int col = t;
    float a = act0_3[br * 256 + col];
    unsigned short h, l;
    bsplit(a, h, l);
    unsigned int hh = (unsigned int)h | ((unsigned int)h << 16);
    uint4 hv = {hh, hh, hh, hh};
#pragma unroll
    for (int row = 0; row < 4; row++)
      *reinterpret_cast<uint4*>(obT + (size_t)col * 576 +
                                (gy * 4 + row) * 24 + gx * 8) = hv;
    return;
  }

  // ---- conv: 3-deep B pipeline, dual accumulators ------------------------
  const int pix0 = lane & 15;
  const int g8 = (lane >> 4) << 3;
  const int ppy = pix0 >> 3, ppx = pix0 & 7;

  f32x4 acc[2][NTW], accB[2][NTW];
  f32x4 zz = {0.f, 0.f, 0.f, 0.f};
#pragma unroll
  for (int mt = 0; mt < 2; mt++)
#pragma unroll
    for (int nt = 0; nt < NTW; nt++) {
      acc[mt][nt] = zz;
      accB[mt][nt] = zz;
    }

  const size_t bbase = (size_t)br * NCH;
  const int nb0 = ng * (NTW * 16) + pix0;
  bf16x8 bufA[2 * NTW], bufB[2 * NTW], bufC[2 * NTW];

  auto loadB = [&](int chunk, bf16x8* dst) {
    const unsigned short* p0 = bph + ((bbase + chunk) * COUT + nb0) * 32 + g8;
    const unsigned short* p1 = bpl + ((bbase + chunk) * COUT + nb0) * 32 + g8;
#pragma unroll
    for (int nt = 0; nt < NTW; nt++) {
      dst[2 * nt] = *reinterpret_cast<const bf16x8*>(p0 + nt * 512);
      dst[2 * nt + 1] = *reinterpret_cast<const bf16x8*>(p1 + nt * 512);
    }
  };
  auto compute = [&](int chunk, bf16x8* b) {
    const int kpos = chunk / CC, cc = chunk - (chunk / CC) * CC;
    const int ky = kpos / 3, kx = kpos - (kpos / 3) * 3;
    const int wxx = ppx + kx;
    const int sx = (wxx & 7) << 3;
    const int cbase = ((cc << 5) + g8) ^ sx;
#pragma unroll
    for (int mt = 0; mt < 2; mt++) {
      const int r0 = (mt * 2 + ppy + ky) * 10 + wxx;
      bf16x8 ah = *reinterpret_cast<const bf16x8*>(&winh[r0 * CIN + cbase]);
      bf16x8 al = *reinterpret_cast<const bf16x8*>(&winl[r0 * CIN + cbase]);
#pragma unroll
      for (int nt = 0; nt < NTW; nt++) {
        acc[mt][nt] = __builtin_amdgcn_mfma_f32_16x16x32_bf16(
            ah, b[2 * nt], acc[mt][nt], 0, 0, 0);
        accB[mt][nt] = __builtin_amdgcn_mfma_f32_16x16x32_bf16(
            ah, b[2 * nt + 1], accB[mt][nt], 0, 0, 0);
        accB[mt][nt] = __builtin_amdgcn_mfma_f32_16x16x32_bf16(
            al, b[2 * nt], accB[mt][nt], 0, 0, 0);
      }
    }
  };

  loadB(0, bufA);
  loadB(1, bufB);
  for (int g = 0; g < NCH; g += 3) {
    if (g + 2 < NCH) loadB(g + 2, bufC);
    compute(g, bufA);
    if (g + 3 < NCH) loadB(g + 3, bufA);
    compute(g + 1, bufB);
    if (g + 4 < NCH) loadB(g + 4, bufB);
    compute(g + 2, bufC);
  }
  __syncthreads();

  const int rgrp = (lane >> 4) << 2;
#pragma unroll
  for (int mt = 0; mt < 2; mt++) {
    const int prow = mt * 16 + rgrp;
#pragma unroll
    for (int nt = 0; nt < NTW; nt++) {
      const int col = ng * (NTW * 16) + nt * 16 + pix0;
      const float sw = sw2s[col];
#pragma unroll
      for (int rg = 0; rg < 4; rg++) {
        const int pix = prow + rg;
        float d2 =
            sp2[pix] + sw - 2.f * (acc[mt][nt][rg] + accB[mt][nt][rg]);
        dmat[pix * PADC + col] = sqrtf(fmaxf(d2, 1e-12f));
      }
    }
  }
  __syncthreads();

  for (int i = 0; i < 8; i++) {
    const int p = wvid * 8 + i;
    float4 f = *reinterpret_cast<const float4*>(&dmat[p * PADC + lane * 4]);
    float v0 = f.x, v1 = f.y, v2 = f.z, v3 = f.w;
    int cnt = __popcll(__ballot(v0 >= w_)) + __popcll(__ballot(v1 >= w_)) +
              __popcll(__ballot(v2 >= w_)) + __popcll(__ballot(v3 >= w_));
    if (cnt > KRANK) {
      if (lane == 0) thrs[p] = w_;
      continue;
    }
    unsigned int k0 = __float_as_uint(v0), k1 = __float_as_uint(v1);
    unsigned int k2 = __float_as_uint(v2), k3 = __float_as_uint(v3);
    unsigned int pre = 0;
    int rem = KRANK;
    for (int b = 30; b >= 0; --b) {
      unsigned int top = (pre >> b) | 1u;
      int c = __popcll(__ballot((k0 >> b) == top)) +
              __popcll(__ballot((k1 >> b) == top)) +
              __popcll(__ballot((k2 >> b) == top)) +
              __popcll(__ballot((k3 >> b) == top));
      if (c > rem) pre |= (1u << b);
      else rem -= c;
    }
    if (lane == 0) thrs[p] = __uint_as_float(pre);
  }
  __syncthreads();

  for (int item = t; item < 256 * 4; item += 256) {
    int chn = item & 255;
    int rowq = item >> 8;
    __align__(16) unsigned short hv[8];
#pragma unroll
    for (int px = 0; px < 8; px++) {
      int p = rowq * 8 + px;
      float d = dmat[p * PADC + chn];
      float tt = fminf(thrs[p], w_);
      float a = 1.f - ((d > tt) ? w_ : d) / w_;
      unsigned short h, l;
      bsplit(a, h, l);
      hv[px] = h;
    }
    *reinterpret_cast<uint4*>(obT + (size_t)chn * 576 +
                              (gy * 4 + rowq) * 24 + gx * 8) =
        *reinterpret_cast<uint4*>(hv);
  }
}

// ---------------- FC: split-K MFMA on bf16 feats ---------------------------
__global__ __launch_bounds__(64) void fc_mfma_kernel(
    const unsigned short* __restrict__ fT, const float* __restrict__ fcw,
    float* __restrict__ partial) {
  const int blk = blockIdx.x;
  const int lane = threadIdx.x;
  const int mrow = lane & 15;
  const int slot = lane >> 4;
  const int slot8 = slot * 8;
  const int k0base = blk * 256;

  f32x4 acc = {0.f, 0.f, 0.f, 0.f};
  float4 z4 = make_float4(0.f, 0.f, 0.f, 0.f);
  for (int cc = 0; cc < 8; ++cc) {
    int k0 = k0base + cc * 32;
    int br = k0 / 147456;
    int rb = k0 - br * 147456;
    int c = rb / 576;
    int pth = rb - c * 576;
    size_t aoff = ((size_t)(br * 16 + mrow) * 256 + c) * 576 + pth + slot8;
    bf16x8 ah = *reinterpret_cast<const bf16x8*>(fT + aoff);
    float4 b0 = z4, b1q = z4;
    if (mrow < 10) {
      const float* bp = fcw + (size_t)mrow * 442368 + k0 + slot8;
      b0 = *reinterpret_cast<const float4*>(bp);
      b1q = *reinterpret_cast<const float4*>(bp + 4);
    }
    float bf[8] = {b0.x, b0.y, b0.z, b0.w, b1q.x, b1q.y, b1q.z, b1q.w};
    unsigned short bhv[8], blv[8];
#pragma unroll
    for (int j = 0; j < 8; j++) bsplit(bf[j], bhv[j], blv[j]);
    bf16x8 bh = *reinterpret_cast<bf16x8*>(bhv);
    bf16x8 bl = *reinterpret_cast<bf16x8*>(blv);
    acc = __builtin_amdgcn_mfma_f32_16x16x32_bf16(ah, bh, acc, 0, 0, 0);
    acc = __builtin_amdgcn_mfma_f32_16x16x32_bf16(ah, bl, acc, 0, 0, 0);
  }
#pragma unroll
  for (int rg = 0; rg < 4; rg++)
    partial[(size_t)blk * 256 + (slot * 4 + rg) * 16 + mrow] = acc[rg];
}

__global__ __launch_bounds__(64) void fc_final_kernel(
    const float* __restrict__ partial, const float* __restrict__ fcb,
    float* __restrict__ outp) {
  const int n = blockIdx.x / 10, oo = blockIdx.x % 10;
  const int lane = threadIdx.x;
  float s = 0.f;
  for (int b = lane; b < 1728; b += 64)
    s += partial[(size_t)b * 256 + n * 16 + oo];
#pragma unroll
  for (int off = 32; off > 0; off >>= 1) s += __shfl_down(s, off, 64);
  if (lane == 0) outp[n * 10 + oo] = s + fcb[oo];
}

// ---------------------------------------------------------------------------
extern "C" void kernel_launch(void* const* d_in, const int* in_sizes, int n_in,
                              void* d_out, int out_size, void* d_ws,
                              size_t ws_size, hipStream_t stream) {
  const float* x   = (const float*)d_in[0];
  const float* w1  = (const float*)d_in[1];
  const float* w2  = (const float*)d_in[2];
  const float* w3  = (const float*)d_in[3];
  const float* tri = (const float*)d_in[4];
  const float* fcw = (const float*)d_in[5];
  const float* fcb = (const float*)d_in[6];
  float* out = (float*)d_out;

  float* ws = (float*)d_ws;
  float* a1      = ws;                    // 7,077,888
  float* a2      = a1 + 7077888;          // 3,538,944
  float* s1      = a2 + 3538944;          // 192
  float* s2      = s1 + 192;              // 384
  float* s3      = s2 + 384;              // 768
  float* po0_2   = s3 + 768;              // 384
  float* sp0_2   = po0_2 + 384;           // 16
  float* act0_3  = sp0_2 + 16;            // 768
  float* partial = act0_3 + 768;          // 442,368
  unsigned short* fT   = (unsigned short*)(partial + 442368);  // 7,077,888
  unsigned short* bw1h = fT + 7077888;    // 6,144
  unsigned short* bw1l = bw1h + 6144;
  unsigned short* bph2 = bw1l + 6144;     // 221,184
  unsigned short* bpl2 = bph2 + 221184;
  unsigned short* bph3 = bpl2 + 221184;   // 884,736
  unsigned short* bpl3 = bph3 + 884736;
  char* zf1 = (char*)(bpl3 + 884736);     // 27,648
  char* zf2 = zf1 + 27648;                // 3,456

  pack_w_kernel<64, 128><<<dim3(128, 1, 3), dim3(256), 0, stream>>>(
      w2, bph2, bpl2, s2);
  pack_w_kernel<128, 256><<<dim3(256, 1, 3), dim3(256), 0, stream>>>(
      w3, bph3, bpl3, s3);
  pack_w1_prep_kernel<<<dim3(30), dim3(256), 0, stream>>>(
      w1, s2, s3, tri, bw1h, bw1l, s1, po0_2, sp0_2, act0_3);

  layer1_kernel<<<dim3(144, 16, 3), dim3(256), 0, stream>>>(x, bw1h, bw1l, s1,
                                                            tri, a1, zf1);
  rbf_l2<<<dim3(72, 16, 3), dim3(256), 0, stream>>>(a1, bph2, bpl2, s2, tri,
                                                    zf1, po0_2, zf2, a2);
  rbf_l3<<<dim3(18, 16, 3), dim3(256), 0, stream>>>(a2, bph3, bpl3, s3, tri,
                                                    zf2, po0_2, sp0_2, act0_3,
                                                    fT);
  fc_mfma_kernel<<<dim3(1728), dim3(64), 0, stream>>>(fT, fcw, partial);
  fc_final_kernel<<<dim3(160), dim3(64), 0, stream>>>(partial, fcb, out);
}